// Round 1
// baseline (1674.026 us; speedup 1.0000x reference)
//
#include <hip/hip_runtime.h>
#include <cmath>

#define B_ 2
#define T_ 2048
#define D_ 1024
#define H_ 16
#define DH 64
#define INNER_ 1024
#define BT (B_*T_)

// ---------------- fp32 tiled GEMM: C[M,N] = A[M,K] @ B[K,N], optional silu ----
#define GBM 64
#define GBN 64
#define GBK 16

__global__ __launch_bounds__(256) void gemm_f32(const float* __restrict__ A,
                                                const float* __restrict__ Bm,
                                                float* __restrict__ C,
                                                int M, int N, int Kd, int act) {
  __shared__ float As[GBK][GBM + 1];
  __shared__ float Bs[GBK][GBN];
  const int tid = threadIdx.x;
  const int tx = tid & 15, ty = tid >> 4;
  const int m0 = blockIdx.y * GBM, n0 = blockIdx.x * GBN;
  const int a_k = tid & 15, a_m = tid >> 4;
  const int b_n = tid & 63, b_k = tid >> 6;
  float acc[4][4];
#pragma unroll
  for (int i = 0; i < 4; ++i)
#pragma unroll
    for (int j = 0; j < 4; ++j) acc[i][j] = 0.f;

  for (int k0 = 0; k0 < Kd; k0 += GBK) {
#pragma unroll
    for (int p = 0; p < 4; ++p)
      As[a_k][a_m + 16 * p] = A[(size_t)(m0 + a_m + 16 * p) * Kd + k0 + a_k];
#pragma unroll
    for (int p = 0; p < 4; ++p)
      Bs[b_k + 4 * p][b_n] = Bm[(size_t)(k0 + b_k + 4 * p) * N + n0 + b_n];
    __syncthreads();
#pragma unroll
    for (int kk = 0; kk < GBK; ++kk) {
      float a4[4], b4[4];
#pragma unroll
      for (int i = 0; i < 4; ++i) a4[i] = As[kk][ty * 4 + i];
#pragma unroll
      for (int j = 0; j < 4; ++j) b4[j] = Bs[kk][tx * 4 + j];
#pragma unroll
      for (int i = 0; i < 4; ++i)
#pragma unroll
        for (int j = 0; j < 4; ++j) acc[i][j] += a4[i] * b4[j];
    }
    __syncthreads();
  }
#pragma unroll
  for (int i = 0; i < 4; ++i) {
#pragma unroll
    for (int j = 0; j < 4; ++j) {
      float v = acc[i][j];
      if (act == 1) v = v / (1.f + expf(-v));  // silu
      C[(size_t)(m0 + ty * 4 + i) * N + n0 + tx * 4 + j] = v;
    }
  }
}

// ---------------- alpha/beta: sigmoid(x@Wa + ba), sigmoid(x@Wb + bb) ----------
__global__ __launch_bounds__(64) void alphabeta_kernel(const float* __restrict__ x,
    const float* __restrict__ Wa, const float* __restrict__ ba,
    const float* __restrict__ Wb, const float* __restrict__ bb,
    float* __restrict__ alpha, float* __restrict__ beta) {
  const int bt = blockIdx.x;
  const int tid = threadIdx.x;  // 64
  __shared__ float xs[D_];
  for (int i = tid; i < D_; i += 64) xs[i] = x[(size_t)bt * D_ + i];
  __syncthreads();
  const int h = tid & 15;
  const int grp = tid >> 4;  // 0..3
  float sa = 0.f, sb = 0.f;
  const int k0 = grp * 256;
  for (int kk = k0; kk < k0 + 256; ++kk) {
    float xv = xs[kk];
    sa += xv * Wa[kk * H_ + h];
    sb += xv * Wb[kk * H_ + h];
  }
  sa += __shfl_xor(sa, 16); sa += __shfl_xor(sa, 32);
  sb += __shfl_xor(sb, 16); sb += __shfl_xor(sb, 32);
  if (grp == 0) {
    alpha[(size_t)bt * H_ + h] = 1.f / (1.f + expf(-(sa + ba[h])));
    beta [(size_t)bt * H_ + h] = 1.f / (1.f + expf(-(sb + bb[h])));
  }
}

// ---------------- depthwise causal conv (K=4) + silu + optional l2norm -------
__global__ __launch_bounds__(256) void convnorm_kernel(
    const float* __restrict__ qpre, const float* __restrict__ kpre, const float* __restrict__ vpre,
    const float* __restrict__ cqw, const float* __restrict__ cqb,
    const float* __restrict__ ckw, const float* __restrict__ ckb,
    const float* __restrict__ cvw, const float* __restrict__ cvb,
    float* __restrict__ qn, float* __restrict__ kn, float* __restrict__ vn) {
  const int bt = blockIdx.x;
  const int t = bt & (T_ - 1);
  const int tid = threadIdx.x;
  const int c = tid * 4;

  auto run = [&](const float* __restrict__ pre, const float* __restrict__ w,
                 const float* __restrict__ bias, float* __restrict__ out, bool norm) {
    float r[4];
    float4 bv = *(const float4*)(bias + c);
    r[0] = bv.x; r[1] = bv.y; r[2] = bv.z; r[3] = bv.w;
    float wl[4][4];
#pragma unroll
    for (int i = 0; i < 4; ++i) {
      float4 wv = *(const float4*)(w + (size_t)(c + i) * 4);
      wl[i][0] = wv.x; wl[i][1] = wv.y; wl[i][2] = wv.z; wl[i][3] = wv.w;
    }
#pragma unroll
    for (int kk = 0; kk < 4; ++kk) {
      int tt = t - 3 + kk;
      if (tt >= 0) {
        float4 xv = *(const float4*)(pre + (size_t)(bt - 3 + kk) * INNER_ + c);
        float xa[4] = {xv.x, xv.y, xv.z, xv.w};
#pragma unroll
        for (int i = 0; i < 4; ++i) r[i] += xa[i] * wl[i][kk];
      }
    }
#pragma unroll
    for (int i = 0; i < 4; ++i) r[i] = r[i] / (1.f + expf(-r[i]));  // silu
    if (norm) {
      float ss = r[0]*r[0] + r[1]*r[1] + r[2]*r[2] + r[3]*r[3];
      ss += __shfl_xor(ss, 1); ss += __shfl_xor(ss, 2);
      ss += __shfl_xor(ss, 4); ss += __shfl_xor(ss, 8);
      float n = sqrtf(ss);
      float sc = 1.f / fmaxf(n, 1e-12f);
#pragma unroll
      for (int i = 0; i < 4; ++i) r[i] *= sc;
    }
    float4 ov = {r[0], r[1], r[2], r[3]};
    *(float4*)(out + (size_t)bt * INNER_ + c) = ov;
  };

  run(qpre, cqw, cqb, qn, true);
  run(kpre, ckw, ckb, kn, true);
  run(vpre, cvw, cvb, vn, false);
}

// ---------------- gated delta recurrence scan --------------------------------
// block = one (b,h): 512 threads = 8 waves; wave owns 8 rows of S; lane owns
// 8 columns of one row. Row update is independent; only intra-wave shfl
// reductions over the 8-lane column groups.
#define CHUNK 32
__global__ __launch_bounds__(512) void scan_kernel(const float* __restrict__ q,
    const float* __restrict__ k, const float* __restrict__ v,
    const float* __restrict__ alpha, const float* __restrict__ beta,
    float* __restrict__ o) {
  const int bh = blockIdx.x;
  const int b = bh >> 4, h = bh & 15;
  const int tid = threadIdx.x;
  const int lane = tid & 63;
  const int wave = tid >> 6;
  const int g = lane & 7;        // column group
  const int r = lane >> 3;       // row within wave
  const int row = wave * 8 + r;  // 0..63
  const int colbase = g * 8;

  __shared__ float qs[CHUNK][64];
  __shared__ float ks[CHUNK][64];
  __shared__ float vs[CHUNK][64];
  __shared__ float as_[CHUNK];
  __shared__ float bs_[CHUNK];

  float S[8];
#pragma unroll
  for (int i = 0; i < 8; ++i) S[i] = 0.f;

  const size_t hofs = (size_t)h * DH;
  for (int t0 = 0; t0 < T_; t0 += CHUNK) {
    __syncthreads();
    for (int idx = tid; idx < CHUNK * 64; idx += 512) {
      int tl = idx >> 6, j = idx & 63;
      size_t gofs = ((size_t)(b * T_ + t0 + tl)) * INNER_ + hofs + j;
      qs[tl][j] = q[gofs];
      ks[tl][j] = k[gofs];
      vs[tl][j] = v[gofs];
    }
    if (tid < CHUNK) {
      int bt = b * T_ + t0 + tid;
      as_[tid] = alpha[(size_t)bt * H_ + h];
      bs_[tid] = beta[(size_t)bt * H_ + h];
    }
    __syncthreads();
#pragma unroll 4
    for (int tl = 0; tl < CHUNK; ++tl) {
      float a = as_[tl], bb = bs_[tl];
      float kf[8], qf[8];
#pragma unroll
      for (int jj = 0; jj < 8; ++jj) {
        kf[jj] = ks[tl][colbase + jj];
        qf[jj] = qs[tl][colbase + jj];
      }
      float vi = vs[tl][row];
      float sk0 = 0.f, sk1 = 0.f, sq0 = 0.f, sq1 = 0.f, kq0 = 0.f, kq1 = 0.f;
#pragma unroll
      for (int jj = 0; jj < 8; jj += 2) {
        sk0 += S[jj] * kf[jj];       sk1 += S[jj + 1] * kf[jj + 1];
        sq0 += S[jj] * qf[jj];       sq1 += S[jj + 1] * qf[jj + 1];
        kq0 += kf[jj] * qf[jj];      kq1 += kf[jj + 1] * qf[jj + 1];
      }
      float sk = sk0 + sk1, sq = sq0 + sq1, kq = kq0 + kq1;
      sk += __shfl_xor(sk, 1); sk += __shfl_xor(sk, 2); sk += __shfl_xor(sk, 4);
      sq += __shfl_xor(sq, 1); sq += __shfl_xor(sq, 2); sq += __shfl_xor(sq, 4);
      kq += __shfl_xor(kq, 1); kq += __shfl_xor(kq, 2); kq += __shfl_xor(kq, 4);
      float c = bb * (vi - a * sk);
#pragma unroll
      for (int jj = 0; jj < 8; ++jj) S[jj] = a * S[jj] + c * kf[jj];
      float oi = a * sq + c * kq;
      if (g == 0)
        o[((size_t)(b * T_ + t0 + tl)) * INNER_ + hofs + row] = oi;
    }
  }
}

// ---------------- RMS norm over INNER, * (1+gamma) * gate --------------------
__global__ __launch_bounds__(256) void rmsgate_kernel(const float* __restrict__ o,
    const float* __restrict__ gate, const float* __restrict__ gamma,
    float* __restrict__ outn) {
  const int bt = blockIdx.x;
  const int tid = threadIdx.x;
  const size_t base = (size_t)bt * INNER_ + tid * 4;
  float4 ov = *(const float4*)(o + base);
  float ss = ov.x*ov.x + ov.y*ov.y + ov.z*ov.z + ov.w*ov.w;
#pragma unroll
  for (int m = 1; m <= 32; m <<= 1) ss += __shfl_xor(ss, m);
  __shared__ float red[4];
  if ((tid & 63) == 0) red[tid >> 6] = ss;
  __syncthreads();
  float tot = red[0] + red[1] + red[2] + red[3];
  float rms = sqrtf(tot * (1.f / (float)INNER_) + 1e-6f);
  float inv = 1.f / rms;
  float4 gm = *(const float4*)(gamma + tid * 4);
  float4 gt = *(const float4*)(gate + base);
  float4 rr;
  rr.x = ov.x * inv * (1.f + gm.x) * gt.x;
  rr.y = ov.y * inv * (1.f + gm.y) * gt.y;
  rr.z = ov.z * inv * (1.f + gm.z) * gt.z;
  rr.w = ov.w * inv * (1.f + gm.w) * gt.w;
  *(float4*)(outn + base) = rr;
}

// ---------------- launch -----------------------------------------------------
extern "C" void kernel_launch(void* const* d_in, const int* in_sizes, int n_in,
                              void* d_out, int out_size, void* d_ws, size_t ws_size,
                              hipStream_t stream) {
  const float* x   = (const float*)d_in[0];
  const float* Wq  = (const float*)d_in[1];
  const float* Wk  = (const float*)d_in[2];
  const float* Wv  = (const float*)d_in[3];
  const float* Wa  = (const float*)d_in[4];
  const float* ba  = (const float*)d_in[5];
  const float* Wb  = (const float*)d_in[6];
  const float* bb  = (const float*)d_in[7];
  const float* Wg  = (const float*)d_in[8];
  const float* Wo  = (const float*)d_in[9];
  const float* cqw = (const float*)d_in[10];
  const float* cqb = (const float*)d_in[11];
  const float* ckw = (const float*)d_in[12];
  const float* ckb = (const float*)d_in[13];
  const float* cvw = (const float*)d_in[14];
  const float* cvb = (const float*)d_in[15];
  const float* gamma = (const float*)d_in[16];

  float* ws = (float*)d_ws;
  const size_t N1 = (size_t)BT * INNER_;
  float* qpre = ws;
  float* kpre = ws + N1;
  float* vpre = ws + 2 * N1;
  float* gate = ws + 3 * N1;
  float* qn   = ws + 4 * N1;
  float* kn   = ws + 5 * N1;
  float* vn   = ws + 6 * N1;
  float* alpha = ws + 7 * N1;
  float* beta  = alpha + (size_t)BT * H_;
  float* obuf = qpre;  // qpre dead after convnorm
  float* nrm  = kpre;  // kpre dead after convnorm
  float* outp = (float*)d_out;

  dim3 ggrid(INNER_ / GBN, BT / GBM);
  gemm_f32<<<ggrid, 256, 0, stream>>>(x, Wq, qpre, BT, INNER_, D_, 0);
  gemm_f32<<<ggrid, 256, 0, stream>>>(x, Wk, kpre, BT, INNER_, D_, 0);
  gemm_f32<<<ggrid, 256, 0, stream>>>(x, Wv, vpre, BT, INNER_, D_, 0);
  gemm_f32<<<ggrid, 256, 0, stream>>>(x, Wg, gate, BT, INNER_, D_, 1);
  alphabeta_kernel<<<BT, 64, 0, stream>>>(x, Wa, ba, Wb, bb, alpha, beta);
  convnorm_kernel<<<BT, 256, 0, stream>>>(qpre, kpre, vpre, cqw, cqb, ckw, ckb,
                                          cvw, cvb, qn, kn, vn);
  scan_kernel<<<B_ * H_, 512, 0, stream>>>(qn, kn, vn, alpha, beta, obuf);
  rmsgate_kernel<<<BT, 256, 0, stream>>>(obuf, gate, gamma, nrm);
  gemm_f32<<<dim3(D_ / GBN, BT / GBM), 256, 0, stream>>>(nrm, Wo, outp, BT, D_, INNER_, 0);
}

// Round 2
// 1180.434 us; speedup vs baseline: 1.4181x; 1.4181x over previous
//
#include <hip/hip_runtime.h>
#include <cmath>

#define B_ 2
#define T_ 2048
#define D_ 1024
#define H_ 16
#define DH 64
#define INNER_ 1024
#define BT (B_*T_)

// ---------------- fp32 tiled GEMM: C[M,N] = A[M,K] @ B[K,N], optional silu ----
#define GBM 64
#define GBN 64
#define GBK 16

__global__ __launch_bounds__(256) void gemm_f32(const float* __restrict__ A,
                                                const float* __restrict__ Bm,
                                                float* __restrict__ C,
                                                int M, int N, int Kd, int act) {
  __shared__ float As[GBK][GBM + 1];
  __shared__ float Bs[GBK][GBN];
  const int tid = threadIdx.x;
  const int tx = tid & 15, ty = tid >> 4;
  const int m0 = blockIdx.y * GBM, n0 = blockIdx.x * GBN;
  const int a_k = tid & 15, a_m = tid >> 4;
  const int b_n = tid & 63, b_k = tid >> 6;
  float acc[4][4];
#pragma unroll
  for (int i = 0; i < 4; ++i)
#pragma unroll
    for (int j = 0; j < 4; ++j) acc[i][j] = 0.f;

  for (int k0 = 0; k0 < Kd; k0 += GBK) {
#pragma unroll
    for (int p = 0; p < 4; ++p)
      As[a_k][a_m + 16 * p] = A[(size_t)(m0 + a_m + 16 * p) * Kd + k0 + a_k];
#pragma unroll
    for (int p = 0; p < 4; ++p)
      Bs[b_k + 4 * p][b_n] = Bm[(size_t)(k0 + b_k + 4 * p) * N + n0 + b_n];
    __syncthreads();
#pragma unroll
    for (int kk = 0; kk < GBK; ++kk) {
      float a4[4], b4[4];
#pragma unroll
      for (int i = 0; i < 4; ++i) a4[i] = As[kk][ty * 4 + i];
#pragma unroll
      for (int j = 0; j < 4; ++j) b4[j] = Bs[kk][tx * 4 + j];
#pragma unroll
      for (int i = 0; i < 4; ++i)
#pragma unroll
        for (int j = 0; j < 4; ++j) acc[i][j] += a4[i] * b4[j];
    }
    __syncthreads();
  }
#pragma unroll
  for (int i = 0; i < 4; ++i) {
#pragma unroll
    for (int j = 0; j < 4; ++j) {
      float v = acc[i][j];
      if (act == 1) v = v / (1.f + expf(-v));  // silu
      C[(size_t)(m0 + ty * 4 + i) * N + n0 + tx * 4 + j] = v;
    }
  }
}

// ---------------- alpha/beta: sigmoid(x@Wa + ba), sigmoid(x@Wb + bb) ----------
__global__ __launch_bounds__(64) void alphabeta_kernel(const float* __restrict__ x,
    const float* __restrict__ Wa, const float* __restrict__ ba,
    const float* __restrict__ Wb, const float* __restrict__ bb,
    float* __restrict__ alpha, float* __restrict__ beta) {
  const int bt = blockIdx.x;
  const int tid = threadIdx.x;  // 64
  __shared__ float xs[D_];
  for (int i = tid; i < D_; i += 64) xs[i] = x[(size_t)bt * D_ + i];
  __syncthreads();
  const int h = tid & 15;
  const int grp = tid >> 4;  // 0..3
  float sa = 0.f, sb = 0.f;
  const int k0 = grp * 256;
  for (int kk = k0; kk < k0 + 256; ++kk) {
    float xv = xs[kk];
    sa += xv * Wa[kk * H_ + h];
    sb += xv * Wb[kk * H_ + h];
  }
  sa += __shfl_xor(sa, 16); sa += __shfl_xor(sa, 32);
  sb += __shfl_xor(sb, 16); sb += __shfl_xor(sb, 32);
  if (grp == 0) {
    alpha[(size_t)bt * H_ + h] = 1.f / (1.f + expf(-(sa + ba[h])));
    beta [(size_t)bt * H_ + h] = 1.f / (1.f + expf(-(sb + bb[h])));
  }
}

// ---------------- depthwise causal conv (K=4) + silu + optional l2norm -------
__global__ __launch_bounds__(256) void convnorm_kernel(
    const float* __restrict__ qpre, const float* __restrict__ kpre, const float* __restrict__ vpre,
    const float* __restrict__ cqw, const float* __restrict__ cqb,
    const float* __restrict__ ckw, const float* __restrict__ ckb,
    const float* __restrict__ cvw, const float* __restrict__ cvb,
    float* __restrict__ qn, float* __restrict__ kn, float* __restrict__ vn) {
  const int bt = blockIdx.x;
  const int t = bt & (T_ - 1);
  const int tid = threadIdx.x;
  const int c = tid * 4;

  auto run = [&](const float* __restrict__ pre, const float* __restrict__ w,
                 const float* __restrict__ bias, float* __restrict__ out, bool norm) {
    float r[4];
    float4 bv = *(const float4*)(bias + c);
    r[0] = bv.x; r[1] = bv.y; r[2] = bv.z; r[3] = bv.w;
    float wl[4][4];
#pragma unroll
    for (int i = 0; i < 4; ++i) {
      float4 wv = *(const float4*)(w + (size_t)(c + i) * 4);
      wl[i][0] = wv.x; wl[i][1] = wv.y; wl[i][2] = wv.z; wl[i][3] = wv.w;
    }
#pragma unroll
    for (int kk = 0; kk < 4; ++kk) {
      int tt = t - 3 + kk;
      if (tt >= 0) {
        float4 xv = *(const float4*)(pre + (size_t)(bt - 3 + kk) * INNER_ + c);
        float xa[4] = {xv.x, xv.y, xv.z, xv.w};
#pragma unroll
        for (int i = 0; i < 4; ++i) r[i] += xa[i] * wl[i][kk];
      }
    }
#pragma unroll
    for (int i = 0; i < 4; ++i) r[i] = r[i] / (1.f + expf(-r[i]));  // silu
    if (norm) {
      float ss = r[0]*r[0] + r[1]*r[1] + r[2]*r[2] + r[3]*r[3];
      ss += __shfl_xor(ss, 1); ss += __shfl_xor(ss, 2);
      ss += __shfl_xor(ss, 4); ss += __shfl_xor(ss, 8);
      float n = sqrtf(ss);
      float sc = 1.f / fmaxf(n, 1e-12f);
#pragma unroll
      for (int i = 0; i < 4; ++i) r[i] *= sc;
    }
    float4 ov = {r[0], r[1], r[2], r[3]};
    *(float4*)(out + (size_t)bt * INNER_ + c) = ov;
  };

  run(qpre, cqw, cqb, qn, true);
  run(kpre, ckw, ckb, kn, true);
  run(vpre, cvw, cvb, vn, false);
}

// ---------------- gated delta recurrence scan --------------------------------
// Rows of S are independent given the per-step shared (a,b,k,q):
//   sk_i = S[i,:]·k ; c_i = b(v_i - a·sk_i) ; S[i,:] = a·S[i,:] + c_i·k
//   o_i  = a·(S[i,:]·q) + c_i·(k·q)
// Mapping: one S-row per 16-lane DPP row (4 cols/lane). All reductions are
// VALU-speed DPP adds (quad_perm xor1/xor2 + row_ror:4/8) — no LDS/ds_permute
// in the serial chain. 128 blocks (4 per (b,h), 16 rows each) x 4 waves
// (1 wave/SIMD — waves never sync inside a chunk). k/q/v/a/b double-buffered
// in LDS, reg-staged global loads issued one chunk ahead.
#define CHUNK 32
#define NCH (T_/CHUNK)

template<int CTRL>
__device__ __forceinline__ float dpp_add(float x) {
  int p = __builtin_amdgcn_update_dpp(0, __float_as_int(x), CTRL, 0xF, 0xF, false);
  return x + __int_as_float(p);
}
__device__ __forceinline__ float rowsum16(float x) {
  x = dpp_add<0xB1>(x);    // quad_perm [1,0,3,2]  (xor 1)
  x = dpp_add<0x4E>(x);    // quad_perm [2,3,0,1]  (xor 2)
  x = dpp_add<0x124>(x);   // row_ror:4
  x = dpp_add<0x128>(x);   // row_ror:8
  return x;                // full 16-lane row sum in every lane
}

__global__ __launch_bounds__(256) void scan_kernel(const float* __restrict__ q,
    const float* __restrict__ k, const float* __restrict__ v,
    const float* __restrict__ alpha, const float* __restrict__ beta,
    float* __restrict__ o) {
  const int blk = blockIdx.x;
  const int bh = blk >> 2;          // 0..31
  const int rb = (blk & 3) * 16;    // row-block base within d=64
  const int b = bh >> 4, h = bh & 15;
  const int tid = threadIdx.x;
  const int lane = tid & 63;
  const int wave = tid >> 6;        // 0..3
  const int g = lane & 15;          // col group within row
  const int cb = g * 4;             // first col of this lane
  const int wrow = wave * 4 + (lane >> 4);  // 0..15: row within block

  __shared__ float ks[2][CHUNK][64];
  __shared__ float qs[2][CHUNK][64];
  __shared__ float vs[2][CHUNK][16];
  __shared__ float as_[2][CHUNK];
  __shared__ float bs_[2][CHUNK];
  __shared__ float os[CHUNK][16];

  const size_t hofs = (size_t)h * DH;
  const size_t btbase = (size_t)b * T_;

  // staging geometry: k/q chunk = 32x64 floats -> 2 float4/thread
  const int e0 = tid * 4;
  const int tl0 = e0 >> 6, j0 = e0 & 63;
  const int tl1 = (1024 + e0) >> 6, j1 = j0;
  const int vtl = tid >> 2, vj = (tid & 3) * 4;   // tid<128: v chunk 32x16

  float4 rk0, rk1, rq0, rq1, rv;
  float ra = 0.f, rbt = 0.f;

  auto issue = [&](int c) {
    size_t bt0 = btbase + (size_t)c * CHUNK;
    rk0 = *(const float4*)&k[(bt0 + tl0) * INNER_ + hofs + j0];
    rk1 = *(const float4*)&k[(bt0 + tl1) * INNER_ + hofs + j1];
    rq0 = *(const float4*)&q[(bt0 + tl0) * INNER_ + hofs + j0];
    rq1 = *(const float4*)&q[(bt0 + tl1) * INNER_ + hofs + j1];
    if (tid < 128) rv = *(const float4*)&v[(bt0 + vtl) * INNER_ + hofs + rb + vj];
    else if (tid < 160) ra = alpha[(bt0 + (tid - 128)) * H_ + h];
    else if (tid < 192) rbt = beta[(bt0 + (tid - 160)) * H_ + h];
  };
  auto commit = [&](int buf) {
    *(float4*)&ks[buf][tl0][j0] = rk0;
    *(float4*)&ks[buf][tl1][j1] = rk1;
    *(float4*)&qs[buf][tl0][j0] = rq0;
    *(float4*)&qs[buf][tl1][j1] = rq1;
    if (tid < 128) *(float4*)&vs[buf][vtl][vj] = rv;
    else if (tid < 160) as_[buf][tid - 128] = ra;
    else if (tid < 192) bs_[buf][tid - 160] = rbt;
  };

  float S0 = 0.f, S1 = 0.f, S2 = 0.f, S3 = 0.f;

  issue(0);
  commit(0);
  __syncthreads();
  int cur = 0;
  for (int c = 0; c < NCH; ++c) {
    if (c + 1 < NCH) issue(c + 1);   // global loads in flight during compute
#pragma unroll 4
    for (int tl = 0; tl < CHUNK; ++tl) {
      float a = as_[cur][tl], bt = bs_[cur][tl];
      float4 kf = *(const float4*)&ks[cur][tl][cb];
      float4 qf = *(const float4*)&qs[cur][tl][cb];
      float vi = vs[cur][tl][wrow];
      float sk = S0 * kf.x + S1 * kf.y + S2 * kf.z + S3 * kf.w;
      float sq = S0 * qf.x + S1 * qf.y + S2 * qf.z + S3 * qf.w;
      float kq = kf.x * qf.x + kf.y * qf.y + kf.z * qf.z + kf.w * qf.w;
      sk = rowsum16(sk);
      sq = rowsum16(sq);
      kq = rowsum16(kq);
      float ci = bt * (vi - a * sk);
      S0 = a * S0 + ci * kf.x;
      S1 = a * S1 + ci * kf.y;
      S2 = a * S2 + ci * kf.z;
      S3 = a * S3 + ci * kf.w;
      if (g == 0) os[tl][wrow] = a * sq + ci * kq;
    }
    __syncthreads();
    {  // coalesced o write for this chunk
      size_t bt0 = btbase + (size_t)c * CHUNK;
      if (tid < 128) {
        float4 ov = *(const float4*)&os[vtl][vj];
        *(float4*)&o[(bt0 + vtl) * INNER_ + hofs + rb + vj] = ov;
      }
    }
    if (c + 1 < NCH) commit(cur ^ 1);
    __syncthreads();
    cur ^= 1;
  }
}

// ---------------- RMS norm over INNER, * (1+gamma) * gate --------------------
__global__ __launch_bounds__(256) void rmsgate_kernel(const float* __restrict__ o,
    const float* __restrict__ gate, const float* __restrict__ gamma,
    float* __restrict__ outn) {
  const int bt = blockIdx.x;
  const int tid = threadIdx.x;
  const size_t base = (size_t)bt * INNER_ + tid * 4;
  float4 ov = *(const float4*)(o + base);
  float ss = ov.x*ov.x + ov.y*ov.y + ov.z*ov.z + ov.w*ov.w;
#pragma unroll
  for (int m = 1; m <= 32; m <<= 1) ss += __shfl_xor(ss, m);
  __shared__ float red[4];
  if ((tid & 63) == 0) red[tid >> 6] = ss;
  __syncthreads();
  float tot = red[0] + red[1] + red[2] + red[3];
  float rms = sqrtf(tot * (1.f / (float)INNER_) + 1e-6f);
  float inv = 1.f / rms;
  float4 gm = *(const float4*)(gamma + tid * 4);
  float4 gt = *(const float4*)(gate + base);
  float4 rr;
  rr.x = ov.x * inv * (1.f + gm.x) * gt.x;
  rr.y = ov.y * inv * (1.f + gm.y) * gt.y;
  rr.z = ov.z * inv * (1.f + gm.z) * gt.z;
  rr.w = ov.w * inv * (1.f + gm.w) * gt.w;
  *(float4*)(outn + base) = rr;
}

// ---------------- launch -----------------------------------------------------
extern "C" void kernel_launch(void* const* d_in, const int* in_sizes, int n_in,
                              void* d_out, int out_size, void* d_ws, size_t ws_size,
                              hipStream_t stream) {
  const float* x   = (const float*)d_in[0];
  const float* Wq  = (const float*)d_in[1];
  const float* Wk  = (const float*)d_in[2];
  const float* Wv  = (const float*)d_in[3];
  const float* Wa  = (const float*)d_in[4];
  const float* ba  = (const float*)d_in[5];
  const float* Wb  = (const float*)d_in[6];
  const float* bb  = (const float*)d_in[7];
  const float* Wg  = (const float*)d_in[8];
  const float* Wo  = (const float*)d_in[9];
  const float* cqw = (const float*)d_in[10];
  const float* cqb = (const float*)d_in[11];
  const float* ckw = (const float*)d_in[12];
  const float* ckb = (const float*)d_in[13];
  const float* cvw = (const float*)d_in[14];
  const float* cvb = (const float*)d_in[15];
  const float* gamma = (const float*)d_in[16];

  float* ws = (float*)d_ws;
  const size_t N1 = (size_t)BT * INNER_;
  float* qpre = ws;
  float* kpre = ws + N1;
  float* vpre = ws + 2 * N1;
  float* gate = ws + 3 * N1;
  float* qn   = ws + 4 * N1;
  float* kn   = ws + 5 * N1;
  float* vn   = ws + 6 * N1;
  float* alpha = ws + 7 * N1;
  float* beta  = alpha + (size_t)BT * H_;
  float* obuf = qpre;  // qpre dead after convnorm
  float* nrm  = kpre;  // kpre dead after convnorm
  float* outp = (float*)d_out;

  dim3 ggrid(INNER_ / GBN, BT / GBM);
  gemm_f32<<<ggrid, 256, 0, stream>>>(x, Wq, qpre, BT, INNER_, D_, 0);
  gemm_f32<<<ggrid, 256, 0, stream>>>(x, Wk, kpre, BT, INNER_, D_, 0);
  gemm_f32<<<ggrid, 256, 0, stream>>>(x, Wv, vpre, BT, INNER_, D_, 0);
  gemm_f32<<<ggrid, 256, 0, stream>>>(x, Wg, gate, BT, INNER_, D_, 1);
  alphabeta_kernel<<<BT, 64, 0, stream>>>(x, Wa, ba, Wb, bb, alpha, beta);
  convnorm_kernel<<<BT, 256, 0, stream>>>(qpre, kpre, vpre, cqw, cqb, ckw, ckb,
                                          cvw, cvb, qn, kn, vn);
  scan_kernel<<<B_ * H_ * 4, 256, 0, stream>>>(qn, kn, vn, alpha, beta, obuf);
  rmsgate_kernel<<<BT, 256, 0, stream>>>(obuf, gate, gamma, nrm);
  gemm_f32<<<dim3(D_ / GBN, BT / GBM), 256, 0, stream>>>(nrm, Wo, outp, BT, D_, INNER_, 0);
}

// Round 3
// 692.624 us; speedup vs baseline: 2.4169x; 1.7043x over previous
//
#include <hip/hip_runtime.h>
#include <hip/hip_bf16.h>
#include <cmath>

#define B_ 2
#define T_ 2048
#define D_ 1024
#define H_ 16
#define DH 64
#define INNER_ 1024
#define BT (B_*T_)

typedef __attribute__((ext_vector_type(8))) __bf16 bf16x8;
typedef __attribute__((ext_vector_type(4))) float f32x4;
typedef const __attribute__((address_space(1))) unsigned gas_u32;
typedef __attribute__((address_space(3))) unsigned las_u32;

__device__ __forceinline__ void async16(const void* g, void* l) {
  __builtin_amdgcn_global_load_lds((gas_u32*)g, (las_u32*)l, 16, 0, 0);
}

// ---------------- convert f32 -> bf16 (elementwise) --------------------------
__global__ __launch_bounds__(256) void cvt_bf16_kernel(const float* __restrict__ in,
                                                       __hip_bfloat16* __restrict__ out,
                                                       int n4) {
  int i = blockIdx.x * 256 + threadIdx.x;
  if (i >= n4) return;
  float4 v = *(const float4*)(in + (size_t)i * 4);
  __hip_bfloat16 t[4];
  t[0] = __float2bfloat16(v.x); t[1] = __float2bfloat16(v.y);
  t[2] = __float2bfloat16(v.z); t[3] = __float2bfloat16(v.w);
  *(uint2*)(out + (size_t)i * 4) = *(uint2*)t;
}

// ---------------- transpose + convert: in [R][C] f32 -> out [C][R] bf16 ------
__global__ __launch_bounds__(256) void transpose_cvt_kernel(const float* __restrict__ in,
                                                            __hip_bfloat16* __restrict__ out,
                                                            int R, int C) {
  __shared__ float tile[32][33];
  const int bc = blockIdx.x * 32, br = blockIdx.y * 32;
  const int tx = threadIdx.x & 31, ty = threadIdx.x >> 5;  // 32 x 8
#pragma unroll
  for (int i = 0; i < 32; i += 8)
    tile[ty + i][tx] = in[(size_t)(br + ty + i) * C + bc + tx];
  __syncthreads();
#pragma unroll
  for (int i = 0; i < 32; i += 8)
    out[(size_t)(bc + ty + i) * R + br + tx] = __float2bfloat16(tile[tx][ty + i]);
}

// ---------------- bf16 MFMA GEMM: C[M,N] f32 = A[M,K]bf16 @ Bt[N,K]bf16^T ----
// m97 structure: 128x128 tile, 4 waves (2x2), BK=32, global_load_lds width 16,
// mfma_f32_16x16x32_bf16, C/D layout col=lane&15 row=(lane>>4)*4+reg.
__global__ __launch_bounds__(256) void gemm_bf16(const __hip_bfloat16* __restrict__ A,
                                                 const __hip_bfloat16* __restrict__ Bt,
                                                 float* __restrict__ C,
                                                 int M, int N, int K, int act) {
  __shared__ __hip_bfloat16 As[128 * 32];
  __shared__ __hip_bfloat16 Bs[128 * 32];
  const int tid = threadIdx.x;
  const int lane = tid & 63, wave = tid >> 6;
  const int wr = wave >> 1, wc = wave & 1;
  const int m0 = blockIdx.y * 128, n0 = blockIdx.x * 128;
  const int srow = tid >> 2, skoff = (tid & 3) * 8;  // staging: 16B per thread
  const int l15 = lane & 15, lg = lane >> 4;

  f32x4 acc[4][4];
#pragma unroll
  for (int m = 0; m < 4; ++m)
#pragma unroll
    for (int n = 0; n < 4; ++n) acc[m][n] = (f32x4)0.f;

  char* asB = (char*)As;
  char* bsB = (char*)Bs;
  const int ldsw = wave * 1024;  // wave-uniform LDS byte base (lane*16 auto)

  for (int k0 = 0; k0 < K; k0 += 32) {
    const __hip_bfloat16* ga0 = A + (size_t)(m0 + srow) * K + k0 + skoff;
    const __hip_bfloat16* ga1 = A + (size_t)(m0 + 64 + srow) * K + k0 + skoff;
    const __hip_bfloat16* gb0 = Bt + (size_t)(n0 + srow) * K + k0 + skoff;
    const __hip_bfloat16* gb1 = Bt + (size_t)(n0 + 64 + srow) * K + k0 + skoff;
    async16(ga0, asB + ldsw);
    async16(ga1, asB + 4096 + ldsw);
    async16(gb0, bsB + ldsw);
    async16(gb1, bsB + 4096 + ldsw);
    __syncthreads();  // drains vmcnt before ds_read

    bf16x8 af[4], bfg[4];
#pragma unroll
    for (int m = 0; m < 4; ++m)
      af[m] = *(const bf16x8*)(asB + ((wr * 64 + m * 16 + l15) * 32 + lg * 8) * 2);
#pragma unroll
    for (int n = 0; n < 4; ++n)
      bfg[n] = *(const bf16x8*)(bsB + ((wc * 64 + n * 16 + l15) * 32 + lg * 8) * 2);
#pragma unroll
    for (int m = 0; m < 4; ++m)
#pragma unroll
      for (int n = 0; n < 4; ++n)
        acc[m][n] = __builtin_amdgcn_mfma_f32_16x16x32_bf16(af[m], bfg[n], acc[m][n], 0, 0, 0);
    __syncthreads();
  }

#pragma unroll
  for (int m = 0; m < 4; ++m) {
    const int rbase = m0 + wr * 64 + m * 16 + lg * 4;
#pragma unroll
    for (int n = 0; n < 4; ++n) {
      const int col = n0 + wc * 64 + n * 16 + l15;
#pragma unroll
      for (int r = 0; r < 4; ++r) {
        float v = acc[m][n][r];
        if (act == 1) v = v / (1.f + expf(-v));  // silu
        C[(size_t)(rbase + r) * N + col] = v;
      }
    }
  }
}

// ---------------- alpha/beta: sigmoid(x@Wa + ba), sigmoid(x@Wb + bb) ----------
__global__ __launch_bounds__(64) void alphabeta_kernel(const float* __restrict__ x,
    const float* __restrict__ Wa, const float* __restrict__ ba,
    const float* __restrict__ Wb, const float* __restrict__ bb,
    float* __restrict__ alpha, float* __restrict__ beta) {
  const int bt = blockIdx.x;
  const int tid = threadIdx.x;  // 64
  __shared__ float xs[D_];
  for (int i = tid; i < D_; i += 64) xs[i] = x[(size_t)bt * D_ + i];
  __syncthreads();
  const int h = tid & 15;
  const int grp = tid >> 4;  // 0..3
  float sa = 0.f, sb = 0.f;
  const int k0 = grp * 256;
  for (int kk = k0; kk < k0 + 256; ++kk) {
    float xv = xs[kk];
    sa += xv * Wa[kk * H_ + h];
    sb += xv * Wb[kk * H_ + h];
  }
  sa += __shfl_xor(sa, 16); sa += __shfl_xor(sa, 32);
  sb += __shfl_xor(sb, 16); sb += __shfl_xor(sb, 32);
  if (grp == 0) {
    alpha[(size_t)bt * H_ + h] = 1.f / (1.f + expf(-(sa + ba[h])));
    beta [(size_t)bt * H_ + h] = 1.f / (1.f + expf(-(sb + bb[h])));
  }
}

// ---------------- depthwise causal conv (K=4) + silu + optional l2norm -------
__global__ __launch_bounds__(256) void convnorm_kernel(
    const float* __restrict__ qpre, const float* __restrict__ kpre, const float* __restrict__ vpre,
    const float* __restrict__ cqw, const float* __restrict__ cqb,
    const float* __restrict__ ckw, const float* __restrict__ ckb,
    const float* __restrict__ cvw, const float* __restrict__ cvb,
    float* __restrict__ qn, float* __restrict__ kn, float* __restrict__ vn) {
  const int bt = blockIdx.x;
  const int t = bt & (T_ - 1);
  const int tid = threadIdx.x;
  const int c = tid * 4;

  auto run = [&](const float* __restrict__ pre, const float* __restrict__ w,
                 const float* __restrict__ bias, float* __restrict__ out, bool norm) {
    float r[4];
    float4 bv = *(const float4*)(bias + c);
    r[0] = bv.x; r[1] = bv.y; r[2] = bv.z; r[3] = bv.w;
    float wl[4][4];
#pragma unroll
    for (int i = 0; i < 4; ++i) {
      float4 wv = *(const float4*)(w + (size_t)(c + i) * 4);
      wl[i][0] = wv.x; wl[i][1] = wv.y; wl[i][2] = wv.z; wl[i][3] = wv.w;
    }
#pragma unroll
    for (int kk = 0; kk < 4; ++kk) {
      int tt = t - 3 + kk;
      if (tt >= 0) {
        float4 xv = *(const float4*)(pre + (size_t)(bt - 3 + kk) * INNER_ + c);
        float xa[4] = {xv.x, xv.y, xv.z, xv.w};
#pragma unroll
        for (int i = 0; i < 4; ++i) r[i] += xa[i] * wl[i][kk];
      }
    }
#pragma unroll
    for (int i = 0; i < 4; ++i) r[i] = r[i] / (1.f + expf(-r[i]));  // silu
    if (norm) {
      float ss = r[0]*r[0] + r[1]*r[1] + r[2]*r[2] + r[3]*r[3];
      ss += __shfl_xor(ss, 1); ss += __shfl_xor(ss, 2);
      ss += __shfl_xor(ss, 4); ss += __shfl_xor(ss, 8);
      float n = sqrtf(ss);
      float sc = 1.f / fmaxf(n, 1e-12f);
#pragma unroll
      for (int i = 0; i < 4; ++i) r[i] *= sc;
    }
    float4 ov = {r[0], r[1], r[2], r[3]};
    *(float4*)(out + (size_t)bt * INNER_ + c) = ov;
  };

  run(qpre, cqw, cqb, qn, true);
  run(kpre, ckw, ckb, kn, true);
  run(vpre, cvw, cvb, vn, false);
}

// ---------------- gated delta recurrence scan --------------------------------
// One S-row per 16-lane DPP row (4 cols/lane); reductions are DPP VALU adds.
// Software pipeline: prefetch step t+1's k/q/v/a/b LDS operands into registers
// while computing step t — pulls LDS latency out of the serial S-chain
// (1 wave/SIMD => no TLP to hide it otherwise).
#define CHUNK 32
#define NCH (T_/CHUNK)

template<int CTRL>
__device__ __forceinline__ float dpp_add(float x) {
  int p = __builtin_amdgcn_update_dpp(0, __float_as_int(x), CTRL, 0xF, 0xF, false);
  return x + __int_as_float(p);
}
__device__ __forceinline__ float rowsum16(float x) {
  x = dpp_add<0xB1>(x);    // quad_perm xor1
  x = dpp_add<0x4E>(x);    // quad_perm xor2
  x = dpp_add<0x124>(x);   // row_ror:4
  x = dpp_add<0x128>(x);   // row_ror:8
  return x;
}

__global__ __launch_bounds__(256) void scan_kernel(const float* __restrict__ q,
    const float* __restrict__ k, const float* __restrict__ v,
    const float* __restrict__ alpha, const float* __restrict__ beta,
    float* __restrict__ o) {
  const int blk = blockIdx.x;
  const int bh = blk >> 2;          // 0..31
  const int rb = (blk & 3) * 16;    // row-block base within d=64
  const int b = bh >> 4, h = bh & 15;
  const int tid = threadIdx.x;
  const int lane = tid & 63;
  const int wave = tid >> 6;        // 0..3
  const int g = lane & 15;          // col group within row
  const int cb = g * 4;             // first col of this lane
  const int wrow = wave * 4 + (lane >> 4);  // 0..15: row within block

  __shared__ float ks[2][CHUNK][64];
  __shared__ float qs[2][CHUNK][64];
  __shared__ float vs[2][CHUNK][16];
  __shared__ float as_[2][CHUNK];
  __shared__ float bs_[2][CHUNK];
  __shared__ float os[CHUNK][16];

  const size_t hofs = (size_t)h * DH;
  const size_t btbase = (size_t)b * T_;

  const int e0 = tid * 4;
  const int tl0 = e0 >> 6, j0 = e0 & 63;
  const int tl1 = (1024 + e0) >> 6, j1 = j0;
  const int vtl = tid >> 2, vj = (tid & 3) * 4;

  float4 rk0, rk1, rq0, rq1, rv;
  float ra = 0.f, rbt = 0.f;

  auto issue = [&](int c) {
    size_t bt0 = btbase + (size_t)c * CHUNK;
    rk0 = *(const float4*)&k[(bt0 + tl0) * INNER_ + hofs + j0];
    rk1 = *(const float4*)&k[(bt0 + tl1) * INNER_ + hofs + j1];
    rq0 = *(const float4*)&q[(bt0 + tl0) * INNER_ + hofs + j0];
    rq1 = *(const float4*)&q[(bt0 + tl1) * INNER_ + hofs + j1];
    if (tid < 128) rv = *(const float4*)&v[(bt0 + vtl) * INNER_ + hofs + rb + vj];
    else if (tid < 160) ra = alpha[(bt0 + (tid - 128)) * H_ + h];
    else if (tid < 192) rbt = beta[(bt0 + (tid - 160)) * H_ + h];
  };
  auto commit = [&](int buf) {
    *(float4*)&ks[buf][tl0][j0] = rk0;
    *(float4*)&ks[buf][tl1][j1] = rk1;
    *(float4*)&qs[buf][tl0][j0] = rq0;
    *(float4*)&qs[buf][tl1][j1] = rq1;
    if (tid < 128) *(float4*)&vs[buf][vtl][vj] = rv;
    else if (tid < 160) as_[buf][tid - 128] = ra;
    else if (tid < 192) bs_[buf][tid - 160] = rbt;
  };

  float S0 = 0.f, S1 = 0.f, S2 = 0.f, S3 = 0.f;

  issue(0);
  commit(0);
  __syncthreads();
  int cur = 0;
  for (int c = 0; c < NCH; ++c) {
    if (c + 1 < NCH) issue(c + 1);   // global loads in flight during compute

    float4 kf = *(const float4*)&ks[cur][0][cb];
    float4 qf = *(const float4*)&qs[cur][0][cb];
    float vi = vs[cur][0][wrow];
    float a = as_[cur][0], bt = bs_[cur][0];
#pragma unroll 4
    for (int tl = 0; tl < CHUNK; ++tl) {
      // prefetch next step's operands (index wraps harmlessly at tl=31)
      const int tn = (tl + 1) & (CHUNK - 1);
      float4 kf2 = *(const float4*)&ks[cur][tn][cb];
      float4 qf2 = *(const float4*)&qs[cur][tn][cb];
      float vi2 = vs[cur][tn][wrow];
      float a2 = as_[cur][tn], bt2 = bs_[cur][tn];

      float sk = S0 * kf.x + S1 * kf.y + S2 * kf.z + S3 * kf.w;
      float sq = S0 * qf.x + S1 * qf.y + S2 * qf.z + S3 * qf.w;
      float kq = kf.x * qf.x + kf.y * qf.y + kf.z * qf.z + kf.w * qf.w;
      sk = rowsum16(sk);
      sq = rowsum16(sq);
      kq = rowsum16(kq);
      float ci = bt * (vi - a * sk);
      S0 = a * S0 + ci * kf.x;
      S1 = a * S1 + ci * kf.y;
      S2 = a * S2 + ci * kf.z;
      S3 = a * S3 + ci * kf.w;
      if (g == 0) os[tl][wrow] = a * sq + ci * kq;

      kf = kf2; qf = qf2; vi = vi2; a = a2; bt = bt2;
    }
    __syncthreads();
    {
      size_t bt0 = btbase + (size_t)c * CHUNK;
      if (tid < 128) {
        float4 ov = *(const float4*)&os[vtl][vj];
        *(float4*)&o[(bt0 + vtl) * INNER_ + hofs + rb + vj] = ov;
      }
    }
    if (c + 1 < NCH) commit(cur ^ 1);
    __syncthreads();
    cur ^= 1;
  }
}

// ---------------- RMS norm over INNER, * (1+gamma) * gate, -> bf16 -----------
__global__ __launch_bounds__(256) void rmsgate_kernel(const float* __restrict__ o,
    const float* __restrict__ gate, const float* __restrict__ gamma,
    __hip_bfloat16* __restrict__ outn) {
  const int bt = blockIdx.x;
  const int tid = threadIdx.x;
  const size_t base = (size_t)bt * INNER_ + tid * 4;
  float4 ov = *(const float4*)(o + base);
  float ss = ov.x*ov.x + ov.y*ov.y + ov.z*ov.z + ov.w*ov.w;
#pragma unroll
  for (int m = 1; m <= 32; m <<= 1) ss += __shfl_xor(ss, m);
  __shared__ float red[4];
  if ((tid & 63) == 0) red[tid >> 6] = ss;
  __syncthreads();
  float tot = red[0] + red[1] + red[2] + red[3];
  float rms = sqrtf(tot * (1.f / (float)INNER_) + 1e-6f);
  float inv = 1.f / rms;
  float4 gm = *(const float4*)(gamma + tid * 4);
  float4 gt = *(const float4*)(gate + base);
  __hip_bfloat16 t[4];
  t[0] = __float2bfloat16(ov.x * inv * (1.f + gm.x) * gt.x);
  t[1] = __float2bfloat16(ov.y * inv * (1.f + gm.y) * gt.y);
  t[2] = __float2bfloat16(ov.z * inv * (1.f + gm.z) * gt.z);
  t[3] = __float2bfloat16(ov.w * inv * (1.f + gm.w) * gt.w);
  *(uint2*)(outn + base) = *(uint2*)t;
}

// ---------------- launch -----------------------------------------------------
extern "C" void kernel_launch(void* const* d_in, const int* in_sizes, int n_in,
                              void* d_out, int out_size, void* d_ws, size_t ws_size,
                              hipStream_t stream) {
  const float* x   = (const float*)d_in[0];
  const float* Wq  = (const float*)d_in[1];
  const float* Wk  = (const float*)d_in[2];
  const float* Wv  = (const float*)d_in[3];
  const float* Wa  = (const float*)d_in[4];
  const float* ba  = (const float*)d_in[5];
  const float* Wb  = (const float*)d_in[6];
  const float* bb  = (const float*)d_in[7];
  const float* Wg  = (const float*)d_in[8];
  const float* Wo  = (const float*)d_in[9];
  const float* cqw = (const float*)d_in[10];
  const float* cqb = (const float*)d_in[11];
  const float* ckw = (const float*)d_in[12];
  const float* ckb = (const float*)d_in[13];
  const float* cvw = (const float*)d_in[14];
  const float* cvb = (const float*)d_in[15];
  const float* gamma = (const float*)d_in[16];

  float* ws = (float*)d_ws;
  const size_t N1 = (size_t)BT * INNER_;
  float* qpre = ws;
  float* kpre = ws + N1;
  float* vpre = ws + 2 * N1;
  float* gate = ws + 3 * N1;
  float* qn   = ws + 4 * N1;
  float* kn   = ws + 5 * N1;
  float* vn   = ws + 6 * N1;
  float* alpha = ws + 7 * N1;
  float* beta  = alpha + (size_t)BT * H_;
  __hip_bfloat16* wt0 = (__hip_bfloat16*)(beta + (size_t)BT * H_);
  __hip_bfloat16* Wqt = wt0;                       // [INNER][D] bf16
  __hip_bfloat16* Wkt = wt0 + (size_t)D_ * INNER_;
  __hip_bfloat16* Wvt = Wkt + (size_t)D_ * INNER_;
  __hip_bfloat16* Wgt = Wvt + (size_t)D_ * INNER_;
  __hip_bfloat16* Wot = Wgt + (size_t)D_ * INNER_;
  __hip_bfloat16* xb  = (__hip_bfloat16*)vn;       // xb dead before convnorm writes vn
  __hip_bfloat16* nrmb = (__hip_bfloat16*)kpre;    // kpre dead after convnorm
  float* obuf = qpre;                              // qpre dead after convnorm
  float* outp = (float*)d_out;

  // 1) conversions
  cvt_bf16_kernel<<<(BT * D_ / 4 + 255) / 256, 256, 0, stream>>>(x, xb, BT * D_ / 4);
  dim3 tgrid(INNER_ / 32, D_ / 32);
  transpose_cvt_kernel<<<tgrid, 256, 0, stream>>>(Wq, Wqt, D_, INNER_);
  transpose_cvt_kernel<<<tgrid, 256, 0, stream>>>(Wk, Wkt, D_, INNER_);
  transpose_cvt_kernel<<<tgrid, 256, 0, stream>>>(Wv, Wvt, D_, INNER_);
  transpose_cvt_kernel<<<tgrid, 256, 0, stream>>>(Wg, Wgt, D_, INNER_);
  transpose_cvt_kernel<<<dim3(D_ / 32, INNER_ / 32), 256, 0, stream>>>(Wo, Wot, INNER_, D_);

  // 2) projection GEMMs (bf16 MFMA, fp32 out)
  dim3 ggrid(INNER_ / 128, BT / 128);
  gemm_bf16<<<ggrid, 256, 0, stream>>>(xb, Wqt, qpre, BT, INNER_, D_, 0);
  gemm_bf16<<<ggrid, 256, 0, stream>>>(xb, Wkt, kpre, BT, INNER_, D_, 0);
  gemm_bf16<<<ggrid, 256, 0, stream>>>(xb, Wvt, vpre, BT, INNER_, D_, 0);
  gemm_bf16<<<ggrid, 256, 0, stream>>>(xb, Wgt, gate, BT, INNER_, D_, 1);

  alphabeta_kernel<<<BT, 64, 0, stream>>>(x, Wa, ba, Wb, bb, alpha, beta);
  convnorm_kernel<<<BT, 256, 0, stream>>>(qpre, kpre, vpre, cqw, cqb, ckw, ckb,
                                          cvw, cvb, qn, kn, vn);
  scan_kernel<<<B_ * H_ * 4, 256, 0, stream>>>(qn, kn, vn, alpha, beta, obuf);
  rmsgate_kernel<<<BT, 256, 0, stream>>>(obuf, gate, gamma, nrmb);
  gemm_bf16<<<dim3(D_ / 128, BT / 128), 256, 0, stream>>>(nrmb, Wot, outp, BT, D_, INNER_, 0);
}

// Round 4
// 690.880 us; speedup vs baseline: 2.4230x; 1.0025x over previous
//
#include <hip/hip_runtime.h>
#include <hip/hip_bf16.h>
#include <cmath>

#define B_ 2
#define T_ 2048
#define D_ 1024
#define H_ 16
#define DH 64
#define INNER_ 1024
#define BT (B_*T_)

typedef __attribute__((ext_vector_type(8))) __bf16 bf16x8;
typedef __attribute__((ext_vector_type(4))) float f32x4;
typedef const __attribute__((address_space(1))) unsigned gas_u32;
typedef __attribute__((address_space(3))) unsigned las_u32;

__device__ __forceinline__ void async16(const void* g, void* l) {
  __builtin_amdgcn_global_load_lds((gas_u32*)g, (las_u32*)l, 16, 0, 0);
}

// ---------------- convert f32 -> bf16 (elementwise) --------------------------
__global__ __launch_bounds__(256) void cvt_bf16_kernel(const float* __restrict__ in,
                                                       __hip_bfloat16* __restrict__ out,
                                                       int n4) {
  int i = blockIdx.x * 256 + threadIdx.x;
  if (i >= n4) return;
  float4 v = *(const float4*)(in + (size_t)i * 4);
  __hip_bfloat16 t[4];
  t[0] = __float2bfloat16(v.x); t[1] = __float2bfloat16(v.y);
  t[2] = __float2bfloat16(v.z); t[3] = __float2bfloat16(v.w);
  *(uint2*)(out + (size_t)i * 4) = *(uint2*)t;
}

// ---------------- transpose + convert: in [R][C] f32 -> out [C][R] bf16 ------
__global__ __launch_bounds__(256) void transpose_cvt_kernel(const float* __restrict__ in,
                                                            __hip_bfloat16* __restrict__ out,
                                                            int R, int C) {
  __shared__ float tile[32][33];
  const int bc = blockIdx.x * 32, br = blockIdx.y * 32;
  const int tx = threadIdx.x & 31, ty = threadIdx.x >> 5;  // 32 x 8
#pragma unroll
  for (int i = 0; i < 32; i += 8)
    tile[ty + i][tx] = in[(size_t)(br + ty + i) * C + bc + tx];
  __syncthreads();
#pragma unroll
  for (int i = 0; i < 32; i += 8)
    out[(size_t)(bc + ty + i) * R + br + tx] = __float2bfloat16(tile[tx][ty + i]);
}

// ---------------- bf16 MFMA GEMM: C[M,N] f32 = A[M,K]bf16 @ Bt[N,K]bf16^T ----
// act: 0 = none, 1 = silu, 2 = split4 epilogue (cols [q|k|v|g], silu on g,
//      outputs 4 contiguous [M][1024] buffers starting at C).
__global__ __launch_bounds__(256) void gemm_bf16(const __hip_bfloat16* __restrict__ A,
                                                 const __hip_bfloat16* __restrict__ Bt,
                                                 float* __restrict__ C,
                                                 int M, int N, int K, int act) {
  __shared__ __hip_bfloat16 As[128 * 32];
  __shared__ __hip_bfloat16 Bs[128 * 32];
  const int tid = threadIdx.x;
  const int lane = tid & 63, wave = tid >> 6;
  const int wr = wave >> 1, wc = wave & 1;
  const int m0 = blockIdx.y * 128, n0 = blockIdx.x * 128;
  const int srow = tid >> 2, skoff = (tid & 3) * 8;  // staging: 16B per thread
  const int l15 = lane & 15, lg = lane >> 4;

  f32x4 acc[4][4];
#pragma unroll
  for (int m = 0; m < 4; ++m)
#pragma unroll
    for (int n = 0; n < 4; ++n) acc[m][n] = (f32x4)0.f;

  char* asB = (char*)As;
  char* bsB = (char*)Bs;
  const int ldsw = wave * 1024;  // wave-uniform LDS byte base (lane*16 auto)

  for (int k0 = 0; k0 < K; k0 += 32) {
    const __hip_bfloat16* ga0 = A + (size_t)(m0 + srow) * K + k0 + skoff;
    const __hip_bfloat16* ga1 = A + (size_t)(m0 + 64 + srow) * K + k0 + skoff;
    const __hip_bfloat16* gb0 = Bt + (size_t)(n0 + srow) * K + k0 + skoff;
    const __hip_bfloat16* gb1 = Bt + (size_t)(n0 + 64 + srow) * K + k0 + skoff;
    async16(ga0, asB + ldsw);
    async16(ga1, asB + 4096 + ldsw);
    async16(gb0, bsB + ldsw);
    async16(gb1, bsB + 4096 + ldsw);
    __syncthreads();  // drains vmcnt before ds_read

    bf16x8 af[4], bfg[4];
#pragma unroll
    for (int m = 0; m < 4; ++m)
      af[m] = *(const bf16x8*)(asB + ((wr * 64 + m * 16 + l15) * 32 + lg * 8) * 2);
#pragma unroll
    for (int n = 0; n < 4; ++n)
      bfg[n] = *(const bf16x8*)(bsB + ((wc * 64 + n * 16 + l15) * 32 + lg * 8) * 2);
#pragma unroll
    for (int m = 0; m < 4; ++m)
#pragma unroll
      for (int n = 0; n < 4; ++n)
        acc[m][n] = __builtin_amdgcn_mfma_f32_16x16x32_bf16(af[m], bfg[n], acc[m][n], 0, 0, 0);
    __syncthreads();
  }

#pragma unroll
  for (int m = 0; m < 4; ++m) {
    const int rbase = m0 + wr * 64 + m * 16 + lg * 4;
#pragma unroll
    for (int n = 0; n < 4; ++n) {
      const int col = n0 + wc * 64 + n * 16 + l15;
      if (act == 2) {
        const int which = col >> 10;
        const int ncol = col & 1023;
        float* dst = C + (size_t)which * ((size_t)BT * INNER_) +
                     (size_t)rbase * 1024 + ncol;
#pragma unroll
        for (int r = 0; r < 4; ++r) {
          float vv = acc[m][n][r];
          if (which == 3) vv = vv / (1.f + expf(-vv));  // silu on gate block
          dst[(size_t)r * 1024] = vv;
        }
      } else {
#pragma unroll
        for (int r = 0; r < 4; ++r) {
          float vv = acc[m][n][r];
          if (act == 1) vv = vv / (1.f + expf(-vv));
          C[(size_t)(rbase + r) * N + col] = vv;
        }
      }
    }
  }
}

// ---------------- alpha/beta: sigmoid(x@Wa + ba), sigmoid(x@Wb + bb) ----------
__global__ __launch_bounds__(64) void alphabeta_kernel(const float* __restrict__ x,
    const float* __restrict__ Wa, const float* __restrict__ ba,
    const float* __restrict__ Wb, const float* __restrict__ bb,
    float* __restrict__ alpha, float* __restrict__ beta) {
  const int bt = blockIdx.x;
  const int tid = threadIdx.x;  // 64
  __shared__ float xs[D_];
  for (int i = tid; i < D_; i += 64) xs[i] = x[(size_t)bt * D_ + i];
  __syncthreads();
  const int h = tid & 15;
  const int grp = tid >> 4;  // 0..3
  float sa = 0.f, sb = 0.f;
  const int k0 = grp * 256;
  for (int kk = k0; kk < k0 + 256; ++kk) {
    float xv = xs[kk];
    sa += xv * Wa[kk * H_ + h];
    sb += xv * Wb[kk * H_ + h];
  }
  sa += __shfl_xor(sa, 16); sa += __shfl_xor(sa, 32);
  sb += __shfl_xor(sb, 16); sb += __shfl_xor(sb, 32);
  if (grp == 0) {
    alpha[(size_t)bt * H_ + h] = 1.f / (1.f + expf(-(sa + ba[h])));
    beta [(size_t)bt * H_ + h] = 1.f / (1.f + expf(-(sb + bb[h])));
  }
}

// ---------------- depthwise causal conv (K=4) + silu + optional l2norm -------
__global__ __launch_bounds__(256) void convnorm_kernel(
    const float* __restrict__ qpre, const float* __restrict__ kpre, const float* __restrict__ vpre,
    const float* __restrict__ cqw, const float* __restrict__ cqb,
    const float* __restrict__ ckw, const float* __restrict__ ckb,
    const float* __restrict__ cvw, const float* __restrict__ cvb,
    float* __restrict__ qn, float* __restrict__ kn, float* __restrict__ vn) {
  const int bt = blockIdx.x;
  const int t = bt & (T_ - 1);
  const int tid = threadIdx.x;
  const int c = tid * 4;

  auto run = [&](const float* __restrict__ pre, const float* __restrict__ w,
                 const float* __restrict__ bias, float* __restrict__ out, bool norm) {
    float r[4];
    float4 bv = *(const float4*)(bias + c);
    r[0] = bv.x; r[1] = bv.y; r[2] = bv.z; r[3] = bv.w;
    float wl[4][4];
#pragma unroll
    for (int i = 0; i < 4; ++i) {
      float4 wv = *(const float4*)(w + (size_t)(c + i) * 4);
      wl[i][0] = wv.x; wl[i][1] = wv.y; wl[i][2] = wv.z; wl[i][3] = wv.w;
    }
#pragma unroll
    for (int kk = 0; kk < 4; ++kk) {
      int tt = t - 3 + kk;
      if (tt >= 0) {
        float4 xv = *(const float4*)(pre + (size_t)(bt - 3 + kk) * INNER_ + c);
        float xa[4] = {xv.x, xv.y, xv.z, xv.w};
#pragma unroll
        for (int i = 0; i < 4; ++i) r[i] += xa[i] * wl[i][kk];
      }
    }
#pragma unroll
    for (int i = 0; i < 4; ++i) r[i] = r[i] / (1.f + expf(-r[i]));  // silu
    if (norm) {
      float ss = r[0]*r[0] + r[1]*r[1] + r[2]*r[2] + r[3]*r[3];
      ss += __shfl_xor(ss, 1); ss += __shfl_xor(ss, 2);
      ss += __shfl_xor(ss, 4); ss += __shfl_xor(ss, 8);
      float n = sqrtf(ss);
      float sc = 1.f / fmaxf(n, 1e-12f);
#pragma unroll
      for (int i = 0; i < 4; ++i) r[i] *= sc;
    }
    float4 ov = {r[0], r[1], r[2], r[3]};
    *(float4*)(out + (size_t)bt * INNER_ + c) = ov;
  };

  run(qpre, cqw, cqb, qn, true);
  run(kpre, ckw, ckb, kn, true);
  run(vpre, cvw, cvb, vn, false);
}

// ---------------- gated delta recurrence scan --------------------------------
// Wave-autonomous, register-resident: each 64-thread block owns 4 S-rows of
// one (b,h). No LDS, no barriers. Operands loaded global->reg, double-buffered
// in 4-step sub-chunks; sched_barrier pins prefetch before compute. Reductions
// are DPP VALU adds (16-lane rows, 4 cols/lane).
#define NS 4

template<int CTRL>
__device__ __forceinline__ float dpp_add(float x) {
  int p = __builtin_amdgcn_update_dpp(0, __float_as_int(x), CTRL, 0xF, 0xF, false);
  return x + __int_as_float(p);
}
__device__ __forceinline__ float rowsum16(float x) {
  x = dpp_add<0xB1>(x);    // quad_perm xor1
  x = dpp_add<0x4E>(x);    // quad_perm xor2
  x = dpp_add<0x124>(x);   // row_ror:4
  x = dpp_add<0x128>(x);   // row_ror:8
  return x;
}

__global__ __launch_bounds__(64) void scan_kernel(const float* __restrict__ q,
    const float* __restrict__ k, const float* __restrict__ v,
    const float* __restrict__ alpha, const float* __restrict__ beta,
    float* __restrict__ o) {
  // XCD-swizzle decode: co-locate the 16 row-group blocks of each (b,h) on
  // one XCD (dispatch round-robins blockIdx % 8 across XCDs).
  const int i = blockIdx.x;            // 0..511
  const int j = i >> 3;                // 0..63
  const int bh = (j >> 4) * 8 + (i & 7);  // 0..31
  const int rg = j & 15;               // row-group of 4 rows
  const int b = bh >> 4, h = bh & 15;
  const int lane = threadIdx.x;
  const int g = lane & 15;             // col group
  const int rloc = lane >> 4;          // 0..3
  const int row = rg * 4 + rloc;       // 0..63
  const int cb = g * 4;

  const size_t btbase = (size_t)b * T_;
  const size_t hofs = (size_t)h * DH;

  float4 kA[NS], qA[NS]; float vA[NS], aA[NS], bA[NS];
  float4 kB[NS], qB[NS]; float vB[NS], aB[NS], bB[NS];
  float S0 = 0.f, S1 = 0.f, S2 = 0.f, S3 = 0.f;

#define ISSUE(c, kb, qb, vb, ab, bb2)                                   \
  do {                                                                  \
    size_t bt0_ = btbase + (size_t)(c) * NS;                            \
    _Pragma("unroll")                                                   \
    for (int ii = 0; ii < NS; ++ii) {                                   \
      size_t off_ = (bt0_ + ii) * INNER_ + hofs;                        \
      kb[ii] = *(const float4*)(k + off_ + cb);                         \
      qb[ii] = *(const float4*)(q + off_ + cb);                         \
      vb[ii] = v[off_ + row];                                           \
      ab[ii] = alpha[(bt0_ + ii) * H_ + h];                             \
      bb2[ii] = beta[(bt0_ + ii) * H_ + h];                             \
    }                                                                   \
    __builtin_amdgcn_sched_barrier(0);                                  \
  } while (0)

#define COMPUTE(c, kb, qb, vb, ab, bb2)                                 \
  do {                                                                  \
    size_t bt0_ = btbase + (size_t)(c) * NS;                            \
    _Pragma("unroll")                                                   \
    for (int ii = 0; ii < NS; ++ii) {                                   \
      float4 kf = kb[ii], qf = qb[ii];                                  \
      float a = ab[ii], bt = bb2[ii], vi = vb[ii];                      \
      float sk = S0 * kf.x + S1 * kf.y + S2 * kf.z + S3 * kf.w;         \
      float sq = S0 * qf.x + S1 * qf.y + S2 * qf.z + S3 * qf.w;         \
      float kq = kf.x * qf.x + kf.y * qf.y + kf.z * qf.z + kf.w * qf.w; \
      sk = rowsum16(sk);                                                \
      sq = rowsum16(sq);                                                \
      kq = rowsum16(kq);                                                \
      float ci = bt * (vi - a * sk);                                    \
      S0 = a * S0 + ci * kf.x;                                          \
      S1 = a * S1 + ci * kf.y;                                          \
      S2 = a * S2 + ci * kf.z;                                          \
      S3 = a * S3 + ci * kf.w;                                          \
      if (g == 0) o[(bt0_ + ii) * INNER_ + hofs + row] = a * sq + ci * kq; \
    }                                                                   \
  } while (0)

  ISSUE(0, kA, qA, vA, aA, bA);
  const int NCHUNK = T_ / NS;  // 512
  for (int c = 0; c < NCHUNK; c += 2) {
    if (c + 1 < NCHUNK) ISSUE(c + 1, kB, qB, vB, aB, bB);
    COMPUTE(c, kA, qA, vA, aA, bA);
    if (c + 2 < NCHUNK) ISSUE(c + 2, kA, qA, vA, aA, bA);
    COMPUTE(c + 1, kB, qB, vB, aB, bB);
  }
#undef ISSUE
#undef COMPUTE
}

// ---------------- RMS norm over INNER, * (1+gamma) * gate, -> bf16 -----------
__global__ __launch_bounds__(256) void rmsgate_kernel(const float* __restrict__ o,
    const float* __restrict__ gate, const float* __restrict__ gamma,
    __hip_bfloat16* __restrict__ outn) {
  const int bt = blockIdx.x;
  const int tid = threadIdx.x;
  const size_t base = (size_t)bt * INNER_ + tid * 4;
  float4 ov = *(const float4*)(o + base);
  float ss = ov.x*ov.x + ov.y*ov.y + ov.z*ov.z + ov.w*ov.w;
#pragma unroll
  for (int m = 1; m <= 32; m <<= 1) ss += __shfl_xor(ss, m);
  __shared__ float red[4];
  if ((tid & 63) == 0) red[tid >> 6] = ss;
  __syncthreads();
  float tot = red[0] + red[1] + red[2] + red[3];
  float rms = sqrtf(tot * (1.f / (float)INNER_) + 1e-6f);
  float inv = 1.f / rms;
  float4 gm = *(const float4*)(gamma + tid * 4);
  float4 gt = *(const float4*)(gate + base);
  __hip_bfloat16 t[4];
  t[0] = __float2bfloat16(ov.x * inv * (1.f + gm.x) * gt.x);
  t[1] = __float2bfloat16(ov.y * inv * (1.f + gm.y) * gt.y);
  t[2] = __float2bfloat16(ov.z * inv * (1.f + gm.z) * gt.z);
  t[3] = __float2bfloat16(ov.w * inv * (1.f + gm.w) * gt.w);
  *(uint2*)(outn + base) = *(uint2*)t;
}

// ---------------- launch -----------------------------------------------------
extern "C" void kernel_launch(void* const* d_in, const int* in_sizes, int n_in,
                              void* d_out, int out_size, void* d_ws, size_t ws_size,
                              hipStream_t stream) {
  const float* x   = (const float*)d_in[0];
  const float* Wq  = (const float*)d_in[1];
  const float* Wk  = (const float*)d_in[2];
  const float* Wv  = (const float*)d_in[3];
  const float* Wa  = (const float*)d_in[4];
  const float* ba  = (const float*)d_in[5];
  const float* Wb  = (const float*)d_in[6];
  const float* bb  = (const float*)d_in[7];
  const float* Wg  = (const float*)d_in[8];
  const float* Wo  = (const float*)d_in[9];
  const float* cqw = (const float*)d_in[10];
  const float* cqb = (const float*)d_in[11];
  const float* ckw = (const float*)d_in[12];
  const float* ckb = (const float*)d_in[13];
  const float* cvw = (const float*)d_in[14];
  const float* cvb = (const float*)d_in[15];
  const float* gamma = (const float*)d_in[16];

  float* ws = (float*)d_ws;
  const size_t N1 = (size_t)BT * INNER_;
  float* qpre = ws;          // fused GEMM writes qpre,kpre,vpre,gate contiguously
  float* kpre = ws + N1;
  float* vpre = ws + 2 * N1;
  float* gate = ws + 3 * N1;
  float* qn   = ws + 4 * N1;
  float* kn   = ws + 5 * N1;
  float* vn   = ws + 6 * N1;
  float* alpha = ws + 7 * N1;
  float* beta  = alpha + (size_t)BT * H_;
  __hip_bfloat16* wt0 = (__hip_bfloat16*)(beta + (size_t)BT * H_);
  __hip_bfloat16* Wqt = wt0;                       // [INNER][D] bf16, x4 contiguous
  __hip_bfloat16* Wkt = wt0 + (size_t)D_ * INNER_;
  __hip_bfloat16* Wvt = Wkt + (size_t)D_ * INNER_;
  __hip_bfloat16* Wgt = Wvt + (size_t)D_ * INNER_;
  __hip_bfloat16* Wot = Wgt + (size_t)D_ * INNER_;
  __hip_bfloat16* xb  = (__hip_bfloat16*)vn;       // xb dead before convnorm writes vn
  __hip_bfloat16* nrmb = (__hip_bfloat16*)kpre;    // kpre dead after convnorm
  float* obuf = qpre;                              // qpre dead after convnorm
  float* outp = (float*)d_out;

  // 1) conversions
  cvt_bf16_kernel<<<(BT * D_ / 4 + 255) / 256, 256, 0, stream>>>(x, xb, BT * D_ / 4);
  dim3 tgrid(INNER_ / 32, D_ / 32);
  transpose_cvt_kernel<<<tgrid, 256, 0, stream>>>(Wq, Wqt, D_, INNER_);
  transpose_cvt_kernel<<<tgrid, 256, 0, stream>>>(Wk, Wkt, D_, INNER_);
  transpose_cvt_kernel<<<tgrid, 256, 0, stream>>>(Wv, Wvt, D_, INNER_);
  transpose_cvt_kernel<<<tgrid, 256, 0, stream>>>(Wg, Wgt, D_, INNER_);
  transpose_cvt_kernel<<<dim3(D_ / 32, INNER_ / 32), 256, 0, stream>>>(Wo, Wot, INNER_, D_);

  // 2) fused projection GEMM: N=4096 over [Wq|Wk|Wv|Wg], split4 epilogue
  gemm_bf16<<<dim3(4 * INNER_ / 128, BT / 128), 256, 0, stream>>>(
      xb, wt0, qpre, BT, 4 * INNER_, D_, 2);

  alphabeta_kernel<<<BT, 64, 0, stream>>>(x, Wa, ba, Wb, bb, alpha, beta);
  convnorm_kernel<<<BT, 256, 0, stream>>>(qpre, kpre, vpre, cqw, cqb, ckw, ckb,
                                          cvw, cvb, qn, kn, vn);
  scan_kernel<<<B_ * H_ * 16, 64, 0, stream>>>(qn, kn, vn, alpha, beta, obuf);
  rmsgate_kernel<<<BT, 256, 0, stream>>>(obuf, gate, gamma, nrmb);
  gemm_bf16<<<dim3(D_ / 128, BT / 128), 256, 0, stream>>>(nrmb, Wot, outp, BT, D_, INNER_, 0);
}

// Round 5
// 484.757 us; speedup vs baseline: 3.4533x; 1.4252x over previous
//
#include <hip/hip_runtime.h>
#include <hip/hip_bf16.h>
#include <cmath>

#define B_ 2
#define T_ 2048
#define D_ 1024
#define H_ 16
#define DH 64
#define INNER_ 1024
#define BT (B_*T_)
#define NCH 32              // chunks per (b,h), chunk length 64
#define NU (B_*H_*NCH)      // 1024 precompute units

typedef __attribute__((ext_vector_type(8))) __bf16 bf16x8;
typedef __attribute__((ext_vector_type(4))) float f32x4;
typedef const __attribute__((address_space(1))) unsigned gas_u32;
typedef __attribute__((address_space(3))) unsigned las_u32;

__device__ __forceinline__ void async16(const void* g, void* l) {
  __builtin_amdgcn_global_load_lds((gas_u32*)g, (las_u32*)l, 16, 0, 0);
}

__device__ __forceinline__ ushort bfr(float x) {
  __hip_bfloat16 t = __float2bfloat16(x);
  return *(ushort*)&t;
}
__device__ __forceinline__ void st_bf4(__hip_bfloat16* p, float a, float b, float c, float d) {
  ushort4 u; u.x = bfr(a); u.y = bfr(b); u.z = bfr(c); u.w = bfr(d);
  *(ushort4*)p = u;
}

// ---------------- convert f32 -> bf16 (elementwise) --------------------------
__global__ __launch_bounds__(256) void cvt_bf16_kernel(const float* __restrict__ in,
                                                       __hip_bfloat16* __restrict__ out,
                                                       int n4) {
  int i = blockIdx.x * 256 + threadIdx.x;
  if (i >= n4) return;
  float4 v = *(const float4*)(in + (size_t)i * 4);
  __hip_bfloat16 t[4];
  t[0] = __float2bfloat16(v.x); t[1] = __float2bfloat16(v.y);
  t[2] = __float2bfloat16(v.z); t[3] = __float2bfloat16(v.w);
  *(uint2*)(out + (size_t)i * 4) = *(uint2*)t;
}

// ---------------- transpose + convert: in [R][C] f32 -> out [C][R] bf16 ------
__global__ __launch_bounds__(256) void transpose_cvt_kernel(const float* __restrict__ in,
                                                            __hip_bfloat16* __restrict__ out,
                                                            int R, int C) {
  __shared__ float tile[32][33];
  const int bc = blockIdx.x * 32, br = blockIdx.y * 32;
  const int tx = threadIdx.x & 31, ty = threadIdx.x >> 5;  // 32 x 8
#pragma unroll
  for (int i = 0; i < 32; i += 8)
    tile[ty + i][tx] = in[(size_t)(br + ty + i) * C + bc + tx];
  __syncthreads();
#pragma unroll
  for (int i = 0; i < 32; i += 8)
    out[(size_t)(bc + ty + i) * R + br + tx] = __float2bfloat16(tile[tx][ty + i]);
}

// ---------------- bf16 MFMA GEMM: C[M,N] f32 = A[M,K]bf16 @ Bt[N,K]bf16^T ----
// act: 0 = none, 1 = silu, 2 = split4 epilogue (cols [q|k|v|g], silu on g).
__global__ __launch_bounds__(256) void gemm_bf16(const __hip_bfloat16* __restrict__ A,
                                                 const __hip_bfloat16* __restrict__ Bt,
                                                 float* __restrict__ C,
                                                 int M, int N, int K, int act) {
  __shared__ __hip_bfloat16 As[128 * 32];
  __shared__ __hip_bfloat16 Bs[128 * 32];
  const int tid = threadIdx.x;
  const int lane = tid & 63, wave = tid >> 6;
  const int wr = wave >> 1, wc = wave & 1;
  const int m0 = blockIdx.y * 128, n0 = blockIdx.x * 128;
  const int srow = tid >> 2, skoff = (tid & 3) * 8;
  const int l15 = lane & 15, lg = lane >> 4;

  f32x4 acc[4][4];
#pragma unroll
  for (int m = 0; m < 4; ++m)
#pragma unroll
    for (int n = 0; n < 4; ++n) acc[m][n] = (f32x4)0.f;

  char* asB = (char*)As;
  char* bsB = (char*)Bs;
  const int ldsw = wave * 1024;

  for (int k0 = 0; k0 < K; k0 += 32) {
    const __hip_bfloat16* ga0 = A + (size_t)(m0 + srow) * K + k0 + skoff;
    const __hip_bfloat16* ga1 = A + (size_t)(m0 + 64 + srow) * K + k0 + skoff;
    const __hip_bfloat16* gb0 = Bt + (size_t)(n0 + srow) * K + k0 + skoff;
    const __hip_bfloat16* gb1 = Bt + (size_t)(n0 + 64 + srow) * K + k0 + skoff;
    async16(ga0, asB + ldsw);
    async16(ga1, asB + 4096 + ldsw);
    async16(gb0, bsB + ldsw);
    async16(gb1, bsB + 4096 + ldsw);
    __syncthreads();

    bf16x8 af[4], bfg[4];
#pragma unroll
    for (int m = 0; m < 4; ++m)
      af[m] = *(const bf16x8*)(asB + ((wr * 64 + m * 16 + l15) * 32 + lg * 8) * 2);
#pragma unroll
    for (int n = 0; n < 4; ++n)
      bfg[n] = *(const bf16x8*)(bsB + ((wc * 64 + n * 16 + l15) * 32 + lg * 8) * 2);
#pragma unroll
    for (int m = 0; m < 4; ++m)
#pragma unroll
      for (int n = 0; n < 4; ++n)
        acc[m][n] = __builtin_amdgcn_mfma_f32_16x16x32_bf16(af[m], bfg[n], acc[m][n], 0, 0, 0);
    __syncthreads();
  }

#pragma unroll
  for (int m = 0; m < 4; ++m) {
    const int rbase = m0 + wr * 64 + m * 16 + lg * 4;
#pragma unroll
    for (int n = 0; n < 4; ++n) {
      const int col = n0 + wc * 64 + n * 16 + l15;
      if (act == 2) {
        const int which = col >> 10;
        const int ncol = col & 1023;
        float* dst = C + (size_t)which * ((size_t)BT * INNER_) +
                     (size_t)rbase * 1024 + ncol;
#pragma unroll
        for (int r = 0; r < 4; ++r) {
          float vv = acc[m][n][r];
          if (which == 3) vv = vv / (1.f + expf(-vv));
          dst[(size_t)r * 1024] = vv;
        }
      } else {
#pragma unroll
        for (int r = 0; r < 4; ++r) {
          float vv = acc[m][n][r];
          if (act == 1) vv = vv / (1.f + expf(-vv));
          C[(size_t)(rbase + r) * N + col] = vv;
        }
      }
    }
  }
}

// ---------------- alpha/beta: sigmoid(x@Wa + ba), sigmoid(x@Wb + bb) ----------
__global__ __launch_bounds__(64) void alphabeta_kernel(const float* __restrict__ x,
    const float* __restrict__ Wa, const float* __restrict__ ba,
    const float* __restrict__ Wb, const float* __restrict__ bb,
    float* __restrict__ alpha, float* __restrict__ beta) {
  const int bt = blockIdx.x;
  const int tid = threadIdx.x;
  __shared__ float xs[D_];
  for (int i = tid; i < D_; i += 64) xs[i] = x[(size_t)bt * D_ + i];
  __syncthreads();
  const int h = tid & 15;
  const int grp = tid >> 4;
  float sa = 0.f, sb = 0.f;
  const int k0 = grp * 256;
  for (int kk = k0; kk < k0 + 256; ++kk) {
    float xv = xs[kk];
    sa += xv * Wa[kk * H_ + h];
    sb += xv * Wb[kk * H_ + h];
  }
  sa += __shfl_xor(sa, 16); sa += __shfl_xor(sa, 32);
  sb += __shfl_xor(sb, 16); sb += __shfl_xor(sb, 32);
  if (grp == 0) {
    alpha[(size_t)bt * H_ + h] = 1.f / (1.f + expf(-(sa + ba[h])));
    beta [(size_t)bt * H_ + h] = 1.f / (1.f + expf(-(sb + bb[h])));
  }
}

// ---------------- depthwise causal conv (K=4) + silu + optional l2norm -------
__global__ __launch_bounds__(256) void convnorm_kernel(
    const float* __restrict__ qpre, const float* __restrict__ kpre, const float* __restrict__ vpre,
    const float* __restrict__ cqw, const float* __restrict__ cqb,
    const float* __restrict__ ckw, const float* __restrict__ ckb,
    const float* __restrict__ cvw, const float* __restrict__ cvb,
    float* __restrict__ qn, float* __restrict__ kn, float* __restrict__ vn) {
  const int bt = blockIdx.x;
  const int t = bt & (T_ - 1);
  const int tid = threadIdx.x;
  const int c = tid * 4;

  auto run = [&](const float* __restrict__ pre, const float* __restrict__ w,
                 const float* __restrict__ bias, float* __restrict__ out, bool norm) {
    float r[4];
    float4 bv = *(const float4*)(bias + c);
    r[0] = bv.x; r[1] = bv.y; r[2] = bv.z; r[3] = bv.w;
    float wl[4][4];
#pragma unroll
    for (int i = 0; i < 4; ++i) {
      float4 wv = *(const float4*)(w + (size_t)(c + i) * 4);
      wl[i][0] = wv.x; wl[i][1] = wv.y; wl[i][2] = wv.z; wl[i][3] = wv.w;
    }
#pragma unroll
    for (int kk = 0; kk < 4; ++kk) {
      int tt = t - 3 + kk;
      if (tt >= 0) {
        float4 xv = *(const float4*)(pre + (size_t)(bt - 3 + kk) * INNER_ + c);
        float xa[4] = {xv.x, xv.y, xv.z, xv.w};
#pragma unroll
        for (int i = 0; i < 4; ++i) r[i] += xa[i] * wl[i][kk];
      }
    }
#pragma unroll
    for (int i = 0; i < 4; ++i) r[i] = r[i] / (1.f + expf(-r[i]));
    if (norm) {
      float ss = r[0]*r[0] + r[1]*r[1] + r[2]*r[2] + r[3]*r[3];
      ss += __shfl_xor(ss, 1); ss += __shfl_xor(ss, 2);
      ss += __shfl_xor(ss, 4); ss += __shfl_xor(ss, 8);
      float n = sqrtf(ss);
      float sc = 1.f / fmaxf(n, 1e-12f);
#pragma unroll
      for (int i = 0; i < 4; ++i) r[i] *= sc;
    }
    float4 ov = {r[0], r[1], r[2], r[3]};
    *(float4*)(out + (size_t)bt * INNER_ + c) = ov;
  };

  run(qpre, cqw, cqb, qn, true);
  run(kpre, ckw, ckb, kn, true);
  run(vpre, cvw, cvb, vn, false);
}

// =============================================================================
// Chunked gated-delta (WY form). Per chunk of 64 steps, with P_t = prod a_s:
//   u_t = b_t v_t - b_t P_t (R k_t) - sum_{s<t} M[t,s] u_s,
//   M[t,s] = b_t (P_t/P_s)(k_t . k_s)
// Solve (I+M)U = [diag(b)V - diag(bP)K R^T] via W = T*diag(bP)K, Vt = T*diag(b)V:
//   U = Vt - W R^T
//   O = diag(P) Q R^T + tril(QP KIP^T) U = AV + Z R^T,  Z = Qp - Attn*W
//   R' = P63 R + U^T Kw = P63 R + Vt^T Kw - R (W^T Kw)  (Kw = P63*Kip)
// Precompute (parallel over 1024 units): AV, Z, G1 = Vt^T Kw, G2[j,m]=(Kw^T W)[j,m]
// Serial (per bh):  O_c = AV + Z R^T ;  R' = P63 R + G1 - R G2^T (Bt = G2 rows)
// =============================================================================
#define BST 72   // bf16 LDS row stride
#define MST 65   // f32 LDS row stride (M)

__device__ __forceinline__ bf16x8 fragld(const __hip_bfloat16* buf, int row, int kk, int lg) {
  return *(const bf16x8*)(buf + row * BST + kk * 32 + lg * 8);
}

__global__ __launch_bounds__(256) void precomp_kernel(
    const float* __restrict__ qn, const float* __restrict__ kn, const float* __restrict__ vn,
    const float* __restrict__ alpha, const float* __restrict__ beta,
    __hip_bfloat16* __restrict__ Zg, __hip_bfloat16* __restrict__ G2g,
    float* __restrict__ AVg, float* __restrict__ G1g, float* __restrict__ P63g) {
  __shared__ __hip_bfloat16 sKb[64 * BST], sKip[64 * BST], sKipT[64 * BST];
  __shared__ __hip_bfloat16 sQp[64 * BST], sVb[64 * BST];
  __shared__ float sM[64 * MST];
  __shared__ __hip_bfloat16 sWT[64 * BST], sVtT[64 * BST], sAttn[64 * BST];
  __shared__ float sP[64], sIP[64], sBP[64], sB[64];

  const int u = blockIdx.x;
  const int bh = u >> 5, c = u & 31;
  const int b = bh >> 4, h = bh & 15;
  const int tid = threadIdx.x, lane = tid & 63, wv = tid >> 6;
  const int l15 = lane & 15, lg = lane >> 4;
  const size_t bt0 = (size_t)b * T_ + (size_t)c * 64;
  const size_t hofs = (size_t)h * DH;

  // ---- phase 0: decay cumprods (wave 0)
  if (wv == 0) {
    float a = alpha[(bt0 + lane) * H_ + h];
    float bb = beta[(bt0 + lane) * H_ + h];
    float la = logf(a);
#pragma unroll
    for (int d = 1; d < 64; d <<= 1) {
      float y = __shfl_up(la, d);
      if (lane >= d) la += y;
    }
    float P = expf(la);
    sP[lane] = P;
    sIP[lane] = 1.f / P;
    sBP[lane] = bb * P;
    sB[lane] = bb;
    if (lane == 63) P63g[u] = P;
  }
  __syncthreads();

  // ---- phase 1: stage K,Q,V with diag scalings (bf16)
#pragma unroll
  for (int i = 0; i < 4; ++i) {
    int e = tid + i * 256;          // float4 index 0..1023
    int row = e >> 4, c4 = (e & 15) * 4;
    size_t g = (bt0 + row) * INNER_ + hofs + c4;
    float4 kv = *(const float4*)(kn + g);
    float4 qv = *(const float4*)(qn + g);
    float4 vv = *(const float4*)(vn + g);
    float bp = sBP[row], ip = sIP[row], pp = sP[row], bo = sB[row];
    st_bf4(&sKb[row * BST + c4], kv.x * bp, kv.y * bp, kv.z * bp, kv.w * bp);
    st_bf4(&sKip[row * BST + c4], kv.x * ip, kv.y * ip, kv.z * ip, kv.w * ip);
    st_bf4(&sQp[row * BST + c4], qv.x * pp, qv.y * pp, qv.z * pp, qv.w * pp);
    st_bf4(&sVb[row * BST + c4], vv.x * bo, vv.y * bo, vv.z * bo, vv.w * bo);
    // transposed Kip
    sKipT[(c4 + 0) * BST + row] = __float2bfloat16(kv.x * ip);
    sKipT[(c4 + 1) * BST + row] = __float2bfloat16(kv.y * ip);
    sKipT[(c4 + 2) * BST + row] = __float2bfloat16(kv.z * ip);
    sKipT[(c4 + 3) * BST + row] = __float2bfloat16(kv.w * ip);
  }
  __syncthreads();

  // ---- phase 2: M (waves 0,1) and Attn (waves 2,3)
  if (wv < 2) {
#pragma unroll
    for (int tt = wv * 2; tt < wv * 2 + 2; ++tt) {
      for (int n = 0; n <= tt; ++n) {
        f32x4 acc = (f32x4)0.f;
#pragma unroll
        for (int kk = 0; kk < 2; ++kk)
          acc = __builtin_amdgcn_mfma_f32_16x16x32_bf16(
              fragld(sKb, tt * 16 + l15, kk, lg), fragld(sKip, n * 16 + l15, kk, lg), acc, 0, 0, 0);
#pragma unroll
        for (int q = 0; q < 4; ++q) {
          int r = tt * 16 + lg * 4 + q, cl = n * 16 + l15;
          sM[r * MST + cl] = (cl < r) ? acc[q] : 0.f;
        }
      }
    }
  } else {
#pragma unroll
    for (int tt = (wv - 2) * 2; tt < (wv - 2) * 2 + 2; ++tt) {
      for (int n = 0; n < 4; ++n) {
        if (n <= tt) {
          f32x4 acc = (f32x4)0.f;
#pragma unroll
          for (int kk = 0; kk < 2; ++kk)
            acc = __builtin_amdgcn_mfma_f32_16x16x32_bf16(
                fragld(sQp, tt * 16 + l15, kk, lg), fragld(sKip, n * 16 + l15, kk, lg), acc, 0, 0, 0);
#pragma unroll
          for (int q = 0; q < 4; ++q) {
            int r = tt * 16 + lg * 4 + q, cl = n * 16 + l15;
            sAttn[r * BST + cl] = __float2bfloat16((cl <= r) ? acc[q] : 0.f);
          }
        } else {
#pragma unroll
          for (int q = 0; q < 4; ++q) {
            int r = tt * 16 + lg * 4 + q, cl = n * 16 + l15;
            sAttn[r * BST + cl] = __float2bfloat16(0.f);
          }
        }
      }
    }
  }
  __syncthreads();

  // ---- phase 3: forward substitution (I+M)X = RHS; waves 0->W, 1->Vt.
  // Lane j owns column j; X history in registers (static idx via full unroll);
  // M[t][s] broadcast via readlane of the lane-distributed M row.
  if (wv < 2) {
    const __hip_bfloat16* RHS = wv ? sVb : sKb;
    __hip_bfloat16* XT = wv ? sVtT : sWT;   // store transposed: XT[j][t]
    const int j = lane;
    float X[64];
#pragma unroll
    for (int t = 0; t < 64; ++t) {
      float a0 = 0.f, a1 = 0.f, a2 = 0.f, a3 = 0.f;
      int mr = __float_as_int(sM[t * MST + j]);
      int s = 0;
#pragma unroll
      for (; s + 3 < t; s += 4) {
        a0 += __int_as_float(__builtin_amdgcn_readlane(mr, s + 0)) * X[s + 0];
        a1 += __int_as_float(__builtin_amdgcn_readlane(mr, s + 1)) * X[s + 1];
        a2 += __int_as_float(__builtin_amdgcn_readlane(mr, s + 2)) * X[s + 2];
        a3 += __int_as_float(__builtin_amdgcn_readlane(mr, s + 3)) * X[s + 3];
      }
#pragma unroll
      for (; s < t; ++s)
        a0 += __int_as_float(__builtin_amdgcn_readlane(mr, s)) * X[s];
      X[t] = __bfloat162float(RHS[t * BST + j]) - ((a0 + a1) + (a2 + a3));
    }
#pragma unroll
    for (int t = 0; t < 64; t += 4)
      st_bf4(&XT[j * BST + t], X[t], X[t + 1], X[t + 2], X[t + 3]);
  }
  __syncthreads();

  // ---- phase 4: outputs. wave wv -> row band tt = wv.
  const float p63 = sP[63];
  const int tt = wv;
  const size_t go = (size_t)u * 4096;
#pragma unroll
  for (int n = 0; n < 4; ++n) {
    f32x4 av = (f32x4)0.f, aw = (f32x4)0.f, g1 = (f32x4)0.f, g2 = (f32x4)0.f;
#pragma unroll
    for (int kk = 0; kk < 2; ++kk) {
      bf16x8 at = fragld(sAttn, tt * 16 + l15, kk, lg);
      bf16x8 kt = fragld(sKipT, tt * 16 + l15, kk, lg);
      bf16x8 bv = fragld(sVtT, n * 16 + l15, kk, lg);
      bf16x8 bw = fragld(sWT, n * 16 + l15, kk, lg);
      av = __builtin_amdgcn_mfma_f32_16x16x32_bf16(at, bv, av, 0, 0, 0);
      aw = __builtin_amdgcn_mfma_f32_16x16x32_bf16(at, bw, aw, 0, 0, 0);
      g1 = __builtin_amdgcn_mfma_f32_16x16x32_bf16(kt, bv, g1, 0, 0, 0);
      g2 = __builtin_amdgcn_mfma_f32_16x16x32_bf16(kt, bw, g2, 0, 0, 0);
    }
#pragma unroll
    for (int q = 0; q < 4; ++q) {
      int r = tt * 16 + lg * 4 + q, cl = n * 16 + l15;
      AVg[go + r * 64 + cl] = av[q];
      float qp = __bfloat162float(sQp[r * BST + cl]);
      Zg[go + r * 64 + cl] = __float2bfloat16(qp - aw[q]);
      // G1 stored TRANSPOSED: G1_correct[i][j] = (Vt^T Kw)[i][j] = p63*(KipT Vt)[j][i]
      G1g[go + cl * 64 + r] = p63 * g1[q];
      G2g[go + r * 64 + cl] = __float2bfloat16(p63 * g2[q]);
    }
  }
}

// ---------------- serial chunk recurrence ------------------------------------
// 32 blocks (one per bh) x 256 thr. R in registers (wave band rows). Per chunk:
// O = AV + Z R^T, R' = p63 R + G1 - R G2^T. Swizzled LDS for bf16 operands.
__device__ __forceinline__ bf16x8 sfrag(const __hip_bfloat16* buf, int row, int kk, int lg) {
  int byte = row * 128 + kk * 64 + lg * 16;
  byte ^= (row & 7) << 4;
  return *(const bf16x8*)((const char*)buf + byte);
}

__global__ __launch_bounds__(256) void chunkrec_kernel(
    const __hip_bfloat16* __restrict__ Zg, const __hip_bfloat16* __restrict__ G2g,
    const float* __restrict__ AVg, const float* __restrict__ G1g,
    const float* __restrict__ P63g, float* __restrict__ o) {
  __shared__ __align__(16) __hip_bfloat16 sR[64 * 64];
  __shared__ __align__(16) __hip_bfloat16 sZ[2][64 * 64];
  __shared__ __align__(16) __hip_bfloat16 sG2[2][64 * 64];
  const int bh = blockIdx.x;
  const int b = bh >> 4, h = bh & 15;
  const int tid = threadIdx.x, lane = tid & 63, wv = tid >> 6;
  const int l15 = lane & 15, lg = lane >> 4;
  const size_t btb = (size_t)b * T_;
  const size_t hofs = (size_t)h * DH;

  f32x4 R[4];
#pragma unroll
  for (int n = 0; n < 4; ++n) R[n] = (f32x4)0.f;

  uint4 zr[2], gr[2];
  const int e0 = tid * 2;  // uint4 index (8 bf16 each), 512 per matrix

  auto issue = [&](int c) {
    size_t ub = ((size_t)bh * NCH + c) * 4096;
#pragma unroll
    for (int i = 0; i < 2; ++i) {
      zr[i] = *(const uint4*)(Zg + ub + (size_t)(e0 + i) * 8);
      gr[i] = *(const uint4*)(G2g + ub + (size_t)(e0 + i) * 8);
    }
  };
  auto commit = [&](int buf) {
#pragma unroll
    for (int i = 0; i < 2; ++i) {
      int e = e0 + i;
      int row = e >> 3, colb = (e & 7) * 16;
      int byte = (row * 128 + colb) ^ ((row & 7) << 4);
      *(uint4*)((char*)sZ[buf] + byte) = zr[i];
      *(uint4*)((char*)sG2[buf] + byte) = gr[i];
    }
  };

  issue(0);
  commit(0);
  int cur = 0;
  for (int c = 0; c < NCH; ++c) {
    // write R (bf16, swizzled) for this chunk's MFMA operands
#pragma unroll
    for (int n = 0; n < 4; ++n)
#pragma unroll
      for (int q = 0; q < 4; ++q) {
        int i = wv * 16 + lg * 4 + q;
        int byte = (i * 128 + (n * 16 + l15) * 2) ^ ((i & 7) << 4);
        *(__hip_bfloat16*)((char*)sR + byte) = __float2bfloat16(R[n][q]);
      }
    __syncthreads();

    // epilogue operand loads (independent of LDS) + next-chunk staging
    const size_t ub = ((size_t)bh * NCH + c) * 4096;
    float avr[4][4], g1r[4][4];
#pragma unroll
    for (int n = 0; n < 4; ++n)
#pragma unroll
      for (int q = 0; q < 4; ++q) {
        int r = wv * 16 + lg * 4 + q, cl = n * 16 + l15;
        avr[n][q] = AVg[ub + r * 64 + cl];
        g1r[n][q] = G1g[ub + r * 64 + cl];
      }
    float p63 = P63g[(size_t)bh * NCH + c];
    if (c + 1 < NCH) issue(c + 1);

    // fragments
    bf16x8 zA[2], rA[2], rB[4][2], gB[4][2];
#pragma unroll
    for (int kk = 0; kk < 2; ++kk) {
      zA[kk] = sfrag(sZ[cur], wv * 16 + l15, kk, lg);
      rA[kk] = sfrag(sR, wv * 16 + l15, kk, lg);
#pragma unroll
      for (int n = 0; n < 4; ++n) {
        rB[n][kk] = sfrag(sR, n * 16 + l15, kk, lg);
        gB[n][kk] = sfrag(sG2[cur], n * 16 + l15, kk, lg);
      }
    }
    f32x4 oacc[4], gacc[4];
#pragma unroll
    for (int n = 0; n < 4; ++n) { oacc[n] = (f32x4)0.f; gacc[n] = (f32x4)0.f; }
#pragma unroll
    for (int kk = 0; kk < 2; ++kk)
#pragma unroll
      for (int n = 0; n < 4; ++n) {
        oacc[n] = __builtin_amdgcn_mfma_f32_16x16x32_bf16(zA[kk], rB[n][kk], oacc[n], 0, 0, 0);
        gacc[n] = __builtin_amdgcn_mfma_f32_16x16x32_bf16(rA[kk], gB[n][kk], gacc[n], 0, 0, 0);
      }

    // epilogue: O out, R update
#pragma unroll
    for (int n = 0; n < 4; ++n)
#pragma unroll
      for (int q = 0; q < 4; ++q) {
        int t = wv * 16 + lg * 4 + q, cl = n * 16 + l15;
        o[(btb + (size_t)c * 64 + t) * INNER_ + hofs + cl] = avr[n][q] + oacc[n][q];
        R[n][q] = p63 * R[n][q] + g1r[n][q] - gacc[n][q];
      }
    __syncthreads();
    if (c + 1 < NCH) commit(cur ^ 1);
    cur ^= 1;
  }
}

// ---------------- RMS norm over INNER, * (1+gamma) * gate, -> bf16 -----------
__global__ __launch_bounds__(256) void rmsgate_kernel(const float* __restrict__ o,
    const float* __restrict__ gate, const float* __restrict__ gamma,
    __hip_bfloat16* __restrict__ outn) {
  const int bt = blockIdx.x;
  const int tid = threadIdx.x;
  const size_t base = (size_t)bt * INNER_ + tid * 4;
  float4 ov = *(const float4*)(o + base);
  float ss = ov.x*ov.x + ov.y*ov.y + ov.z*ov.z + ov.w*ov.w;
#pragma unroll
  for (int m = 1; m <= 32; m <<= 1) ss += __shfl_xor(ss, m);
  __shared__ float red[4];
  if ((tid & 63) == 0) red[tid >> 6] = ss;
  __syncthreads();
  float tot = red[0] + red[1] + red[2] + red[3];
  float rms = sqrtf(tot * (1.f / (float)INNER_) + 1e-6f);
  float inv = 1.f / rms;
  float4 gm = *(const float4*)(gamma + tid * 4);
  float4 gt = *(const float4*)(gate + base);
  __hip_bfloat16 t[4];
  t[0] = __float2bfloat16(ov.x * inv * (1.f + gm.x) * gt.x);
  t[1] = __float2bfloat16(ov.y * inv * (1.f + gm.y) * gt.y);
  t[2] = __float2bfloat16(ov.z * inv * (1.f + gm.z) * gt.z);
  t[3] = __float2bfloat16(ov.w * inv * (1.f + gm.w) * gt.w);
  *(uint2*)(outn + base) = *(uint2*)t;
}

// ---------------- launch -----------------------------------------------------
extern "C" void kernel_launch(void* const* d_in, const int* in_sizes, int n_in,
                              void* d_out, int out_size, void* d_ws, size_t ws_size,
                              hipStream_t stream) {
  const float* x   = (const float*)d_in[0];
  const float* Wq  = (const float*)d_in[1];
  const float* Wk  = (const float*)d_in[2];
  const float* Wv  = (const float*)d_in[3];
  const float* Wa  = (const float*)d_in[4];
  const float* ba  = (const float*)d_in[5];
  const float* Wb  = (const float*)d_in[6];
  const float* bb  = (const float*)d_in[7];
  const float* Wg  = (const float*)d_in[8];
  const float* Wo  = (const float*)d_in[9];
  const float* cqw = (const float*)d_in[10];
  const float* cqb = (const float*)d_in[11];
  const float* ckw = (const float*)d_in[12];
  const float* ckb = (const float*)d_in[13];
  const float* cvw = (const float*)d_in[14];
  const float* cvb = (const float*)d_in[15];
  const float* gamma = (const float*)d_in[16];

  float* ws = (float*)d_ws;
  const size_t N1 = (size_t)BT * INNER_;          // 4.19M elements
  float* qpre = ws;
  float* kpre = ws + N1;
  float* vpre = ws + 2 * N1;
  float* gate = ws + 3 * N1;
  float* qn   = ws + 4 * N1;
  float* kn   = ws + 5 * N1;
  float* vn   = ws + 6 * N1;
  float* alpha = ws + 7 * N1;
  float* beta  = alpha + (size_t)BT * H_;
  __hip_bfloat16* wt0 = (__hip_bfloat16*)(beta + (size_t)BT * H_);
  __hip_bfloat16* Wot = wt0 + 4 * (size_t)D_ * INNER_;
  float* P63s = (float*)(Wot + (size_t)D_ * INNER_);
  __hip_bfloat16* xb  = (__hip_bfloat16*)vn;       // dead before convnorm writes vn
  // chunked intermediates (regions dead after convnorm):
  float* AVg = qpre;
  __hip_bfloat16* Zg  = (__hip_bfloat16*)kpre;     // NU*4096 bf16 (8.4MB)
  __hip_bfloat16* G2g = Zg + (size_t)NU * 4096;    // second half of kpre
  float* G1g = vpre;
  float* obuf = qn;                                // qn dead after precompute
  __hip_bfloat16* nrmb = (__hip_bfloat16*)kn;      // kn dead after precompute
  float* outp = (float*)d_out;

  // 1) conversions
  cvt_bf16_kernel<<<(BT * D_ / 4 + 255) / 256, 256, 0, stream>>>(x, xb, BT * D_ / 4);
  dim3 tgrid(INNER_ / 32, D_ / 32);
  transpose_cvt_kernel<<<tgrid, 256, 0, stream>>>(Wq, wt0, D_, INNER_);
  transpose_cvt_kernel<<<tgrid, 256, 0, stream>>>(Wk, wt0 + (size_t)D_ * INNER_, D_, INNER_);
  transpose_cvt_kernel<<<tgrid, 256, 0, stream>>>(Wv, wt0 + 2 * (size_t)D_ * INNER_, D_, INNER_);
  transpose_cvt_kernel<<<tgrid, 256, 0, stream>>>(Wg, wt0 + 3 * (size_t)D_ * INNER_, D_, INNER_);
  transpose_cvt_kernel<<<dim3(D_ / 32, INNER_ / 32), 256, 0, stream>>>(Wo, Wot, INNER_, D_);

  // 2) fused projection GEMM: N=4096 over [Wq|Wk|Wv|Wg], split4 epilogue
  gemm_bf16<<<dim3(4 * INNER_ / 128, BT / 128), 256, 0, stream>>>(
      xb, wt0, qpre, BT, 4 * INNER_, D_, 2);

  alphabeta_kernel<<<BT, 64, 0, stream>>>(x, Wa, ba, Wb, bb, alpha, beta);
  convnorm_kernel<<<BT, 256, 0, stream>>>(qpre, kpre, vpre, cqw, cqb, ckw, ckb,
                                          cvw, cvb, qn, kn, vn);

  // 3) chunked recurrence
  precomp_kernel<<<NU, 256, 0, stream>>>(qn, kn, vn, alpha, beta, Zg, G2g, AVg, G1g, P63s);
  chunkrec_kernel<<<B_ * H_, 256, 0, stream>>>(Zg, G2g, AVg, G1g, P63s, obuf);

  rmsgate_kernel<<<BT, 256, 0, stream>>>(obuf, gate, gamma, nrmb);
  gemm_bf16<<<dim3(D_ / 128, BT / 128), 256, 0, stream>>>(nrmb, Wot, outp, BT, D_, INNER_, 0);
}

// Round 6
// 409.427 us; speedup vs baseline: 4.0887x; 1.1840x over previous
//
#include <hip/hip_runtime.h>
#include <hip/hip_bf16.h>
#include <cmath>

#define B_ 2
#define T_ 2048
#define D_ 1024
#define H_ 16
#define DH 64
#define INNER_ 1024
#define BT (B_*T_)
#define NCH 32              // chunks per (b,h), chunk length 64
#define NU (B_*H_*NCH)      // 1024 precompute units

typedef __attribute__((ext_vector_type(8))) __bf16 bf16x8;
typedef __attribute__((ext_vector_type(4))) float f32x4;
typedef const __attribute__((address_space(1))) unsigned gas_u32;
typedef __attribute__((address_space(3))) unsigned las_u32;

__device__ __forceinline__ void async16(const void* g, void* l) {
  __builtin_amdgcn_global_load_lds((gas_u32*)g, (las_u32*)l, 16, 0, 0);
}

__device__ __forceinline__ ushort bfr(float x) {
  __hip_bfloat16 t = __float2bfloat16(x);
  return *(ushort*)&t;
}
__device__ __forceinline__ void st_bf4(__hip_bfloat16* p, float a, float b, float c, float d) {
  ushort4 u; u.x = bfr(a); u.y = bfr(b); u.z = bfr(c); u.w = bfr(d);
  *(ushort4*)p = u;
}

// ---------------- convert f32 -> bf16 (elementwise) --------------------------
__global__ __launch_bounds__(256) void cvt_bf16_kernel(const float* __restrict__ in,
                                                       __hip_bfloat16* __restrict__ out,
                                                       int n4) {
  int i = blockIdx.x * 256 + threadIdx.x;
  if (i >= n4) return;
  float4 v = *(const float4*)(in + (size_t)i * 4);
  __hip_bfloat16 t[4];
  t[0] = __float2bfloat16(v.x); t[1] = __float2bfloat16(v.y);
  t[2] = __float2bfloat16(v.z); t[3] = __float2bfloat16(v.w);
  *(uint2*)(out + (size_t)i * 4) = *(uint2*)t;
}

// ---------------- transpose + convert: in [R][C] f32 -> out [C][R] bf16 ------
__global__ __launch_bounds__(256) void transpose_cvt_kernel(const float* __restrict__ in,
                                                            __hip_bfloat16* __restrict__ out,
                                                            int R, int C) {
  __shared__ float tile[32][33];
  const int bc = blockIdx.x * 32, br = blockIdx.y * 32;
  const int tx = threadIdx.x & 31, ty = threadIdx.x >> 5;  // 32 x 8
#pragma unroll
  for (int i = 0; i < 32; i += 8)
    tile[ty + i][tx] = in[(size_t)(br + ty + i) * C + bc + tx];
  __syncthreads();
#pragma unroll
  for (int i = 0; i < 32; i += 8)
    out[(size_t)(bc + ty + i) * R + br + tx] = __float2bfloat16(tile[tx][ty + i]);
}

// ---------------- Wab: pack [Wa|Wb] transposed to [128][1024] bf16 (pad 0) ---
__global__ __launch_bounds__(256) void wab_kernel(const float* __restrict__ Wa,
                                                  const float* __restrict__ Wb,
                                                  __hip_bfloat16* __restrict__ Wabt) {
  int idx = blockIdx.x * 256 + threadIdx.x;  // 128*1024
  int j = idx >> 10, k = idx & 1023;
  float v = 0.f;
  if (j < 16) v = Wa[k * 16 + j];
  else if (j < 32) v = Wb[k * 16 + (j - 16)];
  Wabt[idx] = __float2bfloat16(v);
}

// ---------------- 128^2 bf16 MFMA GEMM (m97 structure) -----------------------
__global__ __launch_bounds__(256) void gemm_bf16(const __hip_bfloat16* __restrict__ A,
                                                 const __hip_bfloat16* __restrict__ Bt,
                                                 float* __restrict__ C,
                                                 int M, int N, int K, int act) {
  __shared__ __hip_bfloat16 As[128 * 32];
  __shared__ __hip_bfloat16 Bs[128 * 32];
  const int tid = threadIdx.x;
  const int lane = tid & 63, wave = tid >> 6;
  const int wr = wave >> 1, wc = wave & 1;
  const int m0 = blockIdx.y * 128, n0 = blockIdx.x * 128;
  const int srow = tid >> 2, skoff = (tid & 3) * 8;
  const int l15 = lane & 15, lg = lane >> 4;

  f32x4 acc[4][4];
#pragma unroll
  for (int m = 0; m < 4; ++m)
#pragma unroll
    for (int n = 0; n < 4; ++n) acc[m][n] = (f32x4)0.f;

  char* asB = (char*)As;
  char* bsB = (char*)Bs;
  const int ldsw = wave * 1024;

  for (int k0 = 0; k0 < K; k0 += 32) {
    async16(A + (size_t)(m0 + srow) * K + k0 + skoff, asB + ldsw);
    async16(A + (size_t)(m0 + 64 + srow) * K + k0 + skoff, asB + 4096 + ldsw);
    async16(Bt + (size_t)(n0 + srow) * K + k0 + skoff, bsB + ldsw);
    async16(Bt + (size_t)(n0 + 64 + srow) * K + k0 + skoff, bsB + 4096 + ldsw);
    __syncthreads();

    bf16x8 af[4], bfg[4];
#pragma unroll
    for (int m = 0; m < 4; ++m)
      af[m] = *(const bf16x8*)(asB + ((wr * 64 + m * 16 + l15) * 32 + lg * 8) * 2);
#pragma unroll
    for (int n = 0; n < 4; ++n)
      bfg[n] = *(const bf16x8*)(bsB + ((wc * 64 + n * 16 + l15) * 32 + lg * 8) * 2);
#pragma unroll
    for (int m = 0; m < 4; ++m)
#pragma unroll
      for (int n = 0; n < 4; ++n)
        acc[m][n] = __builtin_amdgcn_mfma_f32_16x16x32_bf16(af[m], bfg[n], acc[m][n], 0, 0, 0);
    __syncthreads();
  }

#pragma unroll
  for (int m = 0; m < 4; ++m) {
    const int rbase = m0 + wr * 64 + m * 16 + lg * 4;
#pragma unroll
    for (int n = 0; n < 4; ++n) {
      const int col = n0 + wc * 64 + n * 16 + l15;
#pragma unroll
      for (int r = 0; r < 4; ++r) {
        float vv = acc[m][n][r];
        if (act == 1) vv = vv / (1.f + expf(-vv));
        C[(size_t)(rbase + r) * N + col] = vv;
      }
    }
  }
}

// ---------------- gemm_ab: x @ [Wa|Wb] (N=128 padded), sigmoid epilogue ------
__global__ __launch_bounds__(256) void gemm_ab(const __hip_bfloat16* __restrict__ A,
                                               const __hip_bfloat16* __restrict__ Bt,
                                               const float* __restrict__ ba,
                                               const float* __restrict__ bb2,
                                               float* __restrict__ alpha,
                                               float* __restrict__ beta, int K) {
  __shared__ __hip_bfloat16 As[128 * 32];
  __shared__ __hip_bfloat16 Bs[128 * 32];
  const int tid = threadIdx.x;
  const int lane = tid & 63, wave = tid >> 6;
  const int wr = wave >> 1, wc = wave & 1;
  const int m0 = blockIdx.y * 128;
  const int srow = tid >> 2, skoff = (tid & 3) * 8;
  const int l15 = lane & 15, lg = lane >> 4;

  f32x4 acc[4][2];
#pragma unroll
  for (int m = 0; m < 4; ++m)
#pragma unroll
    for (int n = 0; n < 2; ++n) acc[m][n] = (f32x4)0.f;

  char* asB = (char*)As;
  char* bsB = (char*)Bs;
  const int ldsw = wave * 1024;

  for (int k0 = 0; k0 < K; k0 += 32) {
    async16(A + (size_t)(m0 + srow) * K + k0 + skoff, asB + ldsw);
    async16(A + (size_t)(m0 + 64 + srow) * K + k0 + skoff, asB + 4096 + ldsw);
    async16(Bt + (size_t)srow * K + k0 + skoff, bsB + ldsw);
    async16(Bt + (size_t)(64 + srow) * K + k0 + skoff, bsB + 4096 + ldsw);
    __syncthreads();
    if (wc == 0) {  // only cols 0..63 matter (real cols 0..31)
      bf16x8 af[4], bfg[2];
#pragma unroll
      for (int m = 0; m < 4; ++m)
        af[m] = *(const bf16x8*)(asB + ((wr * 64 + m * 16 + l15) * 32 + lg * 8) * 2);
#pragma unroll
      for (int n = 0; n < 2; ++n)
        bfg[n] = *(const bf16x8*)(bsB + ((n * 16 + l15) * 32 + lg * 8) * 2);
#pragma unroll
      for (int m = 0; m < 4; ++m)
#pragma unroll
        for (int n = 0; n < 2; ++n)
          acc[m][n] = __builtin_amdgcn_mfma_f32_16x16x32_bf16(af[m], bfg[n], acc[m][n], 0, 0, 0);
    }
    __syncthreads();
  }
  if (wc != 0) return;
#pragma unroll
  for (int m = 0; m < 4; ++m) {
    const int rbase = m0 + wr * 64 + m * 16 + lg * 4;
#pragma unroll
    for (int n = 0; n < 2; ++n) {
      const int col = n * 16 + l15;
      const float bias = (n == 0) ? ba[l15] : bb2[l15];
      float* dst = (n == 0) ? alpha : beta;
#pragma unroll
      for (int r = 0; r < 4; ++r) {
        float vv = acc[m][n][r] + bias;
        dst[(size_t)(rbase + r) * H_ + l15] = 1.f / (1.f + expf(-vv));
      }
    }
  }
}

// ---------------- 256^2 2-phase double-buffered bf16 MFMA GEMM ---------------
// T3 "minimum 2-phase" (m230: 682 TF @K~1024): 512 thr (8 waves 2x4), BK=64,
// dbuf LDS 128KB, prefetch issued before compute, one vmcnt(0)+barrier per
// K-tile (__syncthreads emits it). T2/T5 skipped (null at 2-phase).
// act: 0 = plain C[M,N]; 2 = split4 epilogue (N=4096: [q|k|v|g], silu on g).
__device__ __forceinline__ bf16x8 pfrag(const __hip_bfloat16* buf, int row, int ks, int lg) {
  return *(const bf16x8*)((const char*)buf + row * 128 + ks * 64 + lg * 16);
}

__global__ __launch_bounds__(512, 2) void gemm256(const __hip_bfloat16* __restrict__ A,
                                                  const __hip_bfloat16* __restrict__ Bt,
                                                  float* __restrict__ C,
                                                  int M, int N, int K, int act) {
  __shared__ __hip_bfloat16 As[2][256 * 64];   // 2 x 32KB
  __shared__ __hip_bfloat16 Bs[2][256 * 64];   // 2 x 32KB
  const int tid = threadIdx.x;
  const int lane = tid & 63, wv = tid >> 6;     // 8 waves
  const int wr = wv >> 2, wc = wv & 3;          // 2 x 4 wave grid
  const int m0 = blockIdx.y * 256, n0 = blockIdx.x * 256;
  const int l15 = lane & 15, lg = lane >> 4;
  const int sr8 = lane >> 3, sc = (lane & 7) * 8;  // staging row-in-8 / col

  f32x4 acc[8][4];
#pragma unroll
  for (int m = 0; m < 8; ++m)
#pragma unroll
    for (int n = 0; n < 4; ++n) acc[m][n] = (f32x4)0.f;

  auto stage = [&](int kt, int bsel) {
    const size_t k0 = (size_t)kt * 64;
    const __hip_bfloat16* Ab = A + (size_t)(m0 + wv * 8 + sr8) * K + k0 + sc;
    const __hip_bfloat16* Bb = Bt + (size_t)(n0 + wv * 8 + sr8) * K + k0 + sc;
    char* al = (char*)As[bsel] + wv * 1024;
    char* bl = (char*)Bs[bsel] + wv * 1024;
#pragma unroll
    for (int q = 0; q < 4; ++q) {
      async16(Ab + (size_t)q * 64 * K, al + q * 8192);
      async16(Bb + (size_t)q * 64 * K, bl + q * 8192);
    }
  };

  const int NT = K >> 6;
  stage(0, 0);
  __syncthreads();
  int cur = 0;
  for (int kt = 0; kt < NT; ++kt) {
    if (kt + 1 < NT) stage(kt + 1, cur ^ 1);
#pragma unroll
    for (int ks = 0; ks < 2; ++ks) {
      bf16x8 af[8], bfg[4];
#pragma unroll
      for (int m = 0; m < 8; ++m)
        af[m] = pfrag(As[cur], wr * 128 + m * 16 + l15, ks, lg);
#pragma unroll
      for (int n = 0; n < 4; ++n)
        bfg[n] = pfrag(Bs[cur], wc * 64 + n * 16 + l15, ks, lg);
#pragma unroll
      for (int m = 0; m < 8; ++m)
#pragma unroll
        for (int n = 0; n < 4; ++n)
          acc[m][n] = __builtin_amdgcn_mfma_f32_16x16x32_bf16(af[m], bfg[n], acc[m][n], 0, 0, 0);
    }
    __syncthreads();   // drains vmcnt(0)+lgkmcnt(0): staged loads landed, reads done
    cur ^= 1;
  }

#pragma unroll
  for (int m = 0; m < 8; ++m) {
    const int rbase = m0 + wr * 128 + m * 16 + lg * 4;
#pragma unroll
    for (int n = 0; n < 4; ++n) {
      const int col = n0 + wc * 64 + n * 16 + l15;
      if (act == 2) {
        const int which = col >> 10;
        const int ncol = col & 1023;
        float* dst = C + (size_t)which * ((size_t)BT * INNER_) +
                     (size_t)rbase * 1024 + ncol;
#pragma unroll
        for (int r = 0; r < 4; ++r) {
          float vv = acc[m][n][r];
          if (which == 3) vv = vv / (1.f + expf(-vv));
          dst[(size_t)r * 1024] = vv;
        }
      } else {
#pragma unroll
        for (int r = 0; r < 4; ++r)
          C[(size_t)(rbase + r) * N + col] = acc[m][n][r];
      }
    }
  }
}

// ---------------- depthwise causal conv (K=4) + silu + optional l2norm -------
__global__ __launch_bounds__(256) void convnorm_kernel(
    const float* __restrict__ qpre, const float* __restrict__ kpre, const float* __restrict__ vpre,
    const float* __restrict__ cqw, const float* __restrict__ cqb,
    const float* __restrict__ ckw, const float* __restrict__ ckb,
    const float* __restrict__ cvw, const float* __restrict__ cvb,
    float* __restrict__ qn, float* __restrict__ kn, float* __restrict__ vn) {
  const int bt = blockIdx.x;
  const int t = bt & (T_ - 1);
  const int tid = threadIdx.x;
  const int c = tid * 4;

  auto run = [&](const float* __restrict__ pre, const float* __restrict__ w,
                 const float* __restrict__ bias, float* __restrict__ out, bool norm) {
    float r[4];
    float4 bv = *(const float4*)(bias + c);
    r[0] = bv.x; r[1] = bv.y; r[2] = bv.z; r[3] = bv.w;
    float wl[4][4];
#pragma unroll
    for (int i = 0; i < 4; ++i) {
      float4 wv = *(const float4*)(w + (size_t)(c + i) * 4);
      wl[i][0] = wv.x; wl[i][1] = wv.y; wl[i][2] = wv.z; wl[i][3] = wv.w;
    }
#pragma unroll
    for (int kk = 0; kk < 4; ++kk) {
      int tt = t - 3 + kk;
      if (tt >= 0) {
        float4 xv = *(const float4*)(pre + (size_t)(bt - 3 + kk) * INNER_ + c);
        float xa[4] = {xv.x, xv.y, xv.z, xv.w};
#pragma unroll
        for (int i = 0; i < 4; ++i) r[i] += xa[i] * wl[i][kk];
      }
    }
#pragma unroll
    for (int i = 0; i < 4; ++i) r[i] = r[i] / (1.f + expf(-r[i]));
    if (norm) {
      float ss = r[0]*r[0] + r[1]*r[1] + r[2]*r[2] + r[3]*r[3];
      ss += __shfl_xor(ss, 1); ss += __shfl_xor(ss, 2);
      ss += __shfl_xor(ss, 4); ss += __shfl_xor(ss, 8);
      float n = sqrtf(ss);
      float sc = 1.f / fmaxf(n, 1e-12f);
#pragma unroll
      for (int i = 0; i < 4; ++i) r[i] *= sc;
    }
    float4 ov = {r[0], r[1], r[2], r[3]};
    *(float4*)(out + (size_t)bt * INNER_ + c) = ov;
  };

  run(qpre, cqw, cqb, qn, true);
  run(kpre, ckw, ckb, kn, true);
  run(vpre, cvw, cvb, vn, false);
}

// =============================================================================
// Chunked gated-delta (WY form) — precompute (unchanged, verified round 5).
// =============================================================================
#define BST 72
#define MST 65

__device__ __forceinline__ bf16x8 fragld(const __hip_bfloat16* buf, int row, int kk, int lg) {
  return *(const bf16x8*)(buf + row * BST + kk * 32 + lg * 8);
}

__global__ __launch_bounds__(256) void precomp_kernel(
    const float* __restrict__ qn, const float* __restrict__ kn, const float* __restrict__ vn,
    const float* __restrict__ alpha, const float* __restrict__ beta,
    __hip_bfloat16* __restrict__ Zg, __hip_bfloat16* __restrict__ G2g,
    float* __restrict__ AVg, float* __restrict__ G1g, float* __restrict__ P63g) {
  __shared__ __hip_bfloat16 sKb[64 * BST], sKip[64 * BST], sKipT[64 * BST];
  __shared__ __hip_bfloat16 sQp[64 * BST], sVb[64 * BST];
  __shared__ float sM[64 * MST];
  __shared__ __hip_bfloat16 sWT[64 * BST], sVtT[64 * BST], sAttn[64 * BST];
  __shared__ float sP[64], sIP[64], sBP[64], sB[64];

  const int u = blockIdx.x;
  const int bh = u >> 5, c = u & 31;
  const int b = bh >> 4, h = bh & 15;
  const int tid = threadIdx.x, lane = tid & 63, wv = tid >> 6;
  const int l15 = lane & 15, lg = lane >> 4;
  const size_t bt0 = (size_t)b * T_ + (size_t)c * 64;
  const size_t hofs = (size_t)h * DH;

  if (wv == 0) {
    float a = alpha[(bt0 + lane) * H_ + h];
    float bb = beta[(bt0 + lane) * H_ + h];
    float la = logf(a);
#pragma unroll
    for (int d = 1; d < 64; d <<= 1) {
      float y = __shfl_up(la, d);
      if (lane >= d) la += y;
    }
    float P = expf(la);
    sP[lane] = P;
    sIP[lane] = 1.f / P;
    sBP[lane] = bb * P;
    sB[lane] = bb;
    if (lane == 63) P63g[u] = P;
  }
  __syncthreads();

#pragma unroll
  for (int i = 0; i < 4; ++i) {
    int e = tid + i * 256;
    int row = e >> 4, c4 = (e & 15) * 4;
    size_t g = (bt0 + row) * INNER_ + hofs + c4;
    float4 kv = *(const float4*)(kn + g);
    float4 qv = *(const float4*)(qn + g);
    float4 vv = *(const float4*)(vn + g);
    float bp = sBP[row], ip = sIP[row], pp = sP[row], bo = sB[row];
    st_bf4(&sKb[row * BST + c4], kv.x * bp, kv.y * bp, kv.z * bp, kv.w * bp);
    st_bf4(&sKip[row * BST + c4], kv.x * ip, kv.y * ip, kv.z * ip, kv.w * ip);
    st_bf4(&sQp[row * BST + c4], qv.x * pp, qv.y * pp, qv.z * pp, qv.w * pp);
    st_bf4(&sVb[row * BST + c4], vv.x * bo, vv.y * bo, vv.z * bo, vv.w * bo);
    sKipT[(c4 + 0) * BST + row] = __float2bfloat16(kv.x * ip);
    sKipT[(c4 + 1) * BST + row] = __float2bfloat16(kv.y * ip);
    sKipT[(c4 + 2) * BST + row] = __float2bfloat16(kv.z * ip);
    sKipT[(c4 + 3) * BST + row] = __float2bfloat16(kv.w * ip);
  }
  __syncthreads();

  if (wv < 2) {
#pragma unroll
    for (int tt = wv * 2; tt < wv * 2 + 2; ++tt) {
      for (int n = 0; n <= tt; ++n) {
        f32x4 acc = (f32x4)0.f;
#pragma unroll
        for (int kk = 0; kk < 2; ++kk)
          acc = __builtin_amdgcn_mfma_f32_16x16x32_bf16(
              fragld(sKb, tt * 16 + l15, kk, lg), fragld(sKip, n * 16 + l15, kk, lg), acc, 0, 0, 0);
#pragma unroll
        for (int q = 0; q < 4; ++q) {
          int r = tt * 16 + lg * 4 + q, cl = n * 16 + l15;
          sM[r * MST + cl] = (cl < r) ? acc[q] : 0.f;
        }
      }
    }
  } else {
#pragma unroll
    for (int tt = (wv - 2) * 2; tt < (wv - 2) * 2 + 2; ++tt) {
      for (int n = 0; n < 4; ++n) {
        if (n <= tt) {
          f32x4 acc = (f32x4)0.f;
#pragma unroll
          for (int kk = 0; kk < 2; ++kk)
            acc = __builtin_amdgcn_mfma_f32_16x16x32_bf16(
                fragld(sQp, tt * 16 + l15, kk, lg), fragld(sKip, n * 16 + l15, kk, lg), acc, 0, 0, 0);
#pragma unroll
          for (int q = 0; q < 4; ++q) {
            int r = tt * 16 + lg * 4 + q, cl = n * 16 + l15;
            sAttn[r * BST + cl] = __float2bfloat16((cl <= r) ? acc[q] : 0.f);
          }
        } else {
#pragma unroll
          for (int q = 0; q < 4; ++q) {
            int r = tt * 16 + lg * 4 + q, cl = n * 16 + l15;
            sAttn[r * BST + cl] = __float2bfloat16(0.f);
          }
        }
      }
    }
  }
  __syncthreads();

  if (wv < 2) {
    const __hip_bfloat16* RHS = wv ? sVb : sKb;
    __hip_bfloat16* XT = wv ? sVtT : sWT;
    const int j = lane;
    float X[64];
#pragma unroll
    for (int t = 0; t < 64; ++t) {
      float a0 = 0.f, a1 = 0.f, a2 = 0.f, a3 = 0.f;
      int mr = __float_as_int(sM[t * MST + j]);
      int s = 0;
#pragma unroll
      for (; s + 3 < t; s += 4) {
        a0 += __int_as_float(__builtin_amdgcn_readlane(mr, s + 0)) * X[s + 0];
        a1 += __int_as_float(__builtin_amdgcn_readlane(mr, s + 1)) * X[s + 1];
        a2 += __int_as_float(__builtin_amdgcn_readlane(mr, s + 2)) * X[s + 2];
        a3 += __int_as_float(__builtin_amdgcn_readlane(mr, s + 3)) * X[s + 3];
      }
#pragma unroll
      for (; s < t; ++s)
        a0 += __int_as_float(__builtin_amdgcn_readlane(mr, s)) * X[s];
      X[t] = __bfloat162float(RHS[t * BST + j]) - ((a0 + a1) + (a2 + a3));
    }
#pragma unroll
    for (int t = 0; t < 64; t += 4)
      st_bf4(&XT[j * BST + t], X[t], X[t + 1], X[t + 2], X[t + 3]);
  }
  __syncthreads();

  const float p63 = sP[63];
  const int tt = wv;
  const size_t go = (size_t)u * 4096;
#pragma unroll
  for (int n = 0; n < 4; ++n) {
    f32x4 av = (f32x4)0.f, aw = (f32x4)0.f, g1 = (f32x4)0.f, g2 = (f32x4)0.f;
#pragma unroll
    for (int kk = 0; kk < 2; ++kk) {
      bf16x8 at = fragld(sAttn, tt * 16 + l15, kk, lg);
      bf16x8 kt = fragld(sKipT, tt * 16 + l15, kk, lg);
      bf16x8 bv = fragld(sVtT, n * 16 + l15, kk, lg);
      bf16x8 bw = fragld(sWT, n * 16 + l15, kk, lg);
      av = __builtin_amdgcn_mfma_f32_16x16x32_bf16(at, bv, av, 0, 0, 0);
      aw = __builtin_amdgcn_mfma_f32_16x16x32_bf16(at, bw, aw, 0, 0, 0);
      g1 = __builtin_amdgcn_mfma_f32_16x16x32_bf16(kt, bv, g1, 0, 0, 0);
      g2 = __builtin_amdgcn_mfma_f32_16x16x32_bf16(kt, bw, g2, 0, 0, 0);
    }
#pragma unroll
    for (int q = 0; q < 4; ++q) {
      int r = tt * 16 + lg * 4 + q, cl = n * 16 + l15;
      AVg[go + r * 64 + cl] = av[q];
      float qp = __bfloat162float(sQp[r * BST + cl]);
      Zg[go + r * 64 + cl] = __float2bfloat16(qp - aw[q]);
      G1g[go + cl * 64 + r] = p63 * g1[q];
      G2g[go + r * 64 + cl] = __float2bfloat16(p63 * g2[q]);
    }
  }
}

// ---------------- serial chunk recurrence, row-partitioned -------------------
// R' = p63 R + G1 - R G2^T : rows i of R evolve independently. 4 blocks per
// (b,h) each own 16 rows (jb) of R and produce O columns [jb*16,+16) for all t.
// 128 blocks x 256 thr; per-thread R state = 4 f32.
__device__ __forceinline__ bf16x8 sfrag(const __hip_bfloat16* buf, int row, int kk, int lg) {
  int byte = row * 128 + kk * 64 + lg * 16;
  byte ^= (row & 7) << 4;
  return *(const bf16x8*)((const char*)buf + byte);
}

__global__ __launch_bounds__(256) void chunkrec_kernel(
    const __hip_bfloat16* __restrict__ Zg, const __hip_bfloat16* __restrict__ G2g,
    const float* __restrict__ AVg, const float* __restrict__ G1g,
    const float* __restrict__ P63g, float* __restrict__ o) {
  __shared__ __align__(16) __hip_bfloat16 sR[16 * 64];
  __shared__ __align__(16) __hip_bfloat16 sZ[2][64 * 64];
  __shared__ __align__(16) __hip_bfloat16 sG2[2][64 * 64];
  const int blk = blockIdx.x;          // 128
  const int bh = blk >> 2;
  const int jb = blk & 3;              // R row-block
  const int b = bh >> 4, h = bh & 15;
  const int tid = threadIdx.x, lane = tid & 63, wv = tid >> 6;
  const int l15 = lane & 15, lg = lane >> 4;
  const size_t btb = (size_t)b * T_;
  const size_t hofs = (size_t)h * DH;

  // lane holds R[i=lg*4+q][m=wv*16+l15] (i local to jb)
  f32x4 R = (f32x4)0.f;

  uint4 zr[2], gr[2];
  const int e0 = tid * 2;

  auto issue = [&](int c) {
    size_t ub = ((size_t)bh * NCH + c) * 4096;
#pragma unroll
    for (int i = 0; i < 2; ++i) {
      zr[i] = *(const uint4*)(Zg + ub + (size_t)(e0 + i) * 8);
      gr[i] = *(const uint4*)(G2g + ub + (size_t)(e0 + i) * 8);
    }
  };
  auto commit = [&](int buf) {
#pragma unroll
    for (int i = 0; i < 2; ++i) {
      int e = e0 + i;
      int row = e >> 3, colb = (e & 7) * 16;
      int byte = (row * 128 + colb) ^ ((row & 7) << 4);
      *(uint4*)((char*)sZ[buf] + byte) = zr[i];
      *(uint4*)((char*)sG2[buf] + byte) = gr[i];
    }
  };

  issue(0);
  commit(0);
  int cur = 0;
  for (int c = 0; c < NCH; ++c) {
    // publish R rows to LDS (swizzled like sfrag)
#pragma unroll
    for (int q = 0; q < 4; ++q) {
      int i = lg * 4 + q;
      int byte = (i * 128 + (wv * 16 + l15) * 2) ^ ((i & 7) << 4);
      *(__hip_bfloat16*)((char*)sR + byte) = __float2bfloat16(R[q]);
    }
    __syncthreads();

    const size_t ub = ((size_t)bh * NCH + c) * 4096;
    float avr[4], g1r[4];
#pragma unroll
    for (int q = 0; q < 4; ++q) {
      int t = wv * 16 + lg * 4 + q;
      avr[q] = AVg[ub + t * 64 + jb * 16 + l15];
      g1r[q] = G1g[ub + (jb * 16 + lg * 4 + q) * 64 + wv * 16 + l15];
    }
    float p63 = P63g[(size_t)bh * NCH + c];
    if (c + 1 < NCH) issue(c + 1);

    bf16x8 zA[2], rF[2], gB[2];
#pragma unroll
    for (int kk = 0; kk < 2; ++kk) {
      zA[kk] = sfrag(sZ[cur], wv * 16 + l15, kk, lg);   // Z t-band wv
      rF[kk] = sfrag(sR, l15, kk, lg);                  // R rows (16)
      gB[kk] = sfrag(sG2[cur], wv * 16 + l15, kk, lg);  // G2 m-band wv
    }
    f32x4 oacc = (f32x4)0.f, gacc = (f32x4)0.f;
#pragma unroll
    for (int kk = 0; kk < 2; ++kk) {
      oacc = __builtin_amdgcn_mfma_f32_16x16x32_bf16(zA[kk], rF[kk], oacc, 0, 0, 0);
      gacc = __builtin_amdgcn_mfma_f32_16x16x32_bf16(rF[kk], gB[kk], gacc, 0, 0, 0);
    }
#pragma unroll
    for (int q = 0; q < 4; ++q) {
      int t = wv * 16 + lg * 4 + q;
      o[(btb + (size_t)c * 64 + t) * INNER_ + hofs + jb * 16 + l15] = avr[q] + oacc[q];
      R[q] = p63 * R[q] + g1r[q] - gacc[q];
    }
    __syncthreads();
    if (c + 1 < NCH) commit(cur ^ 1);
    cur ^= 1;
  }
}

// ---------------- RMS norm over INNER, * (1+gamma) * gate, -> bf16 -----------
__global__ __launch_bounds__(256) void rmsgate_kernel(const float* __restrict__ o,
    const float* __restrict__ gate, const float* __restrict__ gamma,
    __hip_bfloat16* __restrict__ outn) {
  const int bt = blockIdx.x;
  const int tid = threadIdx.x;
  const size_t base = (size_t)bt * INNER_ + tid * 4;
  float4 ov = *(const float4*)(o + base);
  float ss = ov.x*ov.x + ov.y*ov.y + ov.z*ov.z + ov.w*ov.w;
#pragma unroll
  for (int m = 1; m <= 32; m <<= 1) ss += __shfl_xor(ss, m);
  __shared__ float red[4];
  if ((tid & 63) == 0) red[tid >> 6] = ss;
  __syncthreads();
  float tot = red[0] + red[1] + red[2] + red[3];
  float rms = sqrtf(tot * (1.f / (float)INNER_) + 1e-6f);
  float inv = 1.f / rms;
  float4 gm = *(const float4*)(gamma + tid * 4);
  float4 gt = *(const float4*)(gate + base);
  __hip_bfloat16 t[4];
  t[0] = __float2bfloat16(ov.x * inv * (1.f + gm.x) * gt.x);
  t[1] = __float2bfloat16(ov.y * inv * (1.f + gm.y) * gt.y);
  t[2] = __float2bfloat16(ov.z * inv * (1.f + gm.z) * gt.z);
  t[3] = __float2bfloat16(ov.w * inv * (1.f + gm.w) * gt.w);
  *(uint2*)(outn + base) = *(uint2*)t;
}

// ---------------- launch -----------------------------------------------------
extern "C" void kernel_launch(void* const* d_in, const int* in_sizes, int n_in,
                              void* d_out, int out_size, void* d_ws, size_t ws_size,
                              hipStream_t stream) {
  const float* x   = (const float*)d_in[0];
  const float* Wq  = (const float*)d_in[1];
  const float* Wk  = (const float*)d_in[2];
  const float* Wv  = (const float*)d_in[3];
  const float* Wa  = (const float*)d_in[4];
  const float* ba  = (const float*)d_in[5];
  const float* Wb  = (const float*)d_in[6];
  const float* bb  = (const float*)d_in[7];
  const float* Wg  = (const float*)d_in[8];
  const float* Wo  = (const float*)d_in[9];
  const float* cqw = (const float*)d_in[10];
  const float* cqb = (const float*)d_in[11];
  const float* ckw = (const float*)d_in[12];
  const float* ckb = (const float*)d_in[13];
  const float* cvw = (const float*)d_in[14];
  const float* cvb = (const float*)d_in[15];
  const float* gamma = (const float*)d_in[16];

  float* ws = (float*)d_ws;
  const size_t N1 = (size_t)BT * INNER_;
  float* qpre = ws;
  float* kpre = ws + N1;
  float* vpre = ws + 2 * N1;
  float* gate = ws + 3 * N1;
  float* qn   = ws + 4 * N1;
  float* kn   = ws + 5 * N1;
  float* vn   = ws + 6 * N1;
  float* alpha = ws + 7 * N1;
  float* beta  = alpha + (size_t)BT * H_;
  __hip_bfloat16* wt0 = (__hip_bfloat16*)(beta + (size_t)BT * H_);
  __hip_bfloat16* Wot = wt0 + 4 * (size_t)D_ * INNER_;
  float* P63s = (float*)(Wot + (size_t)D_ * INNER_);
  __hip_bfloat16* Wabt = (__hip_bfloat16*)(P63s + NU);   // [128][1024] bf16
  __hip_bfloat16* xb  = (__hip_bfloat16*)vn;       // dead before convnorm writes vn
  float* AVg = qpre;
  __hip_bfloat16* Zg  = (__hip_bfloat16*)kpre;
  __hip_bfloat16* G2g = Zg + (size_t)NU * 4096;
  float* G1g = vpre;
  float* obuf = qn;
  __hip_bfloat16* nrmb = (__hip_bfloat16*)kn;
  float* outp = (float*)d_out;

  // 1) conversions
  cvt_bf16_kernel<<<(BT * D_ / 4 + 255) / 256, 256, 0, stream>>>(x, xb, BT * D_ / 4);
  dim3 tgrid(INNER_ / 32, D_ / 32);
  transpose_cvt_kernel<<<tgrid, 256, 0, stream>>>(Wq, wt0, D_, INNER_);
  transpose_cvt_kernel<<<tgrid, 256, 0, stream>>>(Wk, wt0 + (size_t)D_ * INNER_, D_, INNER_);
  transpose_cvt_kernel<<<tgrid, 256, 0, stream>>>(Wv, wt0 + 2 * (size_t)D_ * INNER_, D_, INNER_);
  transpose_cvt_kernel<<<tgrid, 256, 0, stream>>>(Wg, wt0 + 3 * (size_t)D_ * INNER_, D_, INNER_);
  transpose_cvt_kernel<<<dim3(D_ / 32, INNER_ / 32), 256, 0, stream>>>(Wo, Wot, INNER_, D_);
  wab_kernel<<<(128 * 1024) / 256, 256, 0, stream>>>(Wa, Wb, Wabt);

  // 2) fused projection GEMM (256^2 2-phase) + alpha/beta mini-GEMM
  gemm256<<<dim3(4 * INNER_ / 256, BT / 256), 512, 0, stream>>>(
      xb, wt0, qpre, BT, 4 * INNER_, D_, 2);
  gemm_ab<<<dim3(1, BT / 128), 256, 0, stream>>>(xb, Wabt, ba, bb, alpha, beta, D_);

  convnorm_kernel<<<BT, 256, 0, stream>>>(qpre, kpre, vpre, cqw, cqb, ckw, ckb,
                                          cvw, cvb, qn, kn, vn);

  // 3) chunked recurrence
  precomp_kernel<<<NU, 256, 0, stream>>>(qn, kn, vn, alpha, beta, Zg, G2g, AVg, G1g, P63s);
  chunkrec_kernel<<<B_ * H_ * 4, 256, 0, stream>>>(Zg, G2g, AVg, G1g, P63s, obuf);

  rmsgate_kernel<<<BT, 256, 0, stream>>>(obuf, gate, gamma, nrmb);
  gemm_bf16<<<dim3(D_ / 128, BT / 128), 256, 0, stream>>>(nrmb, Wot, outp, BT, D_, INNER_, 0);
}

// Round 7
// 370.999 us; speedup vs baseline: 4.5122x; 1.1036x over previous
//
#include <hip/hip_runtime.h>
#include <hip/hip_bf16.h>
#include <cmath>

#define B_ 2
#define T_ 2048
#define D_ 1024
#define H_ 16
#define DH 64
#define INNER_ 1024
#define BT (B_*T_)
#define NCH 32              // chunks per (b,h), chunk length 64
#define NU (B_*H_*NCH)      // 1024 precompute units

typedef __attribute__((ext_vector_type(8))) __bf16 bf16x8;
typedef __attribute__((ext_vector_type(4))) float f32x4;
typedef const __attribute__((address_space(1))) unsigned gas_u32;
typedef __attribute__((address_space(3))) unsigned las_u32;

__device__ __forceinline__ void async16(const void* g, void* l) {
  __builtin_amdgcn_global_load_lds((gas_u32*)g, (las_u32*)l, 16, 0, 0);
}

__device__ __forceinline__ ushort bfr(float x) {
  __hip_bfloat16 t = __float2bfloat16(x);
  return *(ushort*)&t;
}
__device__ __forceinline__ void st_bf4(__hip_bfloat16* p, float a, float b, float c, float d) {
  ushort4 u; u.x = bfr(a); u.y = bfr(b); u.z = bfr(c); u.w = bfr(d);
  *(ushort4*)p = u;
}

// ---------------- convert f32 -> bf16 (elementwise) --------------------------
__global__ __launch_bounds__(256) void cvt_bf16_kernel(const float* __restrict__ in,
                                                       __hip_bfloat16* __restrict__ out,
                                                       int n4) {
  int i = blockIdx.x * 256 + threadIdx.x;
  if (i >= n4) return;
  float4 v = *(const float4*)(in + (size_t)i * 4);
  __hip_bfloat16 t[4];
  t[0] = __float2bfloat16(v.x); t[1] = __float2bfloat16(v.y);
  t[2] = __float2bfloat16(v.z); t[3] = __float2bfloat16(v.w);
  *(uint2*)(out + (size_t)i * 4) = *(uint2*)t;
}

// ---------------- transpose + convert: in [R][C] f32 -> out [C][R] bf16 ------
__global__ __launch_bounds__(256) void transpose_cvt_kernel(const float* __restrict__ in,
                                                            __hip_bfloat16* __restrict__ out,
                                                            int R, int C) {
  __shared__ float tile[32][33];
  const int bc = blockIdx.x * 32, br = blockIdx.y * 32;
  const int tx = threadIdx.x & 31, ty = threadIdx.x >> 5;  // 32 x 8
#pragma unroll
  for (int i = 0; i < 32; i += 8)
    tile[ty + i][tx] = in[(size_t)(br + ty + i) * C + bc + tx];
  __syncthreads();
#pragma unroll
  for (int i = 0; i < 32; i += 8)
    out[(size_t)(bc + ty + i) * R + br + tx] = __float2bfloat16(tile[tx][ty + i]);
}

// ---------------- Wab: pack [Wa|Wb] transposed to [128][1024] bf16 (pad 0) ---
__global__ __launch_bounds__(256) void wab_kernel(const float* __restrict__ Wa,
                                                  const float* __restrict__ Wb,
                                                  __hip_bfloat16* __restrict__ Wabt) {
  int idx = blockIdx.x * 256 + threadIdx.x;  // 128*1024
  int j = idx >> 10, k = idx & 1023;
  float v = 0.f;
  if (j < 16) v = Wa[k * 16 + j];
  else if (j < 32) v = Wb[k * 16 + (j - 16)];
  Wabt[idx] = __float2bfloat16(v);
}

// ---------------- gemm_ab: x @ [Wa|Wb] (N=128 padded), sigmoid epilogue ------
__global__ __launch_bounds__(256) void gemm_ab(const __hip_bfloat16* __restrict__ A,
                                               const __hip_bfloat16* __restrict__ Bt,
                                               const float* __restrict__ ba,
                                               const float* __restrict__ bb2,
                                               float* __restrict__ alpha,
                                               float* __restrict__ beta, int K) {
  __shared__ __hip_bfloat16 As[128 * 32];
  __shared__ __hip_bfloat16 Bs[128 * 32];
  const int tid = threadIdx.x;
  const int lane = tid & 63, wave = tid >> 6;
  const int wr = wave >> 1, wc = wave & 1;
  const int m0 = blockIdx.y * 128;
  const int srow = tid >> 2, skoff = (tid & 3) * 8;
  const int l15 = lane & 15, lg = lane >> 4;

  f32x4 acc[4][2];
#pragma unroll
  for (int m = 0; m < 4; ++m)
#pragma unroll
    for (int n = 0; n < 2; ++n) acc[m][n] = (f32x4)0.f;

  char* asB = (char*)As;
  char* bsB = (char*)Bs;
  const int ldsw = wave * 1024;

  for (int k0 = 0; k0 < K; k0 += 32) {
    async16(A + (size_t)(m0 + srow) * K + k0 + skoff, asB + ldsw);
    async16(A + (size_t)(m0 + 64 + srow) * K + k0 + skoff, asB + 4096 + ldsw);
    async16(Bt + (size_t)srow * K + k0 + skoff, bsB + ldsw);
    async16(Bt + (size_t)(64 + srow) * K + k0 + skoff, bsB + 4096 + ldsw);
    __syncthreads();
    if (wc == 0) {
      bf16x8 af[4], bfg[2];
#pragma unroll
      for (int m = 0; m < 4; ++m)
        af[m] = *(const bf16x8*)(asB + ((wr * 64 + m * 16 + l15) * 32 + lg * 8) * 2);
#pragma unroll
      for (int n = 0; n < 2; ++n)
        bfg[n] = *(const bf16x8*)(bsB + ((n * 16 + l15) * 32 + lg * 8) * 2);
#pragma unroll
      for (int m = 0; m < 4; ++m)
#pragma unroll
        for (int n = 0; n < 2; ++n)
          acc[m][n] = __builtin_amdgcn_mfma_f32_16x16x32_bf16(af[m], bfg[n], acc[m][n], 0, 0, 0);
    }
    __syncthreads();
  }
  if (wc != 0) return;
#pragma unroll
  for (int m = 0; m < 4; ++m) {
    const int rbase = m0 + wr * 64 + m * 16 + lg * 4;
#pragma unroll
    for (int n = 0; n < 2; ++n) {
      const float bias = (n == 0) ? ba[l15] : bb2[l15];
      float* dst = (n == 0) ? alpha : beta;
#pragma unroll
      for (int r = 0; r < 4; ++r) {
        float vv = acc[m][n][r] + bias;
        dst[(size_t)(rbase + r) * H_ + l15] = 1.f / (1.f + expf(-vv));
      }
    }
  }
}

// ---------------- 256^2 2-phase double-buffered bf16 MFMA GEMM ---------------
// act: 0 = plain C[M,N]; 2 = split4 epilogue (N=4096: [q|k|v|g], silu on g).
__device__ __forceinline__ bf16x8 pfrag(const __hip_bfloat16* buf, int row, int ks, int lg) {
  return *(const bf16x8*)((const char*)buf + row * 128 + ks * 64 + lg * 16);
}

__global__ __launch_bounds__(512, 2) void gemm256(const __hip_bfloat16* __restrict__ A,
                                                  const __hip_bfloat16* __restrict__ Bt,
                                                  float* __restrict__ C,
                                                  int M, int N, int K, int act) {
  __shared__ __hip_bfloat16 As[2][256 * 64];
  __shared__ __hip_bfloat16 Bs[2][256 * 64];
  const int tid = threadIdx.x;
  const int lane = tid & 63, wv = tid >> 6;
  const int wr = wv >> 2, wc = wv & 3;
  const int m0 = blockIdx.y * 256, n0 = blockIdx.x * 256;
  const int l15 = lane & 15, lg = lane >> 4;
  const int sr8 = lane >> 3, sc = (lane & 7) * 8;

  f32x4 acc[8][4];
#pragma unroll
  for (int m = 0; m < 8; ++m)
#pragma unroll
    for (int n = 0; n < 4; ++n) acc[m][n] = (f32x4)0.f;

  auto stage = [&](int kt, int bsel) {
    const size_t k0 = (size_t)kt * 64;
    const __hip_bfloat16* Ab = A + (size_t)(m0 + wv * 8 + sr8) * K + k0 + sc;
    const __hip_bfloat16* Bb = Bt + (size_t)(n0 + wv * 8 + sr8) * K + k0 + sc;
    char* al = (char*)As[bsel] + wv * 1024;
    char* bl = (char*)Bs[bsel] + wv * 1024;
#pragma unroll
    for (int q = 0; q < 4; ++q) {
      async16(Ab + (size_t)q * 64 * K, al + q * 8192);
      async16(Bb + (size_t)q * 64 * K, bl + q * 8192);
    }
  };

  const int NT = K >> 6;
  stage(0, 0);
  __syncthreads();
  int cur = 0;
  for (int kt = 0; kt < NT; ++kt) {
    if (kt + 1 < NT) stage(kt + 1, cur ^ 1);
#pragma unroll
    for (int ks = 0; ks < 2; ++ks) {
      bf16x8 af[8], bfg[4];
#pragma unroll
      for (int m = 0; m < 8; ++m)
        af[m] = pfrag(As[cur], wr * 128 + m * 16 + l15, ks, lg);
#pragma unroll
      for (int n = 0; n < 4; ++n)
        bfg[n] = pfrag(Bs[cur], wc * 64 + n * 16 + l15, ks, lg);
#pragma unroll
      for (int m = 0; m < 8; ++m)
#pragma unroll
        for (int n = 0; n < 4; ++n)
          acc[m][n] = __builtin_amdgcn_mfma_f32_16x16x32_bf16(af[m], bfg[n], acc[m][n], 0, 0, 0);
    }
    __syncthreads();
    cur ^= 1;
  }

#pragma unroll
  for (int m = 0; m < 8; ++m) {
    const int rbase = m0 + wr * 128 + m * 16 + lg * 4;
#pragma unroll
    for (int n = 0; n < 4; ++n) {
      const int col = n0 + wc * 64 + n * 16 + l15;
      if (act == 2) {
        const int which = col >> 10;
        const int ncol = col & 1023;
        float* dst = C + (size_t)which * ((size_t)BT * INNER_) +
                     (size_t)rbase * 1024 + ncol;
#pragma unroll
        for (int r = 0; r < 4; ++r) {
          float vv = acc[m][n][r];
          if (which == 3) vv = vv / (1.f + expf(-vv));
          dst[(size_t)r * 1024] = vv;
        }
      } else {
#pragma unroll
        for (int r = 0; r < 4; ++r)
          C[(size_t)(rbase + r) * N + col] = acc[m][n][r];
      }
    }
  }
}

// ---------------- depthwise causal conv (K=4) + silu + optional l2norm -------
__global__ __launch_bounds__(256) void convnorm_kernel(
    const float* __restrict__ qpre, const float* __restrict__ kpre, const float* __restrict__ vpre,
    const float* __restrict__ cqw, const float* __restrict__ cqb,
    const float* __restrict__ ckw, const float* __restrict__ ckb,
    const float* __restrict__ cvw, const float* __restrict__ cvb,
    float* __restrict__ qn, float* __restrict__ kn, float* __restrict__ vn) {
  const int bt = blockIdx.x;
  const int t = bt & (T_ - 1);
  const int tid = threadIdx.x;
  const int c = tid * 4;

  auto run = [&](const float* __restrict__ pre, const float* __restrict__ w,
                 const float* __restrict__ bias, float* __restrict__ out, bool norm) {
    float r[4];
    float4 bv = *(const float4*)(bias + c);
    r[0] = bv.x; r[1] = bv.y; r[2] = bv.z; r[3] = bv.w;
    float wl[4][4];
#pragma unroll
    for (int i = 0; i < 4; ++i) {
      float4 wv = *(const float4*)(w + (size_t)(c + i) * 4);
      wl[i][0] = wv.x; wl[i][1] = wv.y; wl[i][2] = wv.z; wl[i][3] = wv.w;
    }
#pragma unroll
    for (int kk = 0; kk < 4; ++kk) {
      int tt = t - 3 + kk;
      if (tt >= 0) {
        float4 xv = *(const float4*)(pre + (size_t)(bt - 3 + kk) * INNER_ + c);
        float xa[4] = {xv.x, xv.y, xv.z, xv.w};
#pragma unroll
        for (int i = 0; i < 4; ++i) r[i] += xa[i] * wl[i][kk];
      }
    }
#pragma unroll
    for (int i = 0; i < 4; ++i) r[i] = r[i] / (1.f + expf(-r[i]));
    if (norm) {
      float ss = r[0]*r[0] + r[1]*r[1] + r[2]*r[2] + r[3]*r[3];
      ss += __shfl_xor(ss, 1); ss += __shfl_xor(ss, 2);
      ss += __shfl_xor(ss, 4); ss += __shfl_xor(ss, 8);
      float n = sqrtf(ss);
      float sc = 1.f / fmaxf(n, 1e-12f);
#pragma unroll
      for (int i = 0; i < 4; ++i) r[i] *= sc;
    }
    float4 ov = {r[0], r[1], r[2], r[3]};
    *(float4*)(out + (size_t)bt * INNER_ + c) = ov;
  };

  run(qpre, cqw, cqb, qn, true);
  run(kpre, ckw, ckb, kn, true);
  run(vpre, cvw, cvb, vn, false);
}

// =============================================================================
// Chunked gated-delta (WY form) precompute, block-triangular solve:
//   (I+M) X = [Kb | Vb]  (128-wide combined RHS), X = [W | Vt]
// sXT holds X^T (128 x 64). Level I (16 rows):
//   update: R'^T[c][t] = RHS^T[c][t] - sum_s X^T[c][s] M[t][s]   (MFMA, bf16 M
//           with DIAG BANDS ZEROED so K-windows pad safely)
//   diag:   16-step scalar substitution, 128 lanes = columns, f32 M diag (sMd)
// =============================================================================
#define BST 72

__device__ __forceinline__ bf16x8 fragld(const __hip_bfloat16* buf, int row, int kk, int lg) {
  return *(const bf16x8*)(buf + row * BST + kk * 32 + lg * 8);
}

__global__ __launch_bounds__(256, 2) void precomp_kernel(
    const float* __restrict__ qn, const float* __restrict__ kn, const float* __restrict__ vn,
    const float* __restrict__ alpha, const float* __restrict__ beta,
    __hip_bfloat16* __restrict__ Zg, __hip_bfloat16* __restrict__ G2g,
    float* __restrict__ AVg, float* __restrict__ G1g, float* __restrict__ P63g) {
  __shared__ __hip_bfloat16 sKb[64 * BST], sKip[64 * BST], sKipT[64 * BST];
  __shared__ __hip_bfloat16 sQp[64 * BST], sAttn[64 * BST];
  __shared__ __hip_bfloat16 sXT[128 * BST];   // X^T: rows 0..63 = W^T, 64..127 = Vt^T
  __shared__ __hip_bfloat16 sM[64 * BST];     // bf16 M, diag 16x16 bands zeroed
  __shared__ float sMd[4][16][16];            // f32 diag bands (strict lower)
  __shared__ float sP[64], sIP[64], sBP[64], sB[64];

  const int u = blockIdx.x;
  const int bh = u >> 5, c = u & 31;
  const int b = bh >> 4, h = bh & 15;
  const int tid = threadIdx.x, lane = tid & 63, wv = tid >> 6;
  const int l15 = lane & 15, lg = lane >> 4;
  const size_t bt0 = (size_t)b * T_ + (size_t)c * 64;
  const size_t hofs = (size_t)h * DH;

  // ---- phase 0: decay cumprods
  if (wv == 0) {
    float a = alpha[(bt0 + lane) * H_ + h];
    float bb = beta[(bt0 + lane) * H_ + h];
    float la = logf(a);
#pragma unroll
    for (int d = 1; d < 64; d <<= 1) {
      float y = __shfl_up(la, d);
      if (lane >= d) la += y;
    }
    float P = expf(la);
    sP[lane] = P;
    sIP[lane] = 1.f / P;
    sBP[lane] = bb * P;
    sB[lane] = bb;
    if (lane == 63) P63g[u] = P;
  }
  __syncthreads();

  // ---- phase 1: stage scaled K,Q (row), Kip^T, and RHS^T into sXT
#pragma unroll
  for (int i = 0; i < 4; ++i) {
    int e = tid + i * 256;
    int row = e >> 4, c4 = (e & 15) * 4;
    size_t g = (bt0 + row) * INNER_ + hofs + c4;
    float4 kv = *(const float4*)(kn + g);
    float4 qv = *(const float4*)(qn + g);
    float4 vv = *(const float4*)(vn + g);
    float bp = sBP[row], ip = sIP[row], pp = sP[row], bo = sB[row];
    st_bf4(&sKb[row * BST + c4], kv.x * bp, kv.y * bp, kv.z * bp, kv.w * bp);
    st_bf4(&sKip[row * BST + c4], kv.x * ip, kv.y * ip, kv.z * ip, kv.w * ip);
    st_bf4(&sQp[row * BST + c4], qv.x * pp, qv.y * pp, qv.z * pp, qv.w * pp);
    sKipT[(c4 + 0) * BST + row] = __float2bfloat16(kv.x * ip);
    sKipT[(c4 + 1) * BST + row] = __float2bfloat16(kv.y * ip);
    sKipT[(c4 + 2) * BST + row] = __float2bfloat16(kv.z * ip);
    sKipT[(c4 + 3) * BST + row] = __float2bfloat16(kv.w * ip);
    // RHS^T: cols 0..63 = Kb^T (W solve), 64..127 = Vb^T (Vt solve)
    sXT[(c4 + 0) * BST + row] = __float2bfloat16(kv.x * bp);
    sXT[(c4 + 1) * BST + row] = __float2bfloat16(kv.y * bp);
    sXT[(c4 + 2) * BST + row] = __float2bfloat16(kv.z * bp);
    sXT[(c4 + 3) * BST + row] = __float2bfloat16(kv.w * bp);
    sXT[(64 + c4 + 0) * BST + row] = __float2bfloat16(vv.x * bo);
    sXT[(64 + c4 + 1) * BST + row] = __float2bfloat16(vv.y * bo);
    sXT[(64 + c4 + 2) * BST + row] = __float2bfloat16(vv.z * bo);
    sXT[(64 + c4 + 3) * BST + row] = __float2bfloat16(vv.w * bo);
  }
  __syncthreads();

  // ---- phase 2: M (waves 0,1) and Attn (waves 2,3)
  if (wv < 2) {
#pragma unroll
    for (int tt = wv * 2; tt < wv * 2 + 2; ++tt) {
      for (int n = 0; n <= tt; ++n) {
        f32x4 acc = (f32x4)0.f;
#pragma unroll
        for (int kk = 0; kk < 2; ++kk)
          acc = __builtin_amdgcn_mfma_f32_16x16x32_bf16(
              fragld(sKb, tt * 16 + l15, kk, lg), fragld(sKip, n * 16 + l15, kk, lg), acc, 0, 0, 0);
        if (n < tt) {
#pragma unroll
          for (int q = 0; q < 4; ++q)
            sM[(tt * 16 + lg * 4 + q) * BST + n * 16 + l15] = __float2bfloat16(acc[q]);
        } else {
#pragma unroll
          for (int q = 0; q < 4; ++q) {
            int rr = lg * 4 + q;
            sMd[tt][rr][l15] = (l15 < rr) ? acc[q] : 0.f;
            sM[(tt * 16 + rr) * BST + tt * 16 + l15] = __float2bfloat16(0.f);
          }
        }
      }
    }
  } else {
#pragma unroll
    for (int tt = (wv - 2) * 2; tt < (wv - 2) * 2 + 2; ++tt) {
      for (int n = 0; n < 4; ++n) {
        if (n <= tt) {
          f32x4 acc = (f32x4)0.f;
#pragma unroll
          for (int kk = 0; kk < 2; ++kk)
            acc = __builtin_amdgcn_mfma_f32_16x16x32_bf16(
                fragld(sQp, tt * 16 + l15, kk, lg), fragld(sKip, n * 16 + l15, kk, lg), acc, 0, 0, 0);
#pragma unroll
          for (int q = 0; q < 4; ++q) {
            int r = tt * 16 + lg * 4 + q, cl = n * 16 + l15;
            sAttn[r * BST + cl] = __float2bfloat16((cl <= r) ? acc[q] : 0.f);
          }
        } else {
#pragma unroll
          for (int q = 0; q < 4; ++q)
            sAttn[(tt * 16 + lg * 4 + q) * BST + n * 16 + l15] = __float2bfloat16(0.f);
        }
      }
    }
  }
  __syncthreads();

  // ---- phase 3: block-triangular solve, X^T in sXT
  auto diag_solve = [&](int I) {
    if (wv < 2) {
      const int cc = wv * 64 + lane;   // column 0..127
      float x[16];
#pragma unroll
      for (int t = 0; t < 16; ++t) {
        float r = __bfloat162float(sXT[cc * BST + I * 16 + t]);
#pragma unroll
        for (int s = 0; s < t; ++s) r -= sMd[I][t][s] * x[s];
        x[t] = r;
        sXT[cc * BST + I * 16 + t] = __float2bfloat16(r);
      }
    }
  };

  diag_solve(0);
  __syncthreads();
#pragma unroll
  for (int I = 1; I < 4; ++I) {
    const int KK = (I == 3) ? 2 : 1;   // K window = ceil(16I/32)*32, diag zeroed
#pragma unroll
    for (int ct2 = 0; ct2 < 2; ++ct2) {
      const int ct = wv * 2 + ct2;     // c row-tile of sXT (8 tiles / 4 waves)
      f32x4 uacc = (f32x4)0.f;
#pragma unroll
      for (int kk = 0; kk < KK; ++kk)
        uacc = __builtin_amdgcn_mfma_f32_16x16x32_bf16(
            fragld(sXT, ct * 16 + l15, kk, lg), fragld(sM, I * 16 + l15, kk, lg), uacc, 0, 0, 0);
#pragma unroll
      for (int q = 0; q < 4; ++q) {
        const int cc = ct * 16 + lg * 4 + q, t = I * 16 + l15;
        float old = __bfloat162float(sXT[cc * BST + t]);
        sXT[cc * BST + t] = __float2bfloat16(old - uacc[q]);
      }
    }
    __syncthreads();
    diag_solve(I);
    __syncthreads();
  }

  // ---- phase 4: outputs. wave wv -> row band tt = wv.
  const float p63 = sP[63];
  const int tt = wv;
  const size_t go = (size_t)u * 4096;
#pragma unroll
  for (int n = 0; n < 4; ++n) {
    f32x4 av = (f32x4)0.f, aw = (f32x4)0.f, g1 = (f32x4)0.f, g2 = (f32x4)0.f;
#pragma unroll
    for (int kk = 0; kk < 2; ++kk) {
      bf16x8 at = fragld(sAttn, tt * 16 + l15, kk, lg);
      bf16x8 kt = fragld(sKipT, tt * 16 + l15, kk, lg);
      bf16x8 bv = fragld(sXT, 64 + n * 16 + l15, kk, lg);   // Vt^T
      bf16x8 bw = fragld(sXT, n * 16 + l15, kk, lg);        // W^T
      av = __builtin_amdgcn_mfma_f32_16x16x32_bf16(at, bv, av, 0, 0, 0);
      aw = __builtin_amdgcn_mfma_f32_16x16x32_bf16(at, bw, aw, 0, 0, 0);
      g1 = __builtin_amdgcn_mfma_f32_16x16x32_bf16(kt, bv, g1, 0, 0, 0);
      g2 = __builtin_amdgcn_mfma_f32_16x16x32_bf16(kt, bw, g2, 0, 0, 0);
    }
#pragma unroll
    for (int q = 0; q < 4; ++q) {
      int r = tt * 16 + lg * 4 + q, cl = n * 16 + l15;
      AVg[go + r * 64 + cl] = av[q];
      float qp = __bfloat162float(sQp[r * BST + cl]);
      Zg[go + r * 64 + cl] = __float2bfloat16(qp - aw[q]);
      G1g[go + cl * 64 + r] = p63 * g1[q];
      G2g[go + r * 64 + cl] = __float2bfloat16(p63 * g2[q]);
    }
  }
}

// ---------------- serial chunk recurrence, row-partitioned -------------------
__device__ __forceinline__ bf16x8 sfrag(const __hip_bfloat16* buf, int row, int kk, int lg) {
  int byte = row * 128 + kk * 64 + lg * 16;
  byte ^= (row & 7) << 4;
  return *(const bf16x8*)((const char*)buf + byte);
}

__global__ __launch_bounds__(256) void chunkrec_kernel(
    const __hip_bfloat16* __restrict__ Zg, const __hip_bfloat16* __restrict__ G2g,
    const float* __restrict__ AVg, const float* __restrict__ G1g,
    const float* __restrict__ P63g, float* __restrict__ o) {
  __shared__ __align__(16) __hip_bfloat16 sR[16 * 64];
  __shared__ __align__(16) __hip_bfloat16 sZ[2][64 * 64];
  __shared__ __align__(16) __hip_bfloat16 sG2[2][64 * 64];
  const int blk = blockIdx.x;
  const int bh = blk >> 2;
  const int jb = blk & 3;
  const int b = bh >> 4, h = bh & 15;
  const int tid = threadIdx.x, lane = tid & 63, wv = tid >> 6;
  const int l15 = lane & 15, lg = lane >> 4;
  const size_t btb = (size_t)b * T_;
  const size_t hofs = (size_t)h * DH;

  f32x4 R = (f32x4)0.f;

  uint4 zr[2], gr[2];
  const int e0 = tid * 2;

  auto issue = [&](int c) {
    size_t ub = ((size_t)bh * NCH + c) * 4096;
#pragma unroll
    for (int i = 0; i < 2; ++i) {
      zr[i] = *(const uint4*)(Zg + ub + (size_t)(e0 + i) * 8);
      gr[i] = *(const uint4*)(G2g + ub + (size_t)(e0 + i) * 8);
    }
  };
  auto commit = [&](int buf) {
#pragma unroll
    for (int i = 0; i < 2; ++i) {
      int e = e0 + i;
      int row = e >> 3, colb = (e & 7) * 16;
      int byte = (row * 128 + colb) ^ ((row & 7) << 4);
      *(uint4*)((char*)sZ[buf] + byte) = zr[i];
      *(uint4*)((char*)sG2[buf] + byte) = gr[i];
    }
  };

  issue(0);
  commit(0);
  int cur = 0;
  for (int c = 0; c < NCH; ++c) {
#pragma unroll
    for (int q = 0; q < 4; ++q) {
      int i = lg * 4 + q;
      int byte = (i * 128 + (wv * 16 + l15) * 2) ^ ((i & 7) << 4);
      *(__hip_bfloat16*)((char*)sR + byte) = __float2bfloat16(R[q]);
    }
    __syncthreads();

    const size_t ub = ((size_t)bh * NCH + c) * 4096;
    float avr[4], g1r[4];
#pragma unroll
    for (int q = 0; q < 4; ++q) {
      int t = wv * 16 + lg * 4 + q;
      avr[q] = AVg[ub + t * 64 + jb * 16 + l15];
      g1r[q] = G1g[ub + (jb * 16 + lg * 4 + q) * 64 + wv * 16 + l15];
    }
    float p63 = P63g[(size_t)bh * NCH + c];
    if (c + 1 < NCH) issue(c + 1);

    bf16x8 zA[2], rF[2], gB[2];
#pragma unroll
    for (int kk = 0; kk < 2; ++kk) {
      zA[kk] = sfrag(sZ[cur], wv * 16 + l15, kk, lg);
      rF[kk] = sfrag(sR, l15, kk, lg);
      gB[kk] = sfrag(sG2[cur], wv * 16 + l15, kk, lg);
    }
    f32x4 oacc = (f32x4)0.f, gacc = (f32x4)0.f;
#pragma unroll
    for (int kk = 0; kk < 2; ++kk) {
      oacc = __builtin_amdgcn_mfma_f32_16x16x32_bf16(zA[kk], rF[kk], oacc, 0, 0, 0);
      gacc = __builtin_amdgcn_mfma_f32_16x16x32_bf16(rF[kk], gB[kk], gacc, 0, 0, 0);
    }
#pragma unroll
    for (int q = 0; q < 4; ++q) {
      int t = wv * 16 + lg * 4 + q;
      o[(btb + (size_t)c * 64 + t) * INNER_ + hofs + jb * 16 + l15] = avr[q] + oacc[q];
      R[q] = p63 * R[q] + g1r[q] - gacc[q];
    }
    __syncthreads();
    if (c + 1 < NCH) commit(cur ^ 1);
    cur ^= 1;
  }
}

// ---------------- RMS norm over INNER, * (1+gamma) * gate, -> bf16 -----------
__global__ __launch_bounds__(256) void rmsgate_kernel(const float* __restrict__ o,
    const float* __restrict__ gate, const float* __restrict__ gamma,
    __hip_bfloat16* __restrict__ outn) {
  const int bt = blockIdx.x;
  const int tid = threadIdx.x;
  const size_t base = (size_t)bt * INNER_ + tid * 4;
  float4 ov = *(const float4*)(o + base);
  float ss = ov.x*ov.x + ov.y*ov.y + ov.z*ov.z + ov.w*ov.w;
#pragma unroll
  for (int m = 1; m <= 32; m <<= 1) ss += __shfl_xor(ss, m);
  __shared__ float red[4];
  if ((tid & 63) == 0) red[tid >> 6] = ss;
  __syncthreads();
  float tot = red[0] + red[1] + red[2] + red[3];
  float rms = sqrtf(tot * (1.f / (float)INNER_) + 1e-6f);
  float inv = 1.f / rms;
  float4 gm = *(const float4*)(gamma + tid * 4);
  float4 gt = *(const float4*)(gate + base);
  __hip_bfloat16 t[4];
  t[0] = __float2bfloat16(ov.x * inv * (1.f + gm.x) * gt.x);
  t[1] = __float2bfloat16(ov.y * inv * (1.f + gm.y) * gt.y);
  t[2] = __float2bfloat16(ov.z * inv * (1.f + gm.z) * gt.z);
  t[3] = __float2bfloat16(ov.w * inv * (1.f + gm.w) * gt.w);
  *(uint2*)(outn + base) = *(uint2*)t;
}

// ---------------- launch -----------------------------------------------------
extern "C" void kernel_launch(void* const* d_in, const int* in_sizes, int n_in,
                              void* d_out, int out_size, void* d_ws, size_t ws_size,
                              hipStream_t stream) {
  const float* x   = (const float*)d_in[0];
  const float* Wq  = (const float*)d_in[1];
  const float* Wk  = (const float*)d_in[2];
  const float* Wv  = (const float*)d_in[3];
  const float* Wa  = (const float*)d_in[4];
  const float* ba  = (const float*)d_in[5];
  const float* Wb  = (const float*)d_in[6];
  const float* bb  = (const float*)d_in[7];
  const float* Wg  = (const float*)d_in[8];
  const float* Wo  = (const float*)d_in[9];
  const float* cqw = (const float*)d_in[10];
  const float* cqb = (const float*)d_in[11];
  const float* ckw = (const float*)d_in[12];
  const float* ckb = (const float*)d_in[13];
  const float* cvw = (const float*)d_in[14];
  const float* cvb = (const float*)d_in[15];
  const float* gamma = (const float*)d_in[16];

  float* ws = (float*)d_ws;
  const size_t N1 = (size_t)BT * INNER_;
  float* qpre = ws;
  float* kpre = ws + N1;
  float* vpre = ws + 2 * N1;
  float* gate = ws + 3 * N1;
  float* qn   = ws + 4 * N1;
  float* kn   = ws + 5 * N1;
  float* vn   = ws + 6 * N1;
  float* alpha = ws + 7 * N1;
  float* beta  = alpha + (size_t)BT * H_;
  __hip_bfloat16* wt0 = (__hip_bfloat16*)(beta + (size_t)BT * H_);
  __hip_bfloat16* Wot = wt0 + 4 * (size_t)D_ * INNER_;
  float* P63s = (float*)(Wot + (size_t)D_ * INNER_);
  __hip_bfloat16* Wabt = (__hip_bfloat16*)(P63s + NU);
  __hip_bfloat16* xb  = (__hip_bfloat16*)vn;
  float* AVg = qpre;
  __hip_bfloat16* Zg  = (__hip_bfloat16*)kpre;
  __hip_bfloat16* G2g = Zg + (size_t)NU * 4096;
  float* G1g = vpre;
  float* obuf = qn;
  __hip_bfloat16* nrmb = (__hip_bfloat16*)kn;
  float* outp = (float*)d_out;

  // 1) conversions
  cvt_bf16_kernel<<<(BT * D_ / 4 + 255) / 256, 256, 0, stream>>>(x, xb, BT * D_ / 4);
  dim3 tgrid(INNER_ / 32, D_ / 32);
  transpose_cvt_kernel<<<tgrid, 256, 0, stream>>>(Wq, wt0, D_, INNER_);
  transpose_cvt_kernel<<<tgrid, 256, 0, stream>>>(Wk, wt0 + (size_t)D_ * INNER_, D_, INNER_);
  transpose_cvt_kernel<<<tgrid, 256, 0, stream>>>(Wv, wt0 + 2 * (size_t)D_ * INNER_, D_, INNER_);
  transpose_cvt_kernel<<<tgrid, 256, 0, stream>>>(Wg, wt0 + 3 * (size_t)D_ * INNER_, D_, INNER_);
  transpose_cvt_kernel<<<dim3(D_ / 32, INNER_ / 32), 256, 0, stream>>>(Wo, Wot, INNER_, D_);
  wab_kernel<<<(128 * 1024) / 256, 256, 0, stream>>>(Wa, Wb, Wabt);

  // 2) fused projection GEMM (256^2 2-phase) + alpha/beta mini-GEMM
  gemm256<<<dim3(4 * INNER_ / 256, BT / 256), 512, 0, stream>>>(
      xb, wt0, qpre, BT, 4 * INNER_, D_, 2);
  gemm_ab<<<dim3(1, BT / 128), 256, 0, stream>>>(xb, Wabt, ba, bb, alpha, beta, D_);

  convnorm_kernel<<<BT, 256, 0, stream>>>(qpre, kpre, vpre, cqw, cqb, ckw, ckb,
                                          cvw, cvb, qn, kn, vn);

  // 3) chunked recurrence
  precomp_kernel<<<NU, 256, 0, stream>>>(qn, kn, vn, alpha, beta, Zg, G2g, AVg, G1g, P63s);
  chunkrec_kernel<<<B_ * H_ * 4, 256, 0, stream>>>(Zg, G2g, AVg, G1g, P63s, obuf);

  rmsgate_kernel<<<BT, 256, 0, stream>>>(obuf, gate, gamma, nrmb);

  // 4) out-projection (256^2 2-phase)
  gemm256<<<dim3(D_ / 256, BT / 256), 512, 0, stream>>>(nrmb, Wot, outp, BT, D_, INNER_, 0);
}

// Round 8
// 365.126 us; speedup vs baseline: 4.5848x; 1.0161x over previous
//
#include <hip/hip_runtime.h>
#include <hip/hip_bf16.h>
#include <cmath>

#define B_ 2
#define T_ 2048
#define D_ 1024
#define H_ 16
#define DH 64
#define INNER_ 1024
#define BT (B_*T_)
#define NCH 32              // chunks per (b,h), chunk length 64
#define NU (B_*H_*NCH)      // 1024 precompute units
#define N1 ((size_t)BT * INNER_)

typedef __attribute__((ext_vector_type(8))) __bf16 bf16x8;
typedef __attribute__((ext_vector_type(4))) float f32x4;
typedef const __attribute__((address_space(1))) unsigned gas_u32;
typedef __attribute__((address_space(3))) unsigned las_u32;

__device__ __forceinline__ void async16(const void* g, void* l) {
  __builtin_amdgcn_global_load_lds((gas_u32*)g, (las_u32*)l, 16, 0, 0);
}

__device__ __forceinline__ ushort bfr(float x) {
  __hip_bfloat16 t = __float2bfloat16(x);
  return *(ushort*)&t;
}
__device__ __forceinline__ void st_bf4(__hip_bfloat16* p, float a, float b, float c, float d) {
  ushort4 u; u.x = bfr(a); u.y = bfr(b); u.z = bfr(c); u.w = bfr(d);
  *(ushort4*)p = u;
}
__device__ __forceinline__ float b2f(ushort s) {
  return __uint_as_float(((unsigned)s) << 16);
}

// ---------------- prep: cvt x->bf16, 5 weight transposes, Wab pad-pack -------
// grid: [0,4096) cvt x | [4096,9216) transposes (5 x 1024) | [9216,10240) Wab
__global__ __launch_bounds__(256) void prep_kernel(
    const float* __restrict__ x,
    const float* __restrict__ Wq, const float* __restrict__ Wk,
    const float* __restrict__ Wv, const float* __restrict__ Wg,
    const float* __restrict__ Wo, const float* __restrict__ Wa,
    const float* __restrict__ Wb,
    __hip_bfloat16* __restrict__ xb, __hip_bfloat16* __restrict__ wtall,
    __hip_bfloat16* __restrict__ Wot) {
  __shared__ float tile[32][33];
  const int bid = blockIdx.x, tid = threadIdx.x;
  if (bid < 4096) {
    int i = bid * 256 + tid;
    float4 v = *(const float4*)(x + (size_t)i * 4);
    st_bf4(xb + (size_t)i * 4, v.x, v.y, v.z, v.w);
    return;
  }
  if (bid < 9216) {
    int wi = (bid - 4096) >> 10;
    int t = (bid - 4096) & 1023;
    const float* src = wi == 0 ? Wq : wi == 1 ? Wk : wi == 2 ? Wv : wi == 3 ? Wg : Wo;
    __hip_bfloat16* dst = (wi < 4) ? (wtall + (size_t)wi * 1024 * 1024) : Wot;
    const int bc = (t & 31) * 32, br = (t >> 5) * 32;
    const int tx = tid & 31, ty = tid >> 5;
#pragma unroll
    for (int i2 = 0; i2 < 32; i2 += 8)
      tile[ty + i2][tx] = src[(size_t)(br + ty + i2) * 1024 + bc + tx];
    __syncthreads();
#pragma unroll
    for (int i2 = 0; i2 < 32; i2 += 8)
      dst[(size_t)(bc + ty + i2) * 1024 + br + tx] = __float2bfloat16(tile[tx][ty + i2]);
    return;
  }
  int idx = (bid - 9216) * 256 + tid;  // 0..262143, rows 4096..4351 of wtall
  int j = idx >> 10, k2 = idx & 1023;
  float v = 0.f;
  if (j < 16) v = Wa[k2 * 16 + j];
  else if (j < 32) v = Wb[k2 * 16 + (j - 16)];
  wtall[(size_t)4096 * 1024 + idx] = __float2bfloat16(v);
}

// ---------------- 256^2 2-phase double-buffered bf16 MFMA GEMM ---------------
// act 0: Cf[M][N] f32.   act 2: N=4352 fused epilogue: cols [q|k|v|g] -> bf16
// (silu on g), cols 4096..4127 -> sigmoid(+bias) alpha/beta [BT][16].
__device__ __forceinline__ bf16x8 pfrag(const __hip_bfloat16* buf, int row, int ks, int lg) {
  return *(const bf16x8*)((const char*)buf + row * 128 + ks * 64 + lg * 16);
}

__global__ __launch_bounds__(512, 2) void gemm256(const __hip_bfloat16* __restrict__ A,
                                                  const __hip_bfloat16* __restrict__ Bt,
                                                  float* __restrict__ Cf,
                                                  __hip_bfloat16* __restrict__ Cb,
                                                  float* __restrict__ alpha,
                                                  float* __restrict__ beta,
                                                  const float* __restrict__ ba,
                                                  const float* __restrict__ bb2,
                                                  int M, int N, int K, int act) {
  __shared__ __hip_bfloat16 As[2][256 * 64];
  __shared__ __hip_bfloat16 Bs[2][256 * 64];
  const int tid = threadIdx.x;
  const int lane = tid & 63, wv = tid >> 6;
  const int wr = wv >> 2, wc = wv & 3;
  const int m0 = blockIdx.y * 256, n0 = blockIdx.x * 256;
  const int l15 = lane & 15, lg = lane >> 4;
  const int sr8 = lane >> 3, sc = (lane & 7) * 8;

  f32x4 acc[8][4];
#pragma unroll
  for (int m = 0; m < 8; ++m)
#pragma unroll
    for (int n = 0; n < 4; ++n) acc[m][n] = (f32x4)0.f;

  auto stage = [&](int kt, int bsel) {
    const size_t k0 = (size_t)kt * 64;
    const __hip_bfloat16* Ab = A + (size_t)(m0 + wv * 8 + sr8) * K + k0 + sc;
    const __hip_bfloat16* Bb = Bt + (size_t)(n0 + wv * 8 + sr8) * K + k0 + sc;
    char* al = (char*)As[bsel] + wv * 1024;
    char* bl = (char*)Bs[bsel] + wv * 1024;
#pragma unroll
    for (int q = 0; q < 4; ++q) {
      async16(Ab + (size_t)q * 64 * K, al + q * 8192);
      async16(Bb + (size_t)q * 64 * K, bl + q * 8192);
    }
  };

  const int NT = K >> 6;
  stage(0, 0);
  __syncthreads();
  int cur = 0;
  for (int kt = 0; kt < NT; ++kt) {
    if (kt + 1 < NT) stage(kt + 1, cur ^ 1);
#pragma unroll
    for (int ks = 0; ks < 2; ++ks) {
      bf16x8 af[8], bfg[4];
#pragma unroll
      for (int m = 0; m < 8; ++m)
        af[m] = pfrag(As[cur], wr * 128 + m * 16 + l15, ks, lg);
#pragma unroll
      for (int n = 0; n < 4; ++n)
        bfg[n] = pfrag(Bs[cur], wc * 64 + n * 16 + l15, ks, lg);
#pragma unroll
      for (int m = 0; m < 8; ++m)
#pragma unroll
        for (int n = 0; n < 4; ++n)
          acc[m][n] = __builtin_amdgcn_mfma_f32_16x16x32_bf16(af[m], bfg[n], acc[m][n], 0, 0, 0);
    }
    __syncthreads();
    cur ^= 1;
  }

#pragma unroll
  for (int m = 0; m < 8; ++m) {
    const int rbase = m0 + wr * 128 + m * 16 + lg * 4;
#pragma unroll
    for (int n = 0; n < 4; ++n) {
      const int col = n0 + wc * 64 + n * 16 + l15;
      if (act == 2) {
        if (col < 4096) {
          const int which = col >> 10;
          const int ncol = col & 1023;
          __hip_bfloat16* dst = Cb + (size_t)which * N1 + (size_t)rbase * 1024 + ncol;
#pragma unroll
          for (int r = 0; r < 4; ++r) {
            float vv = acc[m][n][r];
            if (which == 3) vv = vv / (1.f + expf(-vv));  // silu on gate
            dst[(size_t)r * 1024] = __float2bfloat16(vv);
          }
        } else {
          const int ncol = col - 4096;
          if (ncol < 32) {
            const float bias = (ncol < 16) ? ba[ncol] : bb2[ncol - 16];
            float* dst = (ncol < 16) ? (alpha + ncol) : (beta + (ncol - 16));
#pragma unroll
            for (int r = 0; r < 4; ++r)
              dst[(size_t)(rbase + r) * H_] = 1.f / (1.f + expf(-(acc[m][n][r] + bias)));
          }
        }
      } else {
#pragma unroll
        for (int r = 0; r < 4; ++r)
          Cf[(size_t)(rbase + r) * N + col] = acc[m][n][r];
      }
    }
  }
}

// =============================================================================
// Chunked gated-delta (WY form) precompute with FUSED depthwise conv + silu +
// l2norm in the staging phase (inputs are raw bf16 projections).
// Block-triangular solve for (I+M)X=[Kb|Vb] as in round 7 (verified).
// =============================================================================
#define BST 72

__device__ __forceinline__ bf16x8 fragld(const __hip_bfloat16* buf, int row, int kk, int lg) {
  return *(const bf16x8*)(buf + row * BST + kk * 32 + lg * 8);
}

__global__ __launch_bounds__(256, 2) void precomp_kernel(
    const __hip_bfloat16* __restrict__ qpre, const __hip_bfloat16* __restrict__ kpre,
    const __hip_bfloat16* __restrict__ vpre,
    const float* __restrict__ alpha, const float* __restrict__ beta,
    const float* __restrict__ cqw, const float* __restrict__ cqb,
    const float* __restrict__ ckw, const float* __restrict__ ckb,
    const float* __restrict__ cvw, const float* __restrict__ cvb,
    __hip_bfloat16* __restrict__ Zg, __hip_bfloat16* __restrict__ G2g,
    float* __restrict__ AVg, float* __restrict__ G1g, float* __restrict__ P63g) {
  __shared__ __hip_bfloat16 sKb[64 * BST], sKip[64 * BST], sKipT[64 * BST];
  __shared__ __hip_bfloat16 sQp[64 * BST], sAttn[64 * BST];
  __shared__ __hip_bfloat16 sXT[128 * BST];   // X^T: 0..63 W^T, 64..127 Vt^T
  __shared__ __hip_bfloat16 sM[64 * BST];     // bf16 M, diag bands zeroed
  __shared__ float sMd[4][16][16];
  __shared__ float sP[64], sIP[64], sBP[64], sB[64];

  const int u = blockIdx.x;
  const int bh = u >> 5, c = u & 31;
  const int b = bh >> 4, h = bh & 15;
  const int tid = threadIdx.x, lane = tid & 63, wv = tid >> 6;
  const int l15 = lane & 15, lg = lane >> 4;
  const size_t bt0 = (size_t)b * T_ + (size_t)c * 64;
  const size_t hofs = (size_t)h * DH;

  // ---- phase 0: decay cumprods
  if (wv == 0) {
    float a = alpha[(bt0 + lane) * H_ + h];
    float bb = beta[(bt0 + lane) * H_ + h];
    float la = logf(a);
#pragma unroll
    for (int d = 1; d < 64; d <<= 1) {
      float y = __shfl_up(la, d);
      if (lane >= d) la += y;
    }
    float P = expf(la);
    sP[lane] = P;
    sIP[lane] = 1.f / P;
    sBP[lane] = bb * P;
    sB[lane] = bb;
    if (lane == 63) P63g[u] = P;
  }
  __syncthreads();

  // ---- phase 1: conv(K=4)+silu (+l2norm q,k) then scaled staging
#pragma unroll
  for (int i = 0; i < 4; ++i) {
    int e = tid + i * 256;
    int row = e >> 4, c4 = (e & 15) * 4;
    int gc = (int)hofs + c4;
    int tseq = c * 64 + row;
    float rq[4], rk[4], rv[4];
    {
      float4 bq = *(const float4*)(cqb + gc);
      float4 bk = *(const float4*)(ckb + gc);
      float4 bv = *(const float4*)(cvb + gc);
      rq[0] = bq.x; rq[1] = bq.y; rq[2] = bq.z; rq[3] = bq.w;
      rk[0] = bk.x; rk[1] = bk.y; rk[2] = bk.z; rk[3] = bk.w;
      rv[0] = bv.x; rv[1] = bv.y; rv[2] = bv.z; rv[3] = bv.w;
    }
    float wq[4][4], wk[4][4], wvv[4][4];
#pragma unroll
    for (int j = 0; j < 4; ++j) {
      float4 a4 = *(const float4*)(cqw + (size_t)(gc + j) * 4);
      wq[j][0] = a4.x; wq[j][1] = a4.y; wq[j][2] = a4.z; wq[j][3] = a4.w;
      float4 b4 = *(const float4*)(ckw + (size_t)(gc + j) * 4);
      wk[j][0] = b4.x; wk[j][1] = b4.y; wk[j][2] = b4.z; wk[j][3] = b4.w;
      float4 c4v = *(const float4*)(cvw + (size_t)(gc + j) * 4);
      wvv[j][0] = c4v.x; wvv[j][1] = c4v.y; wvv[j][2] = c4v.z; wvv[j][3] = c4v.w;
    }
#pragma unroll
    for (int kk = 0; kk < 4; ++kk) {
      if (tseq - 3 + kk >= 0) {
        size_t off = (bt0 + row - 3 + kk) * INNER_ + gc;
        ushort4 uq = *(const ushort4*)(qpre + off);
        ushort4 uk = *(const ushort4*)(kpre + off);
        ushort4 uv = *(const ushort4*)(vpre + off);
        rq[0] += b2f(uq.x) * wq[0][kk]; rq[1] += b2f(uq.y) * wq[1][kk];
        rq[2] += b2f(uq.z) * wq[2][kk]; rq[3] += b2f(uq.w) * wq[3][kk];
        rk[0] += b2f(uk.x) * wk[0][kk]; rk[1] += b2f(uk.y) * wk[1][kk];
        rk[2] += b2f(uk.z) * wk[2][kk]; rk[3] += b2f(uk.w) * wk[3][kk];
        rv[0] += b2f(uv.x) * wvv[0][kk]; rv[1] += b2f(uv.y) * wvv[1][kk];
        rv[2] += b2f(uv.z) * wvv[2][kk]; rv[3] += b2f(uv.w) * wvv[3][kk];
      }
    }
#pragma unroll
    for (int j = 0; j < 4; ++j) {
      rq[j] = rq[j] / (1.f + expf(-rq[j]));
      rk[j] = rk[j] / (1.f + expf(-rk[j]));
      rv[j] = rv[j] / (1.f + expf(-rv[j]));
    }
    // l2norm q,k across the 16-lane row group (covers this head's 64 channels)
    float ssq = rq[0]*rq[0] + rq[1]*rq[1] + rq[2]*rq[2] + rq[3]*rq[3];
    float ssk = rk[0]*rk[0] + rk[1]*rk[1] + rk[2]*rk[2] + rk[3]*rk[3];
    ssq += __shfl_xor(ssq, 1); ssq += __shfl_xor(ssq, 2);
    ssq += __shfl_xor(ssq, 4); ssq += __shfl_xor(ssq, 8);
    ssk += __shfl_xor(ssk, 1); ssk += __shfl_xor(ssk, 2);
    ssk += __shfl_xor(ssk, 4); ssk += __shfl_xor(ssk, 8);
    float scq = 1.f / fmaxf(sqrtf(ssq), 1e-12f);
    float sck = 1.f / fmaxf(sqrtf(ssk), 1e-12f);
#pragma unroll
    for (int j = 0; j < 4; ++j) { rq[j] *= scq; rk[j] *= sck; }

    float bp = sBP[row], ip = sIP[row], pp = sP[row], bo = sB[row];
    st_bf4(&sKb[row * BST + c4], rk[0] * bp, rk[1] * bp, rk[2] * bp, rk[3] * bp);
    st_bf4(&sKip[row * BST + c4], rk[0] * ip, rk[1] * ip, rk[2] * ip, rk[3] * ip);
    st_bf4(&sQp[row * BST + c4], rq[0] * pp, rq[1] * pp, rq[2] * pp, rq[3] * pp);
#pragma unroll
    for (int j = 0; j < 4; ++j) {
      sKipT[(c4 + j) * BST + row] = __float2bfloat16(rk[j] * ip);
      sXT[(c4 + j) * BST + row] = __float2bfloat16(rk[j] * bp);
      sXT[(64 + c4 + j) * BST + row] = __float2bfloat16(rv[j] * bo);
    }
  }
  __syncthreads();

  // ---- phase 2: M (waves 0,1) and Attn (waves 2,3)
  if (wv < 2) {
#pragma unroll
    for (int tt = wv * 2; tt < wv * 2 + 2; ++tt) {
      for (int n = 0; n <= tt; ++n) {
        f32x4 acc = (f32x4)0.f;
#pragma unroll
        for (int kk = 0; kk < 2; ++kk)
          acc = __builtin_amdgcn_mfma_f32_16x16x32_bf16(
              fragld(sKb, tt * 16 + l15, kk, lg), fragld(sKip, n * 16 + l15, kk, lg), acc, 0, 0, 0);
        if (n < tt) {
#pragma unroll
          for (int q = 0; q < 4; ++q)
            sM[(tt * 16 + lg * 4 + q) * BST + n * 16 + l15] = __float2bfloat16(acc[q]);
        } else {
#pragma unroll
          for (int q = 0; q < 4; ++q) {
            int rr = lg * 4 + q;
            sMd[tt][rr][l15] = (l15 < rr) ? acc[q] : 0.f;
            sM[(tt * 16 + rr) * BST + tt * 16 + l15] = __float2bfloat16(0.f);
          }
        }
      }
    }
  } else {
#pragma unroll
    for (int tt = (wv - 2) * 2; tt < (wv - 2) * 2 + 2; ++tt) {
      for (int n = 0; n < 4; ++n) {
        if (n <= tt) {
          f32x4 acc = (f32x4)0.f;
#pragma unroll
          for (int kk = 0; kk < 2; ++kk)
            acc = __builtin_amdgcn_mfma_f32_16x16x32_bf16(
                fragld(sQp, tt * 16 + l15, kk, lg), fragld(sKip, n * 16 + l15, kk, lg), acc, 0, 0, 0);
#pragma unroll
          for (int q = 0; q < 4; ++q) {
            int r = tt * 16 + lg * 4 + q, cl = n * 16 + l15;
            sAttn[r * BST + cl] = __float2bfloat16((cl <= r) ? acc[q] : 0.f);
          }
        } else {
#pragma unroll
          for (int q = 0; q < 4; ++q)
            sAttn[(tt * 16 + lg * 4 + q) * BST + n * 16 + l15] = __float2bfloat16(0.f);
        }
      }
    }
  }
  __syncthreads();

  // ---- phase 3: block-triangular solve, X^T in sXT
  auto diag_solve = [&](int I) {
    if (wv < 2) {
      const int cc = wv * 64 + lane;
      float x[16];
#pragma unroll
      for (int t = 0; t < 16; ++t) {
        float r = __bfloat162float(sXT[cc * BST + I * 16 + t]);
#pragma unroll
        for (int s = 0; s < t; ++s) r -= sMd[I][t][s] * x[s];
        x[t] = r;
        sXT[cc * BST + I * 16 + t] = __float2bfloat16(r);
      }
    }
  };

  diag_solve(0);
  __syncthreads();
#pragma unroll
  for (int I = 1; I < 4; ++I) {
    const int KK = (I == 3) ? 2 : 1;
#pragma unroll
    for (int ct2 = 0; ct2 < 2; ++ct2) {
      const int ct = wv * 2 + ct2;
      f32x4 uacc = (f32x4)0.f;
#pragma unroll
      for (int kk = 0; kk < KK; ++kk)
        uacc = __builtin_amdgcn_mfma_f32_16x16x32_bf16(
            fragld(sXT, ct * 16 + l15, kk, lg), fragld(sM, I * 16 + l15, kk, lg), uacc, 0, 0, 0);
#pragma unroll
      for (int q = 0; q < 4; ++q) {
        const int cc = ct * 16 + lg * 4 + q, t = I * 16 + l15;
        float old = __bfloat162float(sXT[cc * BST + t]);
        sXT[cc * BST + t] = __float2bfloat16(old - uacc[q]);
      }
    }
    __syncthreads();
    diag_solve(I);
    __syncthreads();
  }

  // ---- phase 4: outputs
  const float p63 = sP[63];
  const int tt = wv;
  const size_t go = (size_t)u * 4096;
#pragma unroll
  for (int n = 0; n < 4; ++n) {
    f32x4 av = (f32x4)0.f, aw = (f32x4)0.f, g1 = (f32x4)0.f, g2 = (f32x4)0.f;
#pragma unroll
    for (int kk = 0; kk < 2; ++kk) {
      bf16x8 at = fragld(sAttn, tt * 16 + l15, kk, lg);
      bf16x8 kt = fragld(sKipT, tt * 16 + l15, kk, lg);
      bf16x8 bv = fragld(sXT, 64 + n * 16 + l15, kk, lg);
      bf16x8 bw = fragld(sXT, n * 16 + l15, kk, lg);
      av = __builtin_amdgcn_mfma_f32_16x16x32_bf16(at, bv, av, 0, 0, 0);
      aw = __builtin_amdgcn_mfma_f32_16x16x32_bf16(at, bw, aw, 0, 0, 0);
      g1 = __builtin_amdgcn_mfma_f32_16x16x32_bf16(kt, bv, g1, 0, 0, 0);
      g2 = __builtin_amdgcn_mfma_f32_16x16x32_bf16(kt, bw, g2, 0, 0, 0);
    }
#pragma unroll
    for (int q = 0; q < 4; ++q) {
      int r = tt * 16 + lg * 4 + q, cl = n * 16 + l15;
      AVg[go + r * 64 + cl] = av[q];
      float qp = __bfloat162float(sQp[r * BST + cl]);
      Zg[go + r * 64 + cl] = __float2bfloat16(qp - aw[q]);
      G1g[go + cl * 64 + r] = p63 * g1[q];
      G2g[go + r * 64 + cl] = __float2bfloat16(p63 * g2[q]);
    }
  }
}

// ---------------- serial chunk recurrence, row-partitioned -------------------
__device__ __forceinline__ bf16x8 sfrag(const __hip_bfloat16* buf, int row, int kk, int lg) {
  int byte = row * 128 + kk * 64 + lg * 16;
  byte ^= (row & 7) << 4;
  return *(const bf16x8*)((const char*)buf + byte);
}

__global__ __launch_bounds__(256) void chunkrec_kernel(
    const __hip_bfloat16* __restrict__ Zg, const __hip_bfloat16* __restrict__ G2g,
    const float* __restrict__ AVg, const float* __restrict__ G1g,
    const float* __restrict__ P63g, float* __restrict__ o) {
  __shared__ __align__(16) __hip_bfloat16 sR[16 * 64];
  __shared__ __align__(16) __hip_bfloat16 sZ[2][64 * 64];
  __shared__ __align__(16) __hip_bfloat16 sG2[2][64 * 64];
  const int blk = blockIdx.x;
  const int bh = blk >> 2;
  const int jb = blk & 3;
  const int b = bh >> 4, h = bh & 15;
  const int tid = threadIdx.x, lane = tid & 63, wv = tid >> 6;
  const int l15 = lane & 15, lg = lane >> 4;
  const size_t btb = (size_t)b * T_;
  const size_t hofs = (size_t)h * DH;

  f32x4 R = (f32x4)0.f;

  uint4 zr[2], gr[2];
  const int e0 = tid * 2;

  auto issue = [&](int c) {
    size_t ub = ((size_t)bh * NCH + c) * 4096;
#pragma unroll
    for (int i = 0; i < 2; ++i) {
      zr[i] = *(const uint4*)(Zg + ub + (size_t)(e0 + i) * 8);
      gr[i] = *(const uint4*)(G2g + ub + (size_t)(e0 + i) * 8);
    }
  };
  auto commit = [&](int buf) {
#pragma unroll
    for (int i = 0; i < 2; ++i) {
      int e = e0 + i;
      int row = e >> 3, colb = (e & 7) * 16;
      int byte = (row * 128 + colb) ^ ((row & 7) << 4);
      *(uint4*)((char*)sZ[buf] + byte) = zr[i];
      *(uint4*)((char*)sG2[buf] + byte) = gr[i];
    }
  };

  issue(0);
  commit(0);
  int cur = 0;
  for (int c = 0; c < NCH; ++c) {
#pragma unroll
    for (int q = 0; q < 4; ++q) {
      int i = lg * 4 + q;
      int byte = (i * 128 + (wv * 16 + l15) * 2) ^ ((i & 7) << 4);
      *(__hip_bfloat16*)((char*)sR + byte) = __float2bfloat16(R[q]);
    }
    __syncthreads();

    const size_t ub = ((size_t)bh * NCH + c) * 4096;
    float avr[4], g1r[4];
#pragma unroll
    for (int q = 0; q < 4; ++q) {
      int t = wv * 16 + lg * 4 + q;
      avr[q] = AVg[ub + t * 64 + jb * 16 + l15];
      g1r[q] = G1g[ub + (jb * 16 + lg * 4 + q) * 64 + wv * 16 + l15];
    }
    float p63 = P63g[(size_t)bh * NCH + c];
    if (c + 1 < NCH) issue(c + 1);

    bf16x8 zA[2], rF[2], gB[2];
#pragma unroll
    for (int kk = 0; kk < 2; ++kk) {
      zA[kk] = sfrag(sZ[cur], wv * 16 + l15, kk, lg);
      rF[kk] = sfrag(sR, l15, kk, lg);
      gB[kk] = sfrag(sG2[cur], wv * 16 + l15, kk, lg);
    }
    f32x4 oacc = (f32x4)0.f, gacc = (f32x4)0.f;
#pragma unroll
    for (int kk = 0; kk < 2; ++kk) {
      oacc = __builtin_amdgcn_mfma_f32_16x16x32_bf16(zA[kk], rF[kk], oacc, 0, 0, 0);
      gacc = __builtin_amdgcn_mfma_f32_16x16x32_bf16(rF[kk], gB[kk], gacc, 0, 0, 0);
    }
#pragma unroll
    for (int q = 0; q < 4; ++q) {
      int t = wv * 16 + lg * 4 + q;
      o[(btb + (size_t)c * 64 + t) * INNER_ + hofs + jb * 16 + l15] = avr[q] + oacc[q];
      R[q] = p63 * R[q] + g1r[q] - gacc[q];
    }
    __syncthreads();
    if (c + 1 < NCH) commit(cur ^ 1);
    cur ^= 1;
  }
}

// ---------------- RMS norm over INNER, * (1+gamma) * gate(bf16) -> bf16 ------
__global__ __launch_bounds__(256) void rmsgate_kernel(const float* __restrict__ o,
    const __hip_bfloat16* __restrict__ gate, const float* __restrict__ gamma,
    __hip_bfloat16* __restrict__ outn) {
  const int bt = blockIdx.x;
  const int tid = threadIdx.x;
  const size_t base = (size_t)bt * INNER_ + tid * 4;
  float4 ov = *(const float4*)(o + base);
  float ss = ov.x*ov.x + ov.y*ov.y + ov.z*ov.z + ov.w*ov.w;
#pragma unroll
  for (int m = 1; m <= 32; m <<= 1) ss += __shfl_xor(ss, m);
  __shared__ float red[4];
  if ((tid & 63) == 0) red[tid >> 6] = ss;
  __syncthreads();
  float tot = red[0] + red[1] + red[2] + red[3];
  float rms = sqrtf(tot * (1.f / (float)INNER_) + 1e-6f);
  float inv = 1.f / rms;
  float4 gm = *(const float4*)(gamma + tid * 4);
  ushort4 gt = *(const ushort4*)(gate + base);
  st_bf4(outn + base,
         ov.x * inv * (1.f + gm.x) * b2f(gt.x),
         ov.y * inv * (1.f + gm.y) * b2f(gt.y),
         ov.z * inv * (1.f + gm.z) * b2f(gt.z),
         ov.w * inv * (1.f + gm.w) * b2f(gt.w));
}

// ---------------- launch -----------------------------------------------------
extern "C" void kernel_launch(void* const* d_in, const int* in_sizes, int n_in,
                              void* d_out, int out_size, void* d_ws, size_t ws_size,
                              hipStream_t stream) {
  const float* x   = (const float*)d_in[0];
  const float* Wq  = (const float*)d_in[1];
  const float* Wk  = (const float*)d_in[2];
  const float* Wv  = (const float*)d_in[3];
  const float* Wa  = (const float*)d_in[4];
  const float* ba  = (const float*)d_in[5];
  const float* Wb  = (const float*)d_in[6];
  const float* bb  = (const float*)d_in[7];
  const float* Wg  = (const float*)d_in[8];
  const float* Wo  = (const float*)d_in[9];
  const float* cqw = (const float*)d_in[10];
  const float* cqb = (const float*)d_in[11];
  const float* ckw = (const float*)d_in[12];
  const float* ckb = (const float*)d_in[13];
  const float* cvw = (const float*)d_in[14];
  const float* cvb = (const float*)d_in[15];
  const float* gamma = (const float*)d_in[16];

  char* p = (char*)d_ws;
  __hip_bfloat16* qkvg = (__hip_bfloat16*)p;  p += 4 * N1 * 2;        // 33.5MB
  __hip_bfloat16* xb   = (__hip_bfloat16*)p;  p += N1 * 2;            // 8.4MB (reused as nrmb)
  float* alpha = (float*)p;  p += (size_t)BT * H_ * 4;                // 256KB
  float* beta  = (float*)p;  p += (size_t)BT * H_ * 4;
  __hip_bfloat16* wtall = (__hip_bfloat16*)p;  p += (size_t)4352 * 1024 * 2;  // 8.9MB
  __hip_bfloat16* Wot   = (__hip_bfloat16*)p;  p += (size_t)1024 * 1024 * 2;
  float* AVg = (float*)p;  p += (size_t)NU * 4096 * 4;                // 16.8MB
  float* G1g = (float*)p;  p += (size_t)NU * 4096 * 4;
  __hip_bfloat16* Zg  = (__hip_bfloat16*)p;  p += (size_t)NU * 4096 * 2;
  __hip_bfloat16* G2g = (__hip_bfloat16*)p;  p += (size_t)NU * 4096 * 2;
  float* obuf = (float*)p;  p += N1 * 4;                              // 16.8MB
  float* P63s = (float*)p;  p += (size_t)NU * 4;
  __hip_bfloat16* nrmb = xb;   // xb dead after GEMMs
  float* outp = (float*)d_out;

  // 1) prep: cvt x, transpose 5 weights, pack Wab panel
  prep_kernel<<<10240, 256, 0, stream>>>(x, Wq, Wk, Wv, Wg, Wo, Wa, Wb, xb, wtall, Wot);

  // 2) fused projection GEMM (q|k|v|g bf16 + alpha/beta sigmoid tile)
  gemm256<<<dim3(17, BT / 256), 512, 0, stream>>>(
      xb, wtall, nullptr, qkvg, alpha, beta, ba, bb, BT, 4352, D_, 2);

  // 3) chunked recurrence (conv+silu+l2norm fused into precompute)
  precomp_kernel<<<NU, 256, 0, stream>>>(qkvg, qkvg + N1, qkvg + 2 * N1,
                                         alpha, beta, cqw, cqb, ckw, ckb, cvw, cvb,
                                         Zg, G2g, AVg, G1g, P63s);
  chunkrec_kernel<<<B_ * H_ * 4, 256, 0, stream>>>(Zg, G2g, AVg, G1g, P63s, obuf);

  // 4) RMS + gate, then out-projection
  rmsgate_kernel<<<BT, 256, 0, stream>>>(obuf, qkvg + 3 * N1, gamma, nrmb);
  gemm256<<<dim3(D_ / 256, BT / 256), 512, 0, stream>>>(
      nrmb, Wot, outp, nullptr, nullptr, nullptr, nullptr, nullptr, BT, D_, INNER_, 0);
}

// Round 9
// 347.363 us; speedup vs baseline: 4.8192x; 1.0511x over previous
//
#include <hip/hip_runtime.h>
#include <hip/hip_bf16.h>
#include <cmath>

#define B_ 2
#define T_ 2048
#define D_ 1024
#define H_ 16
#define DH 64
#define INNER_ 1024
#define BT (B_*T_)
#define NCH 32              // chunks per (b,h), chunk length 64
#define NU (B_*H_*NCH)      // 1024 precompute units
#define N1 ((size_t)BT * INNER_)

typedef __attribute__((ext_vector_type(8))) __bf16 bf16x8;
typedef __attribute__((ext_vector_type(4))) float f32x4;
typedef const __attribute__((address_space(1))) unsigned gas_u32;
typedef __attribute__((address_space(3))) unsigned las_u32;

__device__ __forceinline__ void async16(const void* g, void* l) {
  __builtin_amdgcn_global_load_lds((gas_u32*)g, (las_u32*)l, 16, 0, 0);
}

__device__ __forceinline__ ushort bfr(float x) {
  __hip_bfloat16 t = __float2bfloat16(x);
  return *(ushort*)&t;
}
__device__ __forceinline__ void st_bf4(__hip_bfloat16* p, float a, float b, float c, float d) {
  ushort4 u; u.x = bfr(a); u.y = bfr(b); u.z = bfr(c); u.w = bfr(d);
  *(ushort4*)p = u;
}
__device__ __forceinline__ float b2f(ushort s) {
  return __uint_as_float(((unsigned)s) << 16);
}

// ---------------- prep: cvt x->bf16, 5 weight transposes, Wab pad-pack -------
__global__ __launch_bounds__(256) void prep_kernel(
    const float* __restrict__ x,
    const float* __restrict__ Wq, const float* __restrict__ Wk,
    const float* __restrict__ Wv, const float* __restrict__ Wg,
    const float* __restrict__ Wo, const float* __restrict__ Wa,
    const float* __restrict__ Wb,
    __hip_bfloat16* __restrict__ xb, __hip_bfloat16* __restrict__ wtall,
    __hip_bfloat16* __restrict__ Wot) {
  __shared__ float tile[32][33];
  const int bid = blockIdx.x, tid = threadIdx.x;
  if (bid < 4096) {
    int i = bid * 256 + tid;
    float4 v = *(const float4*)(x + (size_t)i * 4);
    st_bf4(xb + (size_t)i * 4, v.x, v.y, v.z, v.w);
    return;
  }
  if (bid < 9216) {
    int wi = (bid - 4096) >> 10;
    int t = (bid - 4096) & 1023;
    const float* src = wi == 0 ? Wq : wi == 1 ? Wk : wi == 2 ? Wv : wi == 3 ? Wg : Wo;
    __hip_bfloat16* dst = (wi < 4) ? (wtall + (size_t)wi * 1024 * 1024) : Wot;
    const int bc = (t & 31) * 32, br = (t >> 5) * 32;
    const int tx = tid & 31, ty = tid >> 5;
#pragma unroll
    for (int i2 = 0; i2 < 32; i2 += 8)
      tile[ty + i2][tx] = src[(size_t)(br + ty + i2) * 1024 + bc + tx];
    __syncthreads();
#pragma unroll
    for (int i2 = 0; i2 < 32; i2 += 8)
      dst[(size_t)(bc + ty + i2) * 1024 + br + tx] = __float2bfloat16(tile[tx][ty + i2]);
    return;
  }
  int idx = (bid - 9216) * 256 + tid;  // rows 4096..4351 of wtall
  int j = idx >> 10, k2 = idx & 1023;
  float v = 0.f;
  if (j < 16) v = Wa[k2 * 16 + j];
  else if (j < 32) v = Wb[k2 * 16 + (j - 16)];
  wtall[(size_t)4096 * 1024 + idx] = __float2bfloat16(v);
}

// ---------------- 256^2 2-phase double-buffered bf16 MFMA GEMM (proj) --------
// Flat 272-block grid, XCD-pinned swizzle: col%8 == blockIdx%8 for the 16 full
// column-tiles (B panels stay resident in their XCD's L2); 17th col (alpha/
// beta panel) spread. Epilogue: cols [q|k|v|g]->bf16 (silu on g), cols
// 4096..4127 -> sigmoid(+bias) alpha/beta [BT][16].
__device__ __forceinline__ bf16x8 pfrag(const __hip_bfloat16* buf, int row, int ks, int lg) {
  return *(const bf16x8*)((const char*)buf + row * 128 + ks * 64 + lg * 16);
}

__global__ __launch_bounds__(512, 2) void gemm256(const __hip_bfloat16* __restrict__ A,
                                                  const __hip_bfloat16* __restrict__ Bt,
                                                  __hip_bfloat16* __restrict__ Cb,
                                                  float* __restrict__ alpha,
                                                  float* __restrict__ beta,
                                                  const float* __restrict__ ba,
                                                  const float* __restrict__ bb2,
                                                  int K) {
  __shared__ __hip_bfloat16 As[2][256 * 64];
  __shared__ __hip_bfloat16 Bs[2][256 * 64];
  const int tid = threadIdx.x;
  const int lane = tid & 63, wv = tid >> 6;
  const int wr = wv >> 2, wc = wv & 3;
  // XCD-pinned decode: i%8 == col%8 for cols 0..15
  int m0, n0;
  {
    const int i = blockIdx.x, x8 = i & 7, q = i >> 3;   // q in 0..33
    int row, col;
    if (q < 32) { col = x8 + 8 * (q >> 4); row = q & 15; }
    else        { col = 16; row = (x8 << 1) | (q & 1); }
    m0 = row * 256; n0 = col * 256;
  }
  const int l15 = lane & 15, lg = lane >> 4;
  const int sr8 = lane >> 3, sc = (lane & 7) * 8;

  f32x4 acc[8][4];
#pragma unroll
  for (int m = 0; m < 8; ++m)
#pragma unroll
    for (int n = 0; n < 4; ++n) acc[m][n] = (f32x4)0.f;

  auto stage = [&](int kt, int bsel) {
    const size_t k0 = (size_t)kt * 64;
    const __hip_bfloat16* Ab = A + (size_t)(m0 + wv * 8 + sr8) * K + k0 + sc;
    const __hip_bfloat16* Bb = Bt + (size_t)(n0 + wv * 8 + sr8) * K + k0 + sc;
    char* al = (char*)As[bsel] + wv * 1024;
    char* bl = (char*)Bs[bsel] + wv * 1024;
#pragma unroll
    for (int q = 0; q < 4; ++q) {
      async16(Ab + (size_t)q * 64 * K, al + q * 8192);
      async16(Bb + (size_t)q * 64 * K, bl + q * 8192);
    }
  };

  const int NT = K >> 6;
  stage(0, 0);
  __syncthreads();
  int cur = 0;
  for (int kt = 0; kt < NT; ++kt) {
    if (kt + 1 < NT) stage(kt + 1, cur ^ 1);
#pragma unroll
    for (int ks = 0; ks < 2; ++ks) {
      bf16x8 af[8], bfg[4];
#pragma unroll
      for (int m = 0; m < 8; ++m)
        af[m] = pfrag(As[cur], wr * 128 + m * 16 + l15, ks, lg);
#pragma unroll
      for (int n = 0; n < 4; ++n)
        bfg[n] = pfrag(Bs[cur], wc * 64 + n * 16 + l15, ks, lg);
#pragma unroll
      for (int m = 0; m < 8; ++m)
#pragma unroll
        for (int n = 0; n < 4; ++n)
          acc[m][n] = __builtin_amdgcn_mfma_f32_16x16x32_bf16(af[m], bfg[n], acc[m][n], 0, 0, 0);
    }
    __syncthreads();
    cur ^= 1;
  }

#pragma unroll
  for (int m = 0; m < 8; ++m) {
    const int rbase = m0 + wr * 128 + m * 16 + lg * 4;
#pragma unroll
    for (int n = 0; n < 4; ++n) {
      const int col = n0 + wc * 64 + n * 16 + l15;
      if (col < 4096) {
        const int which = col >> 10;
        const int ncol = col & 1023;
        __hip_bfloat16* dst = Cb + (size_t)which * N1 + (size_t)rbase * 1024 + ncol;
#pragma unroll
        for (int r = 0; r < 4; ++r) {
          float vv = acc[m][n][r];
          if (which == 3) vv = vv / (1.f + expf(-vv));  // silu on gate
          dst[(size_t)r * 1024] = __float2bfloat16(vv);
        }
      } else {
        const int ncol = col - 4096;
        if (ncol < 32) {
          const float bias = (ncol < 16) ? ba[ncol] : bb2[ncol - 16];
          float* dst = (ncol < 16) ? (alpha + ncol) : (beta + (ncol - 16));
#pragma unroll
          for (int r = 0; r < 4; ++r)
            dst[(size_t)(rbase + r) * H_] = 1.f / (1.f + expf(-(acc[m][n][r] + bias)));
        }
      }
    }
  }
}

// ---------------- 128^2 bf16 MFMA GEMM (out-projection, 256 blocks) ----------
__global__ __launch_bounds__(256) void gemm_bf16(const __hip_bfloat16* __restrict__ A,
                                                 const __hip_bfloat16* __restrict__ Bt,
                                                 float* __restrict__ C,
                                                 int M, int N, int K) {
  __shared__ __hip_bfloat16 As[128 * 32];
  __shared__ __hip_bfloat16 Bs[128 * 32];
  const int tid = threadIdx.x;
  const int lane = tid & 63, wave = tid >> 6;
  const int wr = wave >> 1, wc = wave & 1;
  const int m0 = blockIdx.y * 128, n0 = blockIdx.x * 128;
  const int srow = tid >> 2, skoff = (tid & 3) * 8;
  const int l15 = lane & 15, lg = lane >> 4;

  f32x4 acc[4][4];
#pragma unroll
  for (int m = 0; m < 4; ++m)
#pragma unroll
    for (int n = 0; n < 4; ++n) acc[m][n] = (f32x4)0.f;

  char* asB = (char*)As;
  char* bsB = (char*)Bs;
  const int ldsw = wave * 1024;

  for (int k0 = 0; k0 < K; k0 += 32) {
    async16(A + (size_t)(m0 + srow) * K + k0 + skoff, asB + ldsw);
    async16(A + (size_t)(m0 + 64 + srow) * K + k0 + skoff, asB + 4096 + ldsw);
    async16(Bt + (size_t)(n0 + srow) * K + k0 + skoff, bsB + ldsw);
    async16(Bt + (size_t)(n0 + 64 + srow) * K + k0 + skoff, bsB + 4096 + ldsw);
    __syncthreads();

    bf16x8 af[4], bfg[4];
#pragma unroll
    for (int m = 0; m < 4; ++m)
      af[m] = *(const bf16x8*)(asB + ((wr * 64 + m * 16 + l15) * 32 + lg * 8) * 2);
#pragma unroll
    for (int n = 0; n < 4; ++n)
      bfg[n] = *(const bf16x8*)(bsB + ((wc * 64 + n * 16 + l15) * 32 + lg * 8) * 2);
#pragma unroll
    for (int m = 0; m < 4; ++m)
#pragma unroll
      for (int n = 0; n < 4; ++n)
        acc[m][n] = __builtin_amdgcn_mfma_f32_16x16x32_bf16(af[m], bfg[n], acc[m][n], 0, 0, 0);
    __syncthreads();
  }

#pragma unroll
  for (int m = 0; m < 4; ++m) {
    const int rbase = m0 + wr * 64 + m * 16 + lg * 4;
#pragma unroll
    for (int n = 0; n < 4; ++n) {
      const int col = n0 + wc * 64 + n * 16 + l15;
#pragma unroll
      for (int r = 0; r < 4; ++r)
        C[(size_t)(rbase + r) * N + col] = acc[m][n][r];
    }
  }
}

// =============================================================================
// Chunked gated-delta (WY form) precompute with fused conv+silu+l2norm.
// =============================================================================
#define BST 72

__device__ __forceinline__ bf16x8 fragld(const __hip_bfloat16* buf, int row, int kk, int lg) {
  return *(const bf16x8*)(buf + row * BST + kk * 32 + lg * 8);
}

__global__ __launch_bounds__(256, 2) void precomp_kernel(
    const __hip_bfloat16* __restrict__ qpre, const __hip_bfloat16* __restrict__ kpre,
    const __hip_bfloat16* __restrict__ vpre,
    const float* __restrict__ alpha, const float* __restrict__ beta,
    const float* __restrict__ cqw, const float* __restrict__ cqb,
    const float* __restrict__ ckw, const float* __restrict__ ckb,
    const float* __restrict__ cvw, const float* __restrict__ cvb,
    __hip_bfloat16* __restrict__ Zg, __hip_bfloat16* __restrict__ G2g,
    float* __restrict__ AVg, float* __restrict__ G1g, float* __restrict__ P63g) {
  __shared__ __hip_bfloat16 sKb[64 * BST], sKip[64 * BST], sKipT[64 * BST];
  __shared__ __hip_bfloat16 sQp[64 * BST], sAttn[64 * BST];
  __shared__ __hip_bfloat16 sXT[128 * BST];
  __shared__ __hip_bfloat16 sM[64 * BST];
  __shared__ float sMd[4][16][16];
  __shared__ float sP[64], sIP[64], sBP[64], sB[64];

  const int u = blockIdx.x;
  const int bh = u >> 5, c = u & 31;
  const int b = bh >> 4, h = bh & 15;
  const int tid = threadIdx.x, lane = tid & 63, wv = tid >> 6;
  const int l15 = lane & 15, lg = lane >> 4;
  const size_t bt0 = (size_t)b * T_ + (size_t)c * 64;
  const size_t hofs = (size_t)h * DH;

  if (wv == 0) {
    float a = alpha[(bt0 + lane) * H_ + h];
    float bb = beta[(bt0 + lane) * H_ + h];
    float la = logf(a);
#pragma unroll
    for (int d = 1; d < 64; d <<= 1) {
      float y = __shfl_up(la, d);
      if (lane >= d) la += y;
    }
    float P = expf(la);
    sP[lane] = P;
    sIP[lane] = 1.f / P;
    sBP[lane] = bb * P;
    sB[lane] = bb;
    if (lane == 63) P63g[u] = P;
  }
  __syncthreads();

#pragma unroll
  for (int i = 0; i < 4; ++i) {
    int e = tid + i * 256;
    int row = e >> 4, c4 = (e & 15) * 4;
    int gc = (int)hofs + c4;
    int tseq = c * 64 + row;
    float rq[4], rk[4], rv[4];
    {
      float4 bq = *(const float4*)(cqb + gc);
      float4 bk = *(const float4*)(ckb + gc);
      float4 bv = *(const float4*)(cvb + gc);
      rq[0] = bq.x; rq[1] = bq.y; rq[2] = bq.z; rq[3] = bq.w;
      rk[0] = bk.x; rk[1] = bk.y; rk[2] = bk.z; rk[3] = bk.w;
      rv[0] = bv.x; rv[1] = bv.y; rv[2] = bv.z; rv[3] = bv.w;
    }
    float wq[4][4], wk[4][4], wvv[4][4];
#pragma unroll
    for (int j = 0; j < 4; ++j) {
      float4 a4 = *(const float4*)(cqw + (size_t)(gc + j) * 4);
      wq[j][0] = a4.x; wq[j][1] = a4.y; wq[j][2] = a4.z; wq[j][3] = a4.w;
      float4 b4 = *(const float4*)(ckw + (size_t)(gc + j) * 4);
      wk[j][0] = b4.x; wk[j][1] = b4.y; wk[j][2] = b4.z; wk[j][3] = b4.w;
      float4 c4v = *(const float4*)(cvw + (size_t)(gc + j) * 4);
      wvv[j][0] = c4v.x; wvv[j][1] = c4v.y; wvv[j][2] = c4v.z; wvv[j][3] = c4v.w;
    }
#pragma unroll
    for (int kk = 0; kk < 4; ++kk) {
      if (tseq - 3 + kk >= 0) {
        size_t off = (bt0 + row - 3 + kk) * INNER_ + gc;
        ushort4 uq = *(const ushort4*)(qpre + off);
        ushort4 uk = *(const ushort4*)(kpre + off);
        ushort4 uv = *(const ushort4*)(vpre + off);
        rq[0] += b2f(uq.x) * wq[0][kk]; rq[1] += b2f(uq.y) * wq[1][kk];
        rq[2] += b2f(uq.z) * wq[2][kk]; rq[3] += b2f(uq.w) * wq[3][kk];
        rk[0] += b2f(uk.x) * wk[0][kk]; rk[1] += b2f(uk.y) * wk[1][kk];
        rk[2] += b2f(uk.z) * wk[2][kk]; rk[3] += b2f(uk.w) * wk[3][kk];
        rv[0] += b2f(uv.x) * wvv[0][kk]; rv[1] += b2f(uv.y) * wvv[1][kk];
        rv[2] += b2f(uv.z) * wvv[2][kk]; rv[3] += b2f(uv.w) * wvv[3][kk];
      }
    }
#pragma unroll
    for (int j = 0; j < 4; ++j) {
      rq[j] = rq[j] / (1.f + expf(-rq[j]));
      rk[j] = rk[j] / (1.f + expf(-rk[j]));
      rv[j] = rv[j] / (1.f + expf(-rv[j]));
    }
    float ssq = rq[0]*rq[0] + rq[1]*rq[1] + rq[2]*rq[2] + rq[3]*rq[3];
    float ssk = rk[0]*rk[0] + rk[1]*rk[1] + rk[2]*rk[2] + rk[3]*rk[3];
    ssq += __shfl_xor(ssq, 1); ssq += __shfl_xor(ssq, 2);
    ssq += __shfl_xor(ssq, 4); ssq += __shfl_xor(ssq, 8);
    ssk += __shfl_xor(ssk, 1); ssk += __shfl_xor(ssk, 2);
    ssk += __shfl_xor(ssk, 4); ssk += __shfl_xor(ssk, 8);
    float scq = 1.f / fmaxf(sqrtf(ssq), 1e-12f);
    float sck = 1.f / fmaxf(sqrtf(ssk), 1e-12f);
#pragma unroll
    for (int j = 0; j < 4; ++j) { rq[j] *= scq; rk[j] *= sck; }

    float bp = sBP[row], ip = sIP[row], pp = sP[row], bo = sB[row];
    st_bf4(&sKb[row * BST + c4], rk[0] * bp, rk[1] * bp, rk[2] * bp, rk[3] * bp);
    st_bf4(&sKip[row * BST + c4], rk[0] * ip, rk[1] * ip, rk[2] * ip, rk[3] * ip);
    st_bf4(&sQp[row * BST + c4], rq[0] * pp, rq[1] * pp, rq[2] * pp, rq[3] * pp);
#pragma unroll
    for (int j = 0; j < 4; ++j) {
      sKipT[(c4 + j) * BST + row] = __float2bfloat16(rk[j] * ip);
      sXT[(c4 + j) * BST + row] = __float2bfloat16(rk[j] * bp);
      sXT[(64 + c4 + j) * BST + row] = __float2bfloat16(rv[j] * bo);
    }
  }
  __syncthreads();

  if (wv < 2) {
#pragma unroll
    for (int tt = wv * 2; tt < wv * 2 + 2; ++tt) {
      for (int n = 0; n <= tt; ++n) {
        f32x4 acc = (f32x4)0.f;
#pragma unroll
        for (int kk = 0; kk < 2; ++kk)
          acc = __builtin_amdgcn_mfma_f32_16x16x32_bf16(
              fragld(sKb, tt * 16 + l15, kk, lg), fragld(sKip, n * 16 + l15, kk, lg), acc, 0, 0, 0);
        if (n < tt) {
#pragma unroll
          for (int q = 0; q < 4; ++q)
            sM[(tt * 16 + lg * 4 + q) * BST + n * 16 + l15] = __float2bfloat16(acc[q]);
        } else {
#pragma unroll
          for (int q = 0; q < 4; ++q) {
            int rr = lg * 4 + q;
            sMd[tt][rr][l15] = (l15 < rr) ? acc[q] : 0.f;
            sM[(tt * 16 + rr) * BST + tt * 16 + l15] = __float2bfloat16(0.f);
          }
        }
      }
    }
  } else {
#pragma unroll
    for (int tt = (wv - 2) * 2; tt < (wv - 2) * 2 + 2; ++tt) {
      for (int n = 0; n < 4; ++n) {
        if (n <= tt) {
          f32x4 acc = (f32x4)0.f;
#pragma unroll
          for (int kk = 0; kk < 2; ++kk)
            acc = __builtin_amdgcn_mfma_f32_16x16x32_bf16(
                fragld(sQp, tt * 16 + l15, kk, lg), fragld(sKip, n * 16 + l15, kk, lg), acc, 0, 0, 0);
#pragma unroll
          for (int q = 0; q < 4; ++q) {
            int r = tt * 16 + lg * 4 + q, cl = n * 16 + l15;
            sAttn[r * BST + cl] = __float2bfloat16((cl <= r) ? acc[q] : 0.f);
          }
        } else {
#pragma unroll
          for (int q = 0; q < 4; ++q)
            sAttn[(tt * 16 + lg * 4 + q) * BST + n * 16 + l15] = __float2bfloat16(0.f);
        }
      }
    }
  }
  __syncthreads();

  auto diag_solve = [&](int I) {
    if (wv < 2) {
      const int cc = wv * 64 + lane;
      float x[16];
#pragma unroll
      for (int t = 0; t < 16; ++t) {
        float r = __bfloat162float(sXT[cc * BST + I * 16 + t]);
#pragma unroll
        for (int s = 0; s < t; ++s) r -= sMd[I][t][s] * x[s];
        x[t] = r;
        sXT[cc * BST + I * 16 + t] = __float2bfloat16(r);
      }
    }
  };

  diag_solve(0);
  __syncthreads();
#pragma unroll
  for (int I = 1; I < 4; ++I) {
    const int KK = (I == 3) ? 2 : 1;
#pragma unroll
    for (int ct2 = 0; ct2 < 2; ++ct2) {
      const int ct = wv * 2 + ct2;
      f32x4 uacc = (f32x4)0.f;
#pragma unroll
      for (int kk = 0; kk < KK; ++kk)
        uacc = __builtin_amdgcn_mfma_f32_16x16x32_bf16(
            fragld(sXT, ct * 16 + l15, kk, lg), fragld(sM, I * 16 + l15, kk, lg), uacc, 0, 0, 0);
#pragma unroll
      for (int q = 0; q < 4; ++q) {
        const int cc = ct * 16 + lg * 4 + q, t = I * 16 + l15;
        float old = __bfloat162float(sXT[cc * BST + t]);
        sXT[cc * BST + t] = __float2bfloat16(old - uacc[q]);
      }
    }
    __syncthreads();
    diag_solve(I);
    __syncthreads();
  }

  const float p63 = sP[63];
  const int tt = wv;
  const size_t go = (size_t)u * 4096;
#pragma unroll
  for (int n = 0; n < 4; ++n) {
    f32x4 av = (f32x4)0.f, aw = (f32x4)0.f, g1 = (f32x4)0.f, g2 = (f32x4)0.f;
#pragma unroll
    for (int kk = 0; kk < 2; ++kk) {
      bf16x8 at = fragld(sAttn, tt * 16 + l15, kk, lg);
      bf16x8 kt = fragld(sKipT, tt * 16 + l15, kk, lg);
      bf16x8 bv = fragld(sXT, 64 + n * 16 + l15, kk, lg);
      bf16x8 bw = fragld(sXT, n * 16 + l15, kk, lg);
      av = __builtin_amdgcn_mfma_f32_16x16x32_bf16(at, bv, av, 0, 0, 0);
      aw = __builtin_amdgcn_mfma_f32_16x16x32_bf16(at, bw, aw, 0, 0, 0);
      g1 = __builtin_amdgcn_mfma_f32_16x16x32_bf16(kt, bv, g1, 0, 0, 0);
      g2 = __builtin_amdgcn_mfma_f32_16x16x32_bf16(kt, bw, g2, 0, 0, 0);
    }
#pragma unroll
    for (int q = 0; q < 4; ++q) {
      int r = tt * 16 + lg * 4 + q, cl = n * 16 + l15;
      AVg[go + r * 64 + cl] = av[q];
      float qp = __bfloat162float(sQp[r * BST + cl]);
      Zg[go + r * 64 + cl] = __float2bfloat16(qp - aw[q]);
      G1g[go + cl * 64 + r] = p63 * g1[q];
      G2g[go + r * 64 + cl] = __float2bfloat16(p63 * g2[q]);
    }
  }
}

// ---------------- serial chunk recurrence, row-partitioned -------------------
__device__ __forceinline__ bf16x8 sfrag(const __hip_bfloat16* buf, int row, int kk, int lg) {
  int byte = row * 128 + kk * 64 + lg * 16;
  byte ^= (row & 7) << 4;
  return *(const bf16x8*)((const char*)buf + byte);
}

__global__ __launch_bounds__(256) void chunkrec_kernel(
    const __hip_bfloat16* __restrict__ Zg, const __hip_bfloat16* __restrict__ G2g,
    const float* __restrict__ AVg, const float* __restrict__ G1g,
    const float* __restrict__ P63g, float* __restrict__ o) {
  __shared__ __align__(16) __hip_bfloat16 sR[16 * 64];
  __shared__ __align__(16) __hip_bfloat16 sZ[2][64 * 64];
  __shared__ __align__(16) __hip_bfloat16 sG2[2][64 * 64];
  const int blk = blockIdx.x;
  const int bh = blk >> 2;
  const int jb = blk & 3;
  const int b = bh >> 4, h = bh & 15;
  const int tid = threadIdx.x, lane = tid & 63, wv = tid >> 6;
  const int l15 = lane & 15, lg = lane >> 4;
  const size_t btb = (size_t)b * T_;
  const size_t hofs = (size_t)h * DH;

  f32x4 R = (f32x4)0.f;

  uint4 zr[2], gr[2];
  const int e0 = tid * 2;

  auto issue = [&](int c) {
    size_t ub = ((size_t)bh * NCH + c) * 4096;
#pragma unroll
    for (int i = 0; i < 2; ++i) {
      zr[i] = *(const uint4*)(Zg + ub + (size_t)(e0 + i) * 8);
      gr[i] = *(const uint4*)(G2g + ub + (size_t)(e0 + i) * 8);
    }
  };
  auto commit = [&](int buf) {
#pragma unroll
    for (int i = 0; i < 2; ++i) {
      int e = e0 + i;
      int row = e >> 3, colb = (e & 7) * 16;
      int byte = (row * 128 + colb) ^ ((row & 7) << 4);
      *(uint4*)((char*)sZ[buf] + byte) = zr[i];
      *(uint4*)((char*)sG2[buf] + byte) = gr[i];
    }
  };

  issue(0);
  commit(0);
  int cur = 0;
  for (int c = 0; c < NCH; ++c) {
#pragma unroll
    for (int q = 0; q < 4; ++q) {
      int i = lg * 4 + q;
      int byte = (i * 128 + (wv * 16 + l15) * 2) ^ ((i & 7) << 4);
      *(__hip_bfloat16*)((char*)sR + byte) = __float2bfloat16(R[q]);
    }
    __syncthreads();

    const size_t ub = ((size_t)bh * NCH + c) * 4096;
    float avr[4], g1r[4];
#pragma unroll
    for (int q = 0; q < 4; ++q) {
      int t = wv * 16 + lg * 4 + q;
      avr[q] = AVg[ub + t * 64 + jb * 16 + l15];
      g1r[q] = G1g[ub + (jb * 16 + lg * 4 + q) * 64 + wv * 16 + l15];
    }
    float p63 = P63g[(size_t)bh * NCH + c];
    if (c + 1 < NCH) issue(c + 1);

    bf16x8 zA[2], rF[2], gB[2];
#pragma unroll
    for (int kk = 0; kk < 2; ++kk) {
      zA[kk] = sfrag(sZ[cur], wv * 16 + l15, kk, lg);
      rF[kk] = sfrag(sR, l15, kk, lg);
      gB[kk] = sfrag(sG2[cur], wv * 16 + l15, kk, lg);
    }
    f32x4 oacc = (f32x4)0.f, gacc = (f32x4)0.f;
#pragma unroll
    for (int kk = 0; kk < 2; ++kk) {
      oacc = __builtin_amdgcn_mfma_f32_16x16x32_bf16(zA[kk], rF[kk], oacc, 0, 0, 0);
      gacc = __builtin_amdgcn_mfma_f32_16x16x32_bf16(rF[kk], gB[kk], gacc, 0, 0, 0);
    }
#pragma unroll
    for (int q = 0; q < 4; ++q) {
      int t = wv * 16 + lg * 4 + q;
      o[(btb + (size_t)c * 64 + t) * INNER_ + hofs + jb * 16 + l15] = avr[q] + oacc[q];
      R[q] = p63 * R[q] + g1r[q] - gacc[q];
    }
    __syncthreads();
    if (c + 1 < NCH) commit(cur ^ 1);
    cur ^= 1;
  }
}

// ---------------- RMS norm over INNER, * (1+gamma) * gate(bf16) -> bf16 ------
__global__ __launch_bounds__(256) void rmsgate_kernel(const float* __restrict__ o,
    const __hip_bfloat16* __restrict__ gate, const float* __restrict__ gamma,
    __hip_bfloat16* __restrict__ outn) {
  const int bt = blockIdx.x;
  const int tid = threadIdx.x;
  const size_t base = (size_t)bt * INNER_ + tid * 4;
  float4 ov = *(const float4*)(o + base);
  float ss = ov.x*ov.x + ov.y*ov.y + ov.z*ov.z + ov.w*ov.w;
#pragma unroll
  for (int m = 1; m <= 32; m <<= 1) ss += __shfl_xor(ss, m);
  __shared__ float red[4];
  if ((tid & 63) == 0) red[tid >> 6] = ss;
  __syncthreads();
  float tot = red[0] + red[1] + red[2] + red[3];
  float rms = sqrtf(tot * (1.f / (float)INNER_) + 1e-6f);
  float inv = 1.f / rms;
  float4 gm = *(const float4*)(gamma + tid * 4);
  ushort4 gt = *(const ushort4*)(gate + base);
  st_bf4(outn + base,
         ov.x * inv * (1.f + gm.x) * b2f(gt.x),
         ov.y * inv * (1.f + gm.y) * b2f(gt.y),
         ov.z * inv * (1.f + gm.z) * b2f(gt.z),
         ov.w * inv * (1.f + gm.w) * b2f(gt.w));
}

// ---------------- launch -----------------------------------------------------
extern "C" void kernel_launch(void* const* d_in, const int* in_sizes, int n_in,
                              void* d_out, int out_size, void* d_ws, size_t ws_size,
                              hipStream_t stream) {
  const float* x   = (const float*)d_in[0];
  const float* Wq  = (const float*)d_in[1];
  const float* Wk  = (const float*)d_in[2];
  const float* Wv  = (const float*)d_in[3];
  const float* Wa  = (const float*)d_in[4];
  const float* ba  = (const float*)d_in[5];
  const float* Wb  = (const float*)d_in[6];
  const float* bb  = (const float*)d_in[7];
  const float* Wg  = (const float*)d_in[8];
  const float* Wo  = (const float*)d_in[9];
  const float* cqw = (const float*)d_in[10];
  const float* cqb = (const float*)d_in[11];
  const float* ckw = (const float*)d_in[12];
  const float* ckb = (const float*)d_in[13];
  const float* cvw = (const float*)d_in[14];
  const float* cvb = (const float*)d_in[15];
  const float* gamma = (const float*)d_in[16];

  char* p = (char*)d_ws;
  __hip_bfloat16* qkvg = (__hip_bfloat16*)p;  p += 4 * N1 * 2;
  __hip_bfloat16* xb   = (__hip_bfloat16*)p;  p += N1 * 2;
  float* alpha = (float*)p;  p += (size_t)BT * H_ * 4;
  float* beta  = (float*)p;  p += (size_t)BT * H_ * 4;
  __hip_bfloat16* wtall = (__hip_bfloat16*)p;  p += (size_t)4352 * 1024 * 2;
  __hip_bfloat16* Wot   = (__hip_bfloat16*)p;  p += (size_t)1024 * 1024 * 2;
  float* AVg = (float*)p;  p += (size_t)NU * 4096 * 4;
  float* G1g = (float*)p;  p += (size_t)NU * 4096 * 4;
  __hip_bfloat16* Zg  = (__hip_bfloat16*)p;  p += (size_t)NU * 4096 * 2;
  __hip_bfloat16* G2g = (__hip_bfloat16*)p;  p += (size_t)NU * 4096 * 2;
  float* obuf = (float*)p;  p += N1 * 4;
  float* P63s = (float*)p;  p += (size_t)NU * 4;
  __hip_bfloat16* nrmb = xb;   // xb dead after proj GEMM
  float* outp = (float*)d_out;

  // 1) prep: cvt x, transpose 5 weights, pack Wab panel
  prep_kernel<<<10240, 256, 0, stream>>>(x, Wq, Wk, Wv, Wg, Wo, Wa, Wb, xb, wtall, Wot);

  // 2) fused projection GEMM (flat 272-block XCD-pinned grid)
  gemm256<<<272, 512, 0, stream>>>(xb, wtall, qkvg, alpha, beta, ba, bb, D_);

  // 3) chunked recurrence (conv+silu+l2norm fused into precompute)
  precomp_kernel<<<NU, 256, 0, stream>>>(qkvg, qkvg + N1, qkvg + 2 * N1,
                                         alpha, beta, cqw, cqb, ckw, ckb, cvw, cvb,
                                         Zg, G2g, AVg, G1g, P63s);
  chunkrec_kernel<<<B_ * H_ * 4, 256, 0, stream>>>(Zg, G2g, AVg, G1g, P63s, obuf);

  // 4) RMS + gate, then out-projection (128^2, 256 blocks)
  rmsgate_kernel<<<BT, 256, 0, stream>>>(obuf, qkvg + 3 * N1, gamma, nrmb);
  gemm_bf16<<<dim3(D_ / 128, BT / 128), 256, 0, stream>>>(nrmb, Wot, outp, BT, D_, INNER_);
}